// Round 3
// baseline (401805.566 us; speedup 1.0000x reference)
//
#include <hip/hip_runtime.h>
#include <cmath>

#define TDEC 250
#define NB 256
#define EPS_A 1e-6f

// ---------------- barrier area (unsigned words) ----------------
// arrive flag for block b at word b*32 (one cacheline each); gen at word 8192.
#define BAR_WORDS 8448

// ---------------- ws float offsets ----------------
#define OFF_CTX    8448                     // ctx_T   [768][64]
#define OFF_HATT   (OFF_CTX   + 49152)      // h_att_T [256][64]
#define OFF_H1     (OFF_HATT  + 16384)      // h1_T    [256][64]
#define OFF_H2     (OFF_H1    + 16384)      // h2_T    [256][64]
#define OFF_FRAME  (OFF_H2    + 16384)      // frame_T [400][64]
#define OFF_ALPHA  (OFF_FRAME + 25600)      // alpha   [64][512]
#define OFF_X      (OFF_ALPHA + 32768)      // x_T     [256][64]
#define OFF_X2     (OFF_X     + 16384)
#define OFF_X3     (OFF_X2    + 16384)
#define OFF_GICTX  (OFF_X3    + 16384)      // gi_ctx_T [768][64]
#define OFF_GHATT  (OFF_GICTX + 49152)      // gh_att_T [768][64]
#define OFF_GH1    (OFF_GHATT + 49152)
#define OFF_GH2    (OFF_GH1   + 49152)
#define OFF_PRE    (OFF_GH2   + 49152)      // pre_T [128][64]
#define OFF_GT     (OFF_PRE   + 8192)       // G_T   [168][64]
#define OFF_F8     (OFF_GT    + 10752)      // f8    [64][512][8]
#define OFF_LOGP   (OFF_F8    + 262144)     // [64][512]
#define OFF_E      (OFF_LOGP  + 32768)      // [64][512]

struct Prior { float v[11]; };

struct KArgs {
  const float *enc;
  const float *p1w,*p1b,*p2w,*p2b;
  const float *awi,*abi,*awh,*abh;
  const float *dWw,*dWb,*dVw,*dFw,*dUw,*dTw,*dTb,*dvw;
  const float *lw,*lb;
  const float *g1wi,*g1bi,*g1wh,*g1bh;
  const float *g2wi,*g2bi,*g2wh,*g2bh;
  const float *prw,*prb;
  float* ws; float* dout;
  Prior pr;
};

// ---------------- init: zero barrier + states + alpha onehot ----------------
__global__ __launch_bounds__(256) void k_init(float* ws) {
  int idx = blockIdx.x * 256 + threadIdx.x;
  int total = OFF_ALPHA + 32768;
  for (int i = idx; i < total; i += gridDim.x * 256) {
    float v = 0.f;
    if (i >= OFF_ALPHA && (((i - OFF_ALPHA) & 511) == 0)) v = 1.f;
    ws[i] = v;
  }
}

// ---------------- flag-tree grid barrier ----------------
__device__ __forceinline__ void gridbar(unsigned* bar, unsigned g) {
  __syncthreads();
  if (blockIdx.x == NB - 1) {
    int i = threadIdx.x;
    if (i < NB - 1) {
      while (__hip_atomic_load(&bar[i * 32], __ATOMIC_ACQUIRE, __HIP_MEMORY_SCOPE_AGENT) < g)
        __builtin_amdgcn_s_sleep(2);
    }
    __syncthreads();
    if (threadIdx.x == 0)
      __hip_atomic_store(&bar[8192], g, __ATOMIC_RELEASE, __HIP_MEMORY_SCOPE_AGENT);
  } else {
    if (threadIdx.x == 0) {
      __hip_atomic_store(&bar[blockIdx.x * 32], g, __ATOMIC_RELEASE, __HIP_MEMORY_SCOPE_AGENT);
      while (__hip_atomic_load(&bar[8192], __ATOMIC_ACQUIRE, __HIP_MEMORY_SCOPE_AGENT) < g)
        __builtin_amdgcn_s_sleep(2);
    }
  }
  __syncthreads();
}

// ---------------- generic tiled GEMM: outT[N][64] = W[N][K] x actT[K][64] ----------------
struct GemmCfg {
  const float* A0; const float* A1; int K0; int K;
  const float* W; int wstr; int wofs;
  const float* bias; float* outT;
  int N, J, jgN, LR, activ;      // activ 0 none, 1 relu, 2 tanh
  int store;                     // 1: also scatter to dout (proj)
  float* dout; int tq;
};

__device__ __forceinline__ void gstore(const GemmCfg& c, int jj, int b, float v) {
  if (c.activ == 1) v = fmaxf(v, 0.f);
  else if (c.activ == 2) v = tanhf(v);
  c.outT[jj * 64 + b] = v;
  if (c.store == 1)
    c.dout[(size_t)b * 100000 + (jj / 5) * 1250 + c.tq * 5 + (jj % 5)] = v;
}

__device__ void gemm_run(const GemmCfg& c, int rb, float* sm) {
  int R = 1 << c.LR;
  int jg = rb % c.jgN, rg = rb / c.jgN;
  int r0 = rg * R, j0 = jg * c.J;
  int Kp = c.K + 4;
  for (int idx = threadIdx.x; idx < (c.K << c.LR); idx += 256) {
    int k = idx >> c.LR, r = idx & (R - 1);
    float v = (k < c.K0) ? c.A0[k * 64 + r0 + r] : c.A1[(k - c.K0) * 64 + r0 + r];
    sm[r * Kp + k] = v;
  }
  __syncthreads();
  int k4n = c.K >> 2;
  if ((c.J & 1) == 0) {
    int Jh = c.J >> 1;
    int np = Jh << c.LR;
    for (int e = threadIdx.x; e < np; e += 256) {
      int r = e & (R - 1); int q = e >> c.LR;
      int ja = j0 + q, jb = ja + Jh;
      const float4* wa = (const float4*)(c.W + (size_t)ja * c.wstr + c.wofs);
      const float4* wb = (const float4*)(c.W + (size_t)jb * c.wstr + c.wofs);
      const float4* ar = (const float4*)(sm + r * Kp);
      float acca = c.bias ? c.bias[ja] : 0.f;
      float accb = c.bias ? c.bias[jb] : 0.f;
      for (int k4 = 0; k4 < k4n; ++k4) {
        float4 a = ar[k4];
        float4 x = wa[k4], y = wb[k4];
        acca = fmaf(a.x,x.x, fmaf(a.y,x.y, fmaf(a.z,x.z, fmaf(a.w,x.w, acca))));
        accb = fmaf(a.x,y.x, fmaf(a.y,y.y, fmaf(a.z,y.z, fmaf(a.w,y.w, accb))));
      }
      gstore(c, ja, r0 + r, acca);
      gstore(c, jb, r0 + r, accb);
    }
  } else {
    for (int e = threadIdx.x; e < (c.J << c.LR); e += 256) {
      int r = e & (R - 1); int jj = j0 + (e >> c.LR);
      if (jj < c.N) {
        const float4* wa = (const float4*)(c.W + (size_t)jj * c.wstr + c.wofs);
        const float4* ar = (const float4*)(sm + r * Kp);
        float acc = c.bias ? c.bias[jj] : 0.f;
        for (int k4 = 0; k4 < k4n; ++k4) {
          float4 a = ar[k4]; float4 x = wa[k4];
          acc = fmaf(a.x,x.x, fmaf(a.y,x.y, fmaf(a.z,x.z, fmaf(a.w,x.w, acc))));
        }
        gstore(c, jj, r0 + r, acc);
      }
    }
  }
}

// ---------------- striped GRU: block owns 16 gate-triples x 16 batch rows ----------------
__device__ void stripe_gru(const float* actT, int K, const float* W, int wstr, int wofs,
                           const float* giaddT, const float* bi,
                           const float* ghT, const float* bh,
                           float* hT, const float* xaddT, float* xnextT,
                           int rb, float* sm)
{
  int jg = rb & 15, rg = rb >> 4;
  int r0 = rg * 16, j0 = jg * 16;
  int Kp = K + 4;
  for (int idx = threadIdx.x; idx < (K << 4); idx += 256) {
    int k = idx >> 4, r = idx & 15;
    sm[r * Kp + k] = actT[k * 64 + r0 + r];
  }
  __syncthreads();
  int e = threadIdx.x;
  int r = e & 15, q = e >> 4;
  int j = j0 + q, b = r0 + r;
  const float4* w0 = (const float4*)(W + (size_t)j * wstr + wofs);
  const float4* w1 = (const float4*)(W + (size_t)(j + 256) * wstr + wofs);
  const float4* w2 = (const float4*)(W + (size_t)(j + 512) * wstr + wofs);
  const float4* ar = (const float4*)(sm + r * Kp);
  float a0 = 0.f, a1 = 0.f, a2 = 0.f;
  for (int k4 = 0; k4 < (K >> 2); ++k4) {
    float4 a = ar[k4];
    float4 x = w0[k4], y = w1[k4], z4 = w2[k4];
    a0 = fmaf(a.x,x.x, fmaf(a.y,x.y, fmaf(a.z,x.z, fmaf(a.w,x.w, a0))));
    a1 = fmaf(a.x,y.x, fmaf(a.y,y.y, fmaf(a.z,y.z, fmaf(a.w,y.w, a1))));
    a2 = fmaf(a.x,z4.x, fmaf(a.y,z4.y, fmaf(a.z,z4.z, fmaf(a.w,z4.w, a2))));
  }
  if (giaddT) {
    a0 += giaddT[j * 64 + b];
    a1 += giaddT[(j + 256) * 64 + b];
    a2 += giaddT[(j + 512) * 64 + b];
  }
  float gr = a0 + bi[j], gz = a1 + bi[j + 256], gn = a2 + bi[j + 512];
  float hr = ghT[j * 64 + b] + bh[j];
  float hz = ghT[(j + 256) * 64 + b] + bh[j + 256];
  float hn = ghT[(j + 512) * 64 + b] + bh[j + 512];
  float rr = 1.f / (1.f + expf(-(gr + hr)));
  float zz = 1.f / (1.f + expf(-(gz + hz)));
  float nn = tanhf(gn + rr * hn);
  float h = hT[j * 64 + b];
  float hnew = (1.f - zz) * nn + zz * h;
  hT[j * 64 + b] = hnew;
  if (xnextT) xnextT[j * 64 + b] = xaddT[j * 64 + b] + hnew;
}

// ---------------- prenet L1+L2 fused, one block per batch row ----------------
__device__ void prenet_fused(const KArgs& A, int b, float* sm) {
  float* fr = sm;          // 400
  float* h1s = sm + 400;   // 256
  int tid = threadIdx.x;
  for (int k = tid; k < 400; k += 256) fr[k] = A.ws[OFF_FRAME + k * 64 + b];
  __syncthreads();
  {
    const float4* wr = (const float4*)(A.p1w + (size_t)tid * 400);
    float a = A.p1b[tid];
#pragma unroll 4
    for (int k4 = 0; k4 < 100; ++k4) {
      float4 w = wr[k4];
      float4 x = *(const float4*)(&fr[k4 * 4]);
      a = fmaf(w.x, x.x, fmaf(w.y, x.y, fmaf(w.z, x.z, fmaf(w.w, x.w, a))));
    }
    h1s[tid] = fmaxf(a, 0.f);
  }
  __syncthreads();
  if (tid < 128) {
    const float4* wr = (const float4*)(A.p2w + (size_t)tid * 256);
    float a = A.p2b[tid];
#pragma unroll 4
    for (int k4 = 0; k4 < 64; ++k4) {
      float4 w = wr[k4];
      float4 x = *(const float4*)(&h1s[k4 * 4]);
      a = fmaf(w.x, x.x, fmaf(w.y, x.y, fmaf(w.z, x.z, fmaf(w.w, x.w, a))));
    }
    A.ws[OFF_PRE + tid * 64 + b] = fmaxf(a, 0.f);
  }
  __syncthreads();
}

// ---------------- attention GRU gates + dW MLP + dV, one block per batch row ----------------
__device__ void att_fused(const KArgs& A, int b, float* sm) {
  float* spre = sm;        // 128
  float* hs = sm + 128;    // 256
  float* g1s = sm + 384;   // 128
  int j = threadIdx.x;
  if (j < 128) spre[j] = A.ws[OFF_PRE + j * 64 + b];
  __syncthreads();
  const float4* w0 = (const float4*)(A.awi + (size_t)j * 896 + 768);
  const float4* w1 = (const float4*)(A.awi + (size_t)(j + 256) * 896 + 768);
  const float4* w2 = (const float4*)(A.awi + (size_t)(j + 512) * 896 + 768);
  float a0 = 0.f, a1 = 0.f, a2 = 0.f;
#pragma unroll 4
  for (int k4 = 0; k4 < 32; ++k4) {
    float4 x = *(const float4*)(&spre[k4 * 4]);
    float4 p = w0[k4], q = w1[k4], s4 = w2[k4];
    a0 = fmaf(x.x,p.x, fmaf(x.y,p.y, fmaf(x.z,p.z, fmaf(x.w,p.w, a0))));
    a1 = fmaf(x.x,q.x, fmaf(x.y,q.y, fmaf(x.z,q.z, fmaf(x.w,q.w, a1))));
    a2 = fmaf(x.x,s4.x, fmaf(x.y,s4.y, fmaf(x.z,s4.z, fmaf(x.w,s4.w, a2))));
  }
  a0 += A.ws[OFF_GICTX + j * 64 + b];
  a1 += A.ws[OFF_GICTX + (j + 256) * 64 + b];
  a2 += A.ws[OFF_GICTX + (j + 512) * 64 + b];
  float gr = a0 + A.abi[j], gz = a1 + A.abi[j + 256], gn = a2 + A.abi[j + 512];
  float hr = A.ws[OFF_GHATT + j * 64 + b] + A.abh[j];
  float hz = A.ws[OFF_GHATT + (j + 256) * 64 + b] + A.abh[j + 256];
  float hn = A.ws[OFF_GHATT + (j + 512) * 64 + b] + A.abh[j + 512];
  float rr = 1.f / (1.f + expf(-(gr + hr)));
  float zz = 1.f / (1.f + expf(-(gz + hz)));
  float nn = tanhf(gn + rr * hn);
  float h = A.ws[OFF_HATT + j * 64 + b];
  float hnew = (1.f - zz) * nn + zz * h;
  A.ws[OFF_HATT + j * 64 + b] = hnew;
  hs[j] = hnew;
  __syncthreads();
  if (j < 128) {
    const float4* wr = (const float4*)(A.dWw + (size_t)j * 256);
    float a = A.dWb[j];
#pragma unroll 4
    for (int k4 = 0; k4 < 64; ++k4) {
      float4 w = wr[k4];
      float4 x = *(const float4*)(&hs[k4 * 4]);
      a = fmaf(w.x, x.x, fmaf(w.y, x.y, fmaf(w.z, x.z, fmaf(w.w, x.w, a))));
    }
    g1s[j] = tanhf(a);
  }
  __syncthreads();
  if (j < 168) {
    const float4* wr = (const float4*)(A.dVw + (size_t)j * 128);
    float a = 0.f;
#pragma unroll 4
    for (int k4 = 0; k4 < 32; ++k4) {
      float4 w = wr[k4];
      float4 x = *(const float4*)(&g1s[k4 * 4]);
      a = fmaf(w.x, x.x, fmaf(w.y, x.y, fmaf(w.z, x.z, fmaf(w.w, x.w, a))));
    }
    A.ws[OFF_GT + j * 64 + b] = a;
  }
  __syncthreads();
}

// ---------------- static conv + prior (reads prev alpha) ----------------
__device__ void conv_fp(const KArgs& A, int item, float* sm) {
  int b = item >> 2, s0 = (item & 3) * 128;
  float* sal = sm;
  float* sdF = sm + 160;
  for (int i = threadIdx.x; i < 148; i += 256) {
    int sg = s0 - 10 + i;
    sal[i] = (sg >= 0 && sg < 512) ? A.ws[OFF_ALPHA + b * 512 + sg] : 0.f;
  }
  for (int i = threadIdx.x; i < 168; i += 256) sdF[i] = A.dFw[i];
  __syncthreads();
  for (int q = threadIdx.x; q < 1024; q += 256) {
    int sl = q >> 3, ch = q & 7;
    float fa = 0.f;
#pragma unroll
    for (int k = 0; k < 21; ++k) fa = fmaf(sdF[ch * 21 + k], sal[sl + k], fa);
    A.ws[OFF_F8 + ((size_t)b * 512 + s0 + sl) * 8 + ch] = fa;
  }
  if (threadIdx.x < 128) {
    int sl = threadIdx.x;
    float p = 0.f;
#pragma unroll
    for (int k = 0; k < 11; ++k) p = fmaf(A.pr.v[k], sal[sl + k], p);
    A.ws[OFF_LOGP + b * 512 + s0 + sl] = logf(fmaxf(p, 1e-6f));
  }
  __syncthreads();
}

// ---------------- dynamic conv + energy MLP ----------------
__device__ void dyn_e(const KArgs& A, float* sm) {
  int b = blockIdx.x >> 2, s0 = (blockIdx.x & 3) * 128;
  float* sal = sm;            // 148 (pad 152)
  float* sG  = sm + 152;      // 168
  float* sfp = sm + 320;      // 1152
  float* sgp = sfp + 1152;    // 1152
  float* sdU = sgp + 1152;    // 1024
  float* sdT = sdU + 1024;    // 1024
  float* sdtb = sdT + 1024;   // 128
  float* sdv = sdtb + 128;    // 128
  float* slp = sdv + 128;     // 128
  float* ses = slp + 128;     // 256
  int tid = threadIdx.x;
  for (int i = tid; i < 148; i += 256) {
    int sg = s0 - 10 + i;
    sal[i] = (sg >= 0 && sg < 512) ? A.ws[OFF_ALPHA + b * 512 + sg] : 0.f;
  }
  for (int i = tid; i < 168; i += 256) sG[i] = A.ws[OFF_GT + i * 64 + b];
  for (int i = tid; i < 1024; i += 256) {
    sdU[i] = A.dUw[i]; sdT[i] = A.dTw[i];
    int sl = i >> 3, ch = i & 7;
    sfp[sl * 9 + ch] = A.ws[OFF_F8 + ((size_t)b * 512 + s0 + sl) * 8 + ch];
  }
  if (tid < 128) {
    sdtb[tid] = A.dTb[tid]; sdv[tid] = A.dvw[tid];
    slp[tid] = A.ws[OFF_LOGP + b * 512 + s0 + tid];
  }
  __syncthreads();
  for (int q = tid; q < 1024; q += 256) {
    int sl = q >> 3, ch = q & 7;
    float ga = 0.f;
#pragma unroll
    for (int k = 0; k < 21; ++k) ga = fmaf(sG[ch * 21 + k], sal[sl + k], ga);
    sgp[sl * 9 + ch] = ga;
  }
  __syncthreads();
  int sl = tid & 127, half = tid >> 7;
  float f0[8], g0[8];
#pragma unroll
  for (int r2 = 0; r2 < 8; ++r2) { f0[r2] = sfp[sl * 9 + r2]; g0[r2] = sgp[sl * 9 + r2]; }
  float acc = 0.f;
  for (int cc = half * 64; cc < half * 64 + 64; ++cc) {
    float a = sdtb[cc];
#pragma unroll
    for (int r2 = 0; r2 < 8; ++r2) a = fmaf(sdU[cc * 8 + r2], f0[r2], fmaf(sdT[cc * 8 + r2], g0[r2], a));
    acc = fmaf(sdv[cc], tanhf(a), acc);
  }
  ses[half * 128 + sl] = acc;
  __syncthreads();
  if (tid < 128)
    A.ws[OFF_E + b * 512 + s0 + tid] = ses[tid] + ses[128 + tid] + slp[tid];
  __syncthreads();
}

// ---------------- softmax + sparse context ----------------
__device__ void softmax_ctx(const KArgs& A, float* sm) {
  int b = blockIdx.x, tid = threadIdx.x;
  float* red = sm;                 // 4 (pad 8)
  int* wc = (int*)(sm + 8);        // 8
  float* lv = sm + 16;             // 512
  short* li = (short*)(sm + 528);  // 512 shorts
  float e0 = A.ws[OFF_E + b * 512 + tid];
  float e1 = A.ws[OFF_E + b * 512 + 256 + tid];
  float m = fmaxf(e0, e1);
  for (int o = 32; o; o >>= 1) m = fmaxf(m, __shfl_xor(m, o));
  int lane = tid & 63, wv = tid >> 6;
  if (lane == 0) red[wv] = m;
  __syncthreads();
  m = fmaxf(fmaxf(red[0], red[1]), fmaxf(red[2], red[3]));
  float p0 = expf(e0 - m), p1 = expf(e1 - m);
  float s = p0 + p1;
  for (int o = 32; o; o >>= 1) s += __shfl_xor(s, o);
  __syncthreads();
  if (lane == 0) red[wv] = s;
  __syncthreads();
  float inv = 1.f / (red[0] + red[1] + red[2] + red[3]);
  float a0 = p0 * inv, a1 = p1 * inv;
  A.ws[OFF_ALPHA + b * 512 + tid] = a0;
  A.ws[OFF_ALPHA + b * 512 + 256 + tid] = a1;
  unsigned long long m0 = __ballot(a0 > EPS_A);
  unsigned long long m1 = __ballot(a1 > EPS_A);
  if (lane == 0) { wc[wv] = (int)__popcll(m0); wc[4 + wv] = (int)__popcll(m1); }
  __syncthreads();
  int base0 = 0;
  for (int w = 0; w < wv; ++w) base0 += wc[w];
  int totalA = wc[0] + wc[1] + wc[2] + wc[3];
  int base1 = totalA;
  for (int w = 0; w < wv; ++w) base1 += wc[4 + w];
  int n = totalA + wc[4] + wc[5] + wc[6] + wc[7];
  unsigned long long below = (1ull << lane) - 1ull;
  if (a0 > EPS_A) { int p = base0 + (int)__popcll(m0 & below); li[p] = (short)tid; lv[p] = a0; }
  if (a1 > EPS_A) { int p = base1 + (int)__popcll(m1 & below); li[p] = (short)(256 + tid); lv[p] = a1; }
  __syncthreads();
  const float* encb = A.enc + (size_t)b * 512 * 768;
  for (int d = tid; d < 768; d += 256) {
    float acc = 0.f;
    for (int i = 0; i < n; ++i) acc = fmaf(lv[i], encb[(size_t)li[i] * 768 + d], acc);
    A.ws[OFF_CTX + d * 64 + b] = acc;
  }
  __syncthreads();
}

// ---------------- the persistent decoder ----------------
__global__ __launch_bounds__(256, 1) void k_decode(KArgs A) {
  __shared__ __align__(16) float sm[16448];
  float* ws = A.ws;
  unsigned* bar = (unsigned*)ws;
  int blk = blockIdx.x;
  unsigned g = 0;

  for (int t = 0; t <= TDEC; ++t) {
    // ---- P0: proj(t-1) || gi_ctx || gh_att || gh1 || gh2 ----
    if (blk < 64) {
      if (t > 0) {
        GemmCfg c{ws + OFF_X3, nullptr, 256, 256, A.prw, 256, 0, A.prb, ws + OFF_FRAME,
                  400, 25, 16, 4, 0, 1, A.dout, t - 1};
        gemm_run(c, blk, sm);
      }
    } else if (t < TDEC) {
      if (blk < 160) {
        GemmCfg c{ws + OFF_CTX, nullptr, 768, 768, A.awi, 896, 0, nullptr, ws + OFF_GICTX,
                  768, 32, 24, 4, 0, 0, nullptr, 0};
        gemm_run(c, blk - 64, sm);
      } else if (blk < 192) {
        GemmCfg c{ws + OFF_HATT, nullptr, 256, 256, A.awh, 256, 0, nullptr, ws + OFF_GHATT,
                  768, 48, 16, 5, 0, 0, nullptr, 0};
        gemm_run(c, blk - 160, sm);
      } else if (blk < 224) {
        GemmCfg c{ws + OFF_H1, nullptr, 256, 256, A.g1wh, 256, 0, nullptr, ws + OFF_GH1,
                  768, 48, 16, 5, 0, 0, nullptr, 0};
        gemm_run(c, blk - 192, sm);
      } else {
        GemmCfg c{ws + OFF_H2, nullptr, 256, 256, A.g2wh, 256, 0, nullptr, ws + OFF_GH2,
                  768, 48, 16, 5, 0, 0, nullptr, 0};
        gemm_run(c, blk - 224, sm);
      }
    }
    if (t == TDEC) break;
    gridbar(bar, ++g);

    // ---- P1: prenet L1+L2 (per-b) || static conv + prior ----
    if (blk < 64) {
      prenet_fused(A, blk, sm);
    } else {
      int rel = blk - 64;
      for (int item = rel; item < 256; item += 192) conv_fp(A, item, sm);
    }
    gridbar(bar, ++g);

    // ---- P2: attention GRU gates + dW + dV (per-b) ----
    if (blk < 64) att_fused(A, blk, sm);
    gridbar(bar, ++g);

    // ---- P3: dynamic conv + energy MLP ----
    dyn_e(A, sm);
    gridbar(bar, ++g);

    // ---- P4: softmax + sparse context ----
    if (blk < 64) softmax_ctx(A, sm);
    gridbar(bar, ++g);

    // ---- P5: x = [ctx; h_att] @ lw + lb ----
    if (blk < 64) {
      GemmCfg c{ws + OFF_CTX, ws + OFF_HATT, 768, 1024, A.lw, 1024, 0, A.lb, ws + OFF_X,
                256, 16, 16, 4, 0, 0, nullptr, 0};
      gemm_run(c, blk, sm);
    }
    gridbar(bar, ++g);

    // ---- P6: GRU1 (striped) -> h1, x2 ----
    if (blk < 64)
      stripe_gru(ws + OFF_X, 256, A.g1wi, 256, 0, nullptr, A.g1bi,
                 ws + OFF_GH1, A.g1bh, ws + OFF_H1, ws + OFF_X, ws + OFF_X2, blk, sm);
    gridbar(bar, ++g);

    // ---- P7: GRU2 (striped) -> h2, x3 ----
    if (blk < 64)
      stripe_gru(ws + OFF_X2, 256, A.g2wi, 256, 0, nullptr, A.g2bi,
                 ws + OFF_GH2, A.g2bh, ws + OFF_H2, ws + OFF_X2, ws + OFF_X3, blk, sm);
    gridbar(bar, ++g);
  }
}

// ---------------- host ----------------
extern "C" void kernel_launch(void* const* d_in, const int* in_sizes, int n_in,
                              void* d_out, int out_size, void* d_ws, size_t ws_size,
                              hipStream_t stream) {
  (void)in_sizes; (void)n_in; (void)out_size; (void)ws_size;
  KArgs A;
  A.enc  = (const float*)d_in[0];
  A.p1w  = (const float*)d_in[1];  A.p1b  = (const float*)d_in[2];
  A.p2w  = (const float*)d_in[3];  A.p2b  = (const float*)d_in[4];
  A.awi  = (const float*)d_in[5];  A.abi  = (const float*)d_in[6];
  A.awh  = (const float*)d_in[7];  A.abh  = (const float*)d_in[8];
  A.dWw  = (const float*)d_in[9];  A.dWb  = (const float*)d_in[10];
  A.dVw  = (const float*)d_in[11]; A.dFw  = (const float*)d_in[12];
  A.dUw  = (const float*)d_in[13]; A.dTw  = (const float*)d_in[14];
  A.dTb  = (const float*)d_in[15]; A.dvw  = (const float*)d_in[16];
  A.lw   = (const float*)d_in[17]; A.lb   = (const float*)d_in[18];
  A.g1wi = (const float*)d_in[19]; A.g1bi = (const float*)d_in[20];
  A.g1wh = (const float*)d_in[21]; A.g1bh = (const float*)d_in[22];
  A.g2wi = (const float*)d_in[23]; A.g2bi = (const float*)d_in[24];
  A.g2wh = (const float*)d_in[25]; A.g2bh = (const float*)d_in[26];
  A.prw  = (const float*)d_in[27]; A.prb  = (const float*)d_in[28];
  A.ws   = (float*)d_ws;
  A.dout = (float*)d_out;

  // beta-binomial prior pmf (n=10, a=0.1, b=0.9), flipped
  {
    double aP = 0.1, bP = 0.9;
    double logB0 = lgamma(aP) + lgamma(bP) - lgamma(aP + bP);
    double pm[11];
    for (int k = 0; k <= 10; ++k) {
      double logC = lgamma(11.0) - lgamma(k + 1.0) - lgamma(11.0 - k);
      double logBt = lgamma(k + aP) + lgamma(10.0 - k + bP) - lgamma(10.0 + aP + bP);
      pm[k] = exp(logC + logBt - logB0);
    }
    for (int k = 0; k < 11; ++k) A.pr.v[k] = (float)pm[10 - k];
  }

  k_init<<<256, 256, 0, stream>>>((float*)d_ws);
  k_decode<<<NB, 256, 0, stream>>>(A);
}

// Round 4
// 146709.534 us; speedup vs baseline: 2.7388x; 2.7388x over previous
//
#include <hip/hip_runtime.h>
#include <cmath>

#define TDEC 250
#define NB 256
#define EPS_A 1e-6f

// ---------------- barrier area (unsigned words) ----------------
// arrive flag for block b at word b*32 (one cacheline each); gen at word 8192.
#define BAR_WORDS 8448

// ---------------- ws float offsets ----------------
#define OFF_CTX    8448                     // ctx_T   [768][64]
#define OFF_HATT   (OFF_CTX   + 49152)      // h_att_T [256][64]
#define OFF_H1     (OFF_HATT  + 16384)      // h1_T    [256][64]
#define OFF_H2     (OFF_H1    + 16384)      // h2_T    [256][64]
#define OFF_FRAME  (OFF_H2    + 16384)      // frame_T [400][64]
#define OFF_ALPHA  (OFF_FRAME + 25600)      // alpha   [64][512]
#define OFF_X      (OFF_ALPHA + 32768)      // x_T     [256][64]
#define OFF_X2     (OFF_X     + 16384)
#define OFF_X3     (OFF_X2    + 16384)
#define OFF_GICTX  (OFF_X3    + 16384)      // gi_ctx_T [768][64]
#define OFF_GHATT  (OFF_GICTX + 49152)      // gh_att_T [768][64]
#define OFF_GH1    (OFF_GHATT + 49152)
#define OFF_GH2    (OFF_GH1   + 49152)
#define OFF_PRE    (OFF_GH2   + 49152)      // pre_T [128][64]
#define OFF_GT     (OFF_PRE   + 8192)       // G_T   [168][64]
#define OFF_F8     (OFF_GT    + 10752)      // f8    [64][512][8]
#define OFF_LOGP   (OFF_F8    + 262144)     // [64][512]
#define OFF_E      (OFF_LOGP  + 32768)      // [64][512]

struct Prior { float v[11]; };

struct KArgs {
  const float *enc;
  const float *p1w,*p1b,*p2w,*p2b;
  const float *awi,*abi,*awh,*abh;
  const float *dWw,*dWb,*dVw,*dFw,*dUw,*dTw,*dTb,*dvw;
  const float *lw,*lb;
  const float *g1wi,*g1bi,*g1wh,*g1bh;
  const float *g2wi,*g2bi,*g2wh,*g2bh;
  const float *prw,*prb;
  float* ws; float* dout;
  Prior pr;
};

// ---------------- init: zero barrier + states + alpha onehot ----------------
__global__ __launch_bounds__(256) void k_init(float* ws) {
  int idx = blockIdx.x * 256 + threadIdx.x;
  int total = OFF_ALPHA + 32768;
  for (int i = idx; i < total; i += gridDim.x * 256) {
    float v = 0.f;
    if (i >= OFF_ALPHA && (((i - OFF_ALPHA) & 511) == 0)) v = 1.f;
    ws[i] = v;
  }
}

// ---------------- flag-tree grid barrier, relaxed polls + one fence each ----------------
// Acquire-polling is catastrophic on gfx950: every acquire load emits buffer_inv
// (full L2 invalidate). Poll RELAXED (coherent via MALL, no cache maintenance),
// fence exactly once per barrier per block.
__device__ __forceinline__ void gridbar(unsigned* bar, unsigned g) {
  __syncthreads();
  if (blockIdx.x == NB - 1) {
    // coordinator: its own prior writes are published by the acq_rel fence below.
    int i = threadIdx.x;
    if (i < NB - 1) {
      while (__hip_atomic_load(&bar[i * 32], __ATOMIC_RELAXED, __HIP_MEMORY_SCOPE_AGENT) < g)
        __builtin_amdgcn_s_sleep(1);
    }
    __syncthreads();
    if (threadIdx.x == 0) {
      // acq: see all workers' data (and transitively republish); rel: publish own data + flag order
      __builtin_amdgcn_fence(__ATOMIC_ACQ_REL, "agent");
      __hip_atomic_store(&bar[8192], g, __ATOMIC_RELAXED, __HIP_MEMORY_SCOPE_AGENT);
    }
  } else {
    if (threadIdx.x == 0) {
      __builtin_amdgcn_fence(__ATOMIC_RELEASE, "agent");   // one buffer_wbl2
      __hip_atomic_store(&bar[blockIdx.x * 32], g, __ATOMIC_RELAXED, __HIP_MEMORY_SCOPE_AGENT);
      while (__hip_atomic_load(&bar[8192], __ATOMIC_RELAXED, __HIP_MEMORY_SCOPE_AGENT) < g)
        __builtin_amdgcn_s_sleep(1);
      __builtin_amdgcn_fence(__ATOMIC_ACQUIRE, "agent");   // one buffer_inv
    }
  }
  __syncthreads();
}

// ---------------- generic tiled GEMM: outT[N][64] = W[N][K] x actT[K][64] ----------------
struct GemmCfg {
  const float* A0; const float* A1; int K0; int K;
  const float* W; int wstr; int wofs;
  const float* bias; float* outT;
  int N, J, jgN, LR, activ;      // activ 0 none, 1 relu, 2 tanh
  int store;                     // 1: also scatter to dout (proj)
  float* dout; int tq;
};

__device__ __forceinline__ void gstore(const GemmCfg& c, int jj, int b, float v) {
  if (c.activ == 1) v = fmaxf(v, 0.f);
  else if (c.activ == 2) v = tanhf(v);
  c.outT[jj * 64 + b] = v;
  if (c.store == 1)
    c.dout[(size_t)b * 100000 + (jj / 5) * 1250 + c.tq * 5 + (jj % 5)] = v;
}

__device__ void gemm_run(const GemmCfg& c, int rb, float* sm) {
  int R = 1 << c.LR;
  int jg = rb % c.jgN, rg = rb / c.jgN;
  int r0 = rg * R, j0 = jg * c.J;
  int Kp = c.K + 4;
  for (int idx = threadIdx.x; idx < (c.K << c.LR); idx += 256) {
    int k = idx >> c.LR, r = idx & (R - 1);
    float v = (k < c.K0) ? c.A0[k * 64 + r0 + r] : c.A1[(k - c.K0) * 64 + r0 + r];
    sm[r * Kp + k] = v;
  }
  __syncthreads();
  int k4n = c.K >> 2;
  if ((c.J & 1) == 0) {
    int Jh = c.J >> 1;
    int np = Jh << c.LR;
    for (int e = threadIdx.x; e < np; e += 256) {
      int r = e & (R - 1); int q = e >> c.LR;
      int ja = j0 + q, jb = ja + Jh;
      const float4* wa = (const float4*)(c.W + (size_t)ja * c.wstr + c.wofs);
      const float4* wb = (const float4*)(c.W + (size_t)jb * c.wstr + c.wofs);
      const float4* ar = (const float4*)(sm + r * Kp);
      float acca = c.bias ? c.bias[ja] : 0.f;
      float accb = c.bias ? c.bias[jb] : 0.f;
      for (int k4 = 0; k4 < k4n; ++k4) {
        float4 a = ar[k4];
        float4 x = wa[k4], y = wb[k4];
        acca = fmaf(a.x,x.x, fmaf(a.y,x.y, fmaf(a.z,x.z, fmaf(a.w,x.w, acca))));
        accb = fmaf(a.x,y.x, fmaf(a.y,y.y, fmaf(a.z,y.z, fmaf(a.w,y.w, accb))));
      }
      gstore(c, ja, r0 + r, acca);
      gstore(c, jb, r0 + r, accb);
    }
  } else {
    for (int e = threadIdx.x; e < (c.J << c.LR); e += 256) {
      int r = e & (R - 1); int jj = j0 + (e >> c.LR);
      if (jj < c.N) {
        const float4* wa = (const float4*)(c.W + (size_t)jj * c.wstr + c.wofs);
        const float4* ar = (const float4*)(sm + r * Kp);
        float acc = c.bias ? c.bias[jj] : 0.f;
        for (int k4 = 0; k4 < k4n; ++k4) {
          float4 a = ar[k4]; float4 x = wa[k4];
          acc = fmaf(a.x,x.x, fmaf(a.y,x.y, fmaf(a.z,x.z, fmaf(a.w,x.w, acc))));
        }
        gstore(c, jj, r0 + r, acc);
      }
    }
  }
}

// ---------------- striped GRU: block owns 16 gate-triples x 16 batch rows ----------------
__device__ void stripe_gru(const float* actT, int K, const float* W, int wstr, int wofs,
                           const float* giaddT, const float* bi,
                           const float* ghT, const float* bh,
                           float* hT, const float* xaddT, float* xnextT,
                           int rb, float* sm)
{
  int jg = rb & 15, rg = rb >> 4;
  int r0 = rg * 16, j0 = jg * 16;
  int Kp = K + 4;
  for (int idx = threadIdx.x; idx < (K << 4); idx += 256) {
    int k = idx >> 4, r = idx & 15;
    sm[r * Kp + k] = actT[k * 64 + r0 + r];
  }
  __syncthreads();
  int e = threadIdx.x;
  int r = e & 15, q = e >> 4;
  int j = j0 + q, b = r0 + r;
  const float4* w0 = (const float4*)(W + (size_t)j * wstr + wofs);
  const float4* w1 = (const float4*)(W + (size_t)(j + 256) * wstr + wofs);
  const float4* w2 = (const float4*)(W + (size_t)(j + 512) * wstr + wofs);
  const float4* ar = (const float4*)(sm + r * Kp);
  float a0 = 0.f, a1 = 0.f, a2 = 0.f;
  for (int k4 = 0; k4 < (K >> 2); ++k4) {
    float4 a = ar[k4];
    float4 x = w0[k4], y = w1[k4], z4 = w2[k4];
    a0 = fmaf(a.x,x.x, fmaf(a.y,x.y, fmaf(a.z,x.z, fmaf(a.w,x.w, a0))));
    a1 = fmaf(a.x,y.x, fmaf(a.y,y.y, fmaf(a.z,y.z, fmaf(a.w,y.w, a1))));
    a2 = fmaf(a.x,z4.x, fmaf(a.y,z4.y, fmaf(a.z,z4.z, fmaf(a.w,z4.w, a2))));
  }
  if (giaddT) {
    a0 += giaddT[j * 64 + b];
    a1 += giaddT[(j + 256) * 64 + b];
    a2 += giaddT[(j + 512) * 64 + b];
  }
  float gr = a0 + bi[j], gz = a1 + bi[j + 256], gn = a2 + bi[j + 512];
  float hr = ghT[j * 64 + b] + bh[j];
  float hz = ghT[(j + 256) * 64 + b] + bh[j + 256];
  float hn = ghT[(j + 512) * 64 + b] + bh[j + 512];
  float rr = 1.f / (1.f + expf(-(gr + hr)));
  float zz = 1.f / (1.f + expf(-(gz + hz)));
  float nn = tanhf(gn + rr * hn);
  float h = hT[j * 64 + b];
  float hnew = (1.f - zz) * nn + zz * h;
  hT[j * 64 + b] = hnew;
  if (xnextT) xnextT[j * 64 + b] = xaddT[j * 64 + b] + hnew;
}

// ---------------- prenet L1+L2 fused, one block per batch row ----------------
__device__ void prenet_fused(const KArgs& A, int b, float* sm) {
  float* fr = sm;          // 400
  float* h1s = sm + 400;   // 256
  int tid = threadIdx.x;
  for (int k = tid; k < 400; k += 256) fr[k] = A.ws[OFF_FRAME + k * 64 + b];
  __syncthreads();
  {
    const float4* wr = (const float4*)(A.p1w + (size_t)tid * 400);
    float a = A.p1b[tid];
#pragma unroll 4
    for (int k4 = 0; k4 < 100; ++k4) {
      float4 w = wr[k4];
      float4 x = *(const float4*)(&fr[k4 * 4]);
      a = fmaf(w.x, x.x, fmaf(w.y, x.y, fmaf(w.z, x.z, fmaf(w.w, x.w, a))));
    }
    h1s[tid] = fmaxf(a, 0.f);
  }
  __syncthreads();
  if (tid < 128) {
    const float4* wr = (const float4*)(A.p2w + (size_t)tid * 256);
    float a = A.p2b[tid];
#pragma unroll 4
    for (int k4 = 0; k4 < 64; ++k4) {
      float4 w = wr[k4];
      float4 x = *(const float4*)(&h1s[k4 * 4]);
      a = fmaf(w.x, x.x, fmaf(w.y, x.y, fmaf(w.z, x.z, fmaf(w.w, x.w, a))));
    }
    A.ws[OFF_PRE + tid * 64 + b] = fmaxf(a, 0.f);
  }
  __syncthreads();
}

// ---------------- attention GRU gates + dW MLP + dV, one block per batch row ----------------
__device__ void att_fused(const KArgs& A, int b, float* sm) {
  float* spre = sm;        // 128
  float* hs = sm + 128;    // 256
  float* g1s = sm + 384;   // 128
  int j = threadIdx.x;
  if (j < 128) spre[j] = A.ws[OFF_PRE + j * 64 + b];
  __syncthreads();
  const float4* w0 = (const float4*)(A.awi + (size_t)j * 896 + 768);
  const float4* w1 = (const float4*)(A.awi + (size_t)(j + 256) * 896 + 768);
  const float4* w2 = (const float4*)(A.awi + (size_t)(j + 512) * 896 + 768);
  float a0 = 0.f, a1 = 0.f, a2 = 0.f;
#pragma unroll 4
  for (int k4 = 0; k4 < 32; ++k4) {
    float4 x = *(const float4*)(&spre[k4 * 4]);
    float4 p = w0[k4], q = w1[k4], s4 = w2[k4];
    a0 = fmaf(x.x,p.x, fmaf(x.y,p.y, fmaf(x.z,p.z, fmaf(x.w,p.w, a0))));
    a1 = fmaf(x.x,q.x, fmaf(x.y,q.y, fmaf(x.z,q.z, fmaf(x.w,q.w, a1))));
    a2 = fmaf(x.x,s4.x, fmaf(x.y,s4.y, fmaf(x.z,s4.z, fmaf(x.w,s4.w, a2))));
  }
  a0 += A.ws[OFF_GICTX + j * 64 + b];
  a1 += A.ws[OFF_GICTX + (j + 256) * 64 + b];
  a2 += A.ws[OFF_GICTX + (j + 512) * 64 + b];
  float gr = a0 + A.abi[j], gz = a1 + A.abi[j + 256], gn = a2 + A.abi[j + 512];
  float hr = A.ws[OFF_GHATT + j * 64 + b] + A.abh[j];
  float hz = A.ws[OFF_GHATT + (j + 256) * 64 + b] + A.abh[j + 256];
  float hn = A.ws[OFF_GHATT + (j + 512) * 64 + b] + A.abh[j + 512];
  float rr = 1.f / (1.f + expf(-(gr + hr)));
  float zz = 1.f / (1.f + expf(-(gz + hz)));
  float nn = tanhf(gn + rr * hn);
  float h = A.ws[OFF_HATT + j * 64 + b];
  float hnew = (1.f - zz) * nn + zz * h;
  A.ws[OFF_HATT + j * 64 + b] = hnew;
  hs[j] = hnew;
  __syncthreads();
  if (j < 128) {
    const float4* wr = (const float4*)(A.dWw + (size_t)j * 256);
    float a = A.dWb[j];
#pragma unroll 4
    for (int k4 = 0; k4 < 64; ++k4) {
      float4 w = wr[k4];
      float4 x = *(const float4*)(&hs[k4 * 4]);
      a = fmaf(w.x, x.x, fmaf(w.y, x.y, fmaf(w.z, x.z, fmaf(w.w, x.w, a))));
    }
    g1s[j] = tanhf(a);
  }
  __syncthreads();
  if (j < 168) {
    const float4* wr = (const float4*)(A.dVw + (size_t)j * 128);
    float a = 0.f;
#pragma unroll 4
    for (int k4 = 0; k4 < 32; ++k4) {
      float4 w = wr[k4];
      float4 x = *(const float4*)(&g1s[k4 * 4]);
      a = fmaf(w.x, x.x, fmaf(w.y, x.y, fmaf(w.z, x.z, fmaf(w.w, x.w, a))));
    }
    A.ws[OFF_GT + j * 64 + b] = a;
  }
  __syncthreads();
}

// ---------------- static conv + prior (reads prev alpha) ----------------
__device__ void conv_fp(const KArgs& A, int item, float* sm) {
  int b = item >> 2, s0 = (item & 3) * 128;
  float* sal = sm;
  float* sdF = sm + 160;
  for (int i = threadIdx.x; i < 148; i += 256) {
    int sg = s0 - 10 + i;
    sal[i] = (sg >= 0 && sg < 512) ? A.ws[OFF_ALPHA + b * 512 + sg] : 0.f;
  }
  for (int i = threadIdx.x; i < 168; i += 256) sdF[i] = A.dFw[i];
  __syncthreads();
  for (int q = threadIdx.x; q < 1024; q += 256) {
    int sl = q >> 3, ch = q & 7;
    float fa = 0.f;
#pragma unroll
    for (int k = 0; k < 21; ++k) fa = fmaf(sdF[ch * 21 + k], sal[sl + k], fa);
    A.ws[OFF_F8 + ((size_t)b * 512 + s0 + sl) * 8 + ch] = fa;
  }
  if (threadIdx.x < 128) {
    int sl = threadIdx.x;
    float p = 0.f;
#pragma unroll
    for (int k = 0; k < 11; ++k) p = fmaf(A.pr.v[k], sal[sl + k], p);
    A.ws[OFF_LOGP + b * 512 + s0 + sl] = logf(fmaxf(p, 1e-6f));
  }
  __syncthreads();
}

// ---------------- dynamic conv + energy MLP ----------------
__device__ void dyn_e(const KArgs& A, float* sm) {
  int b = blockIdx.x >> 2, s0 = (blockIdx.x & 3) * 128;
  float* sal = sm;            // 148 (pad 152)
  float* sG  = sm + 152;      // 168
  float* sfp = sm + 320;      // 1152
  float* sgp = sfp + 1152;    // 1152
  float* sdU = sgp + 1152;    // 1024
  float* sdT = sdU + 1024;    // 1024
  float* sdtb = sdT + 1024;   // 128
  float* sdv = sdtb + 128;    // 128
  float* slp = sdv + 128;     // 128
  float* ses = slp + 128;     // 256
  int tid = threadIdx.x;
  for (int i = tid; i < 148; i += 256) {
    int sg = s0 - 10 + i;
    sal[i] = (sg >= 0 && sg < 512) ? A.ws[OFF_ALPHA + b * 512 + sg] : 0.f;
  }
  for (int i = tid; i < 168; i += 256) sG[i] = A.ws[OFF_GT + i * 64 + b];
  for (int i = tid; i < 1024; i += 256) {
    sdU[i] = A.dUw[i]; sdT[i] = A.dTw[i];
    int sl = i >> 3, ch = i & 7;
    sfp[sl * 9 + ch] = A.ws[OFF_F8 + ((size_t)b * 512 + s0 + sl) * 8 + ch];
  }
  if (tid < 128) {
    sdtb[tid] = A.dTb[tid]; sdv[tid] = A.dvw[tid];
    slp[tid] = A.ws[OFF_LOGP + b * 512 + s0 + tid];
  }
  __syncthreads();
  for (int q = tid; q < 1024; q += 256) {
    int sl = q >> 3, ch = q & 7;
    float ga = 0.f;
#pragma unroll
    for (int k = 0; k < 21; ++k) ga = fmaf(sG[ch * 21 + k], sal[sl + k], ga);
    sgp[sl * 9 + ch] = ga;
  }
  __syncthreads();
  int sl = tid & 127, half = tid >> 7;
  float f0[8], g0[8];
#pragma unroll
  for (int r2 = 0; r2 < 8; ++r2) { f0[r2] = sfp[sl * 9 + r2]; g0[r2] = sgp[sl * 9 + r2]; }
  float acc = 0.f;
  for (int cc = half * 64; cc < half * 64 + 64; ++cc) {
    float a = sdtb[cc];
#pragma unroll
    for (int r2 = 0; r2 < 8; ++r2) a = fmaf(sdU[cc * 8 + r2], f0[r2], fmaf(sdT[cc * 8 + r2], g0[r2], a));
    acc = fmaf(sdv[cc], tanhf(a), acc);
  }
  ses[half * 128 + sl] = acc;
  __syncthreads();
  if (tid < 128)
    A.ws[OFF_E + b * 512 + s0 + tid] = ses[tid] + ses[128 + tid] + slp[tid];
  __syncthreads();
}

// ---------------- softmax + sparse context ----------------
__device__ void softmax_ctx(const KArgs& A, float* sm) {
  int b = blockIdx.x, tid = threadIdx.x;
  float* red = sm;                 // 4 (pad 8)
  int* wc = (int*)(sm + 8);        // 8
  float* lv = sm + 16;             // 512
  short* li = (short*)(sm + 528);  // 512 shorts
  float e0 = A.ws[OFF_E + b * 512 + tid];
  float e1 = A.ws[OFF_E + b * 512 + 256 + tid];
  float m = fmaxf(e0, e1);
  for (int o = 32; o; o >>= 1) m = fmaxf(m, __shfl_xor(m, o));
  int lane = tid & 63, wv = tid >> 6;
  if (lane == 0) red[wv] = m;
  __syncthreads();
  m = fmaxf(fmaxf(red[0], red[1]), fmaxf(red[2], red[3]));
  float p0 = expf(e0 - m), p1 = expf(e1 - m);
  float s = p0 + p1;
  for (int o = 32; o; o >>= 1) s += __shfl_xor(s, o);
  __syncthreads();
  if (lane == 0) red[wv] = s;
  __syncthreads();
  float inv = 1.f / (red[0] + red[1] + red[2] + red[3]);
  float a0 = p0 * inv, a1 = p1 * inv;
  A.ws[OFF_ALPHA + b * 512 + tid] = a0;
  A.ws[OFF_ALPHA + b * 512 + 256 + tid] = a1;
  unsigned long long m0 = __ballot(a0 > EPS_A);
  unsigned long long m1 = __ballot(a1 > EPS_A);
  if (lane == 0) { wc[wv] = (int)__popcll(m0); wc[4 + wv] = (int)__popcll(m1); }
  __syncthreads();
  int base0 = 0;
  for (int w = 0; w < wv; ++w) base0 += wc[w];
  int totalA = wc[0] + wc[1] + wc[2] + wc[3];
  int base1 = totalA;
  for (int w = 0; w < wv; ++w) base1 += wc[4 + w];
  int n = totalA + wc[4] + wc[5] + wc[6] + wc[7];
  unsigned long long below = (1ull << lane) - 1ull;
  if (a0 > EPS_A) { int p = base0 + (int)__popcll(m0 & below); li[p] = (short)tid; lv[p] = a0; }
  if (a1 > EPS_A) { int p = base1 + (int)__popcll(m1 & below); li[p] = (short)(256 + tid); lv[p] = a1; }
  __syncthreads();
  const float* encb = A.enc + (size_t)b * 512 * 768;
  for (int d = tid; d < 768; d += 256) {
    float acc = 0.f;
    for (int i = 0; i < n; ++i) acc = fmaf(lv[i], encb[(size_t)li[i] * 768 + d], acc);
    A.ws[OFF_CTX + d * 64 + b] = acc;
  }
  __syncthreads();
}

// ---------------- the persistent decoder ----------------
__global__ __launch_bounds__(256, 1) void k_decode(KArgs A) {
  __shared__ __align__(16) float sm[16448];
  float* ws = A.ws;
  unsigned* bar = (unsigned*)ws;
  int blk = blockIdx.x;
  unsigned g = 0;

  for (int t = 0; t <= TDEC; ++t) {
    // ---- P0: proj(t-1) || gi_ctx || gh_att || gh1 || gh2 ----
    if (blk < 64) {
      if (t > 0) {
        GemmCfg c{ws + OFF_X3, nullptr, 256, 256, A.prw, 256, 0, A.prb, ws + OFF_FRAME,
                  400, 25, 16, 4, 0, 1, A.dout, t - 1};
        gemm_run(c, blk, sm);
      }
    } else if (t < TDEC) {
      if (blk < 160) {
        GemmCfg c{ws + OFF_CTX, nullptr, 768, 768, A.awi, 896, 0, nullptr, ws + OFF_GICTX,
                  768, 32, 24, 4, 0, 0, nullptr, 0};
        gemm_run(c, blk - 64, sm);
      } else if (blk < 192) {
        GemmCfg c{ws + OFF_HATT, nullptr, 256, 256, A.awh, 256, 0, nullptr, ws + OFF_GHATT,
                  768, 48, 16, 5, 0, 0, nullptr, 0};
        gemm_run(c, blk - 160, sm);
      } else if (blk < 224) {
        GemmCfg c{ws + OFF_H1, nullptr, 256, 256, A.g1wh, 256, 0, nullptr, ws + OFF_GH1,
                  768, 48, 16, 5, 0, 0, nullptr, 0};
        gemm_run(c, blk - 192, sm);
      } else {
        GemmCfg c{ws + OFF_H2, nullptr, 256, 256, A.g2wh, 256, 0, nullptr, ws + OFF_GH2,
                  768, 48, 16, 5, 0, 0, nullptr, 0};
        gemm_run(c, blk - 224, sm);
      }
    }
    if (t == TDEC) break;
    gridbar(bar, ++g);

    // ---- P1: prenet L1+L2 (per-b) || static conv + prior ----
    if (blk < 64) {
      prenet_fused(A, blk, sm);
    } else {
      int rel = blk - 64;
      for (int item = rel; item < 256; item += 192) conv_fp(A, item, sm);
    }
    gridbar(bar, ++g);

    // ---- P2: attention GRU gates + dW + dV (per-b) ----
    if (blk < 64) att_fused(A, blk, sm);
    gridbar(bar, ++g);

    // ---- P3: dynamic conv + energy MLP ----
    dyn_e(A, sm);
    gridbar(bar, ++g);

    // ---- P4: softmax + sparse context ----
    if (blk < 64) softmax_ctx(A, sm);
    gridbar(bar, ++g);

    // ---- P5: x = [ctx; h_att] @ lw + lb ----
    if (blk < 64) {
      GemmCfg c{ws + OFF_CTX, ws + OFF_HATT, 768, 1024, A.lw, 1024, 0, A.lb, ws + OFF_X,
                256, 16, 16, 4, 0, 0, nullptr, 0};
      gemm_run(c, blk, sm);
    }
    gridbar(bar, ++g);

    // ---- P6: GRU1 (striped) -> h1, x2 ----
    if (blk < 64)
      stripe_gru(ws + OFF_X, 256, A.g1wi, 256, 0, nullptr, A.g1bi,
                 ws + OFF_GH1, A.g1bh, ws + OFF_H1, ws + OFF_X, ws + OFF_X2, blk, sm);
    gridbar(bar, ++g);

    // ---- P7: GRU2 (striped) -> h2, x3 ----
    if (blk < 64)
      stripe_gru(ws + OFF_X2, 256, A.g2wi, 256, 0, nullptr, A.g2bi,
                 ws + OFF_GH2, A.g2bh, ws + OFF_H2, ws + OFF_X2, ws + OFF_X3, blk, sm);
    gridbar(bar, ++g);
  }
}

// ---------------- host ----------------
extern "C" void kernel_launch(void* const* d_in, const int* in_sizes, int n_in,
                              void* d_out, int out_size, void* d_ws, size_t ws_size,
                              hipStream_t stream) {
  (void)in_sizes; (void)n_in; (void)out_size; (void)ws_size;
  KArgs A;
  A.enc  = (const float*)d_in[0];
  A.p1w  = (const float*)d_in[1];  A.p1b  = (const float*)d_in[2];
  A.p2w  = (const float*)d_in[3];  A.p2b  = (const float*)d_in[4];
  A.awi  = (const float*)d_in[5];  A.abi  = (const float*)d_in[6];
  A.awh  = (const float*)d_in[7];  A.abh  = (const float*)d_in[8];
  A.dWw  = (const float*)d_in[9];  A.dWb  = (const float*)d_in[10];
  A.dVw  = (const float*)d_in[11]; A.dFw  = (const float*)d_in[12];
  A.dUw  = (const float*)d_in[13]; A.dTw  = (const float*)d_in[14];
  A.dTb  = (const float*)d_in[15]; A.dvw  = (const float*)d_in[16];
  A.lw   = (const float*)d_in[17]; A.lb   = (const float*)d_in[18];
  A.g1wi = (const float*)d_in[19]; A.g1bi = (const float*)d_in[20];
  A.g1wh = (const float*)d_in[21]; A.g1bh = (const float*)d_in[22];
  A.g2wi = (const float*)d_in[23]; A.g2bi = (const float*)d_in[24];
  A.g2wh = (const float*)d_in[25]; A.g2bh = (const float*)d_in[26];
  A.prw  = (const float*)d_in[27]; A.prb  = (const float*)d_in[28];
  A.ws   = (float*)d_ws;
  A.dout = (float*)d_out;

  // beta-binomial prior pmf (n=10, a=0.1, b=0.9), flipped
  {
    double aP = 0.1, bP = 0.9;
    double logB0 = lgamma(aP) + lgamma(bP) - lgamma(aP + bP);
    double pm[11];
    for (int k = 0; k <= 10; ++k) {
      double logC = lgamma(11.0) - lgamma(k + 1.0) - lgamma(11.0 - k);
      double logBt = lgamma(k + aP) + lgamma(10.0 - k + bP) - lgamma(10.0 + aP + bP);
      pm[k] = exp(logC + logBt - logB0);
    }
    for (int k = 0; k < 11; ++k) A.pr.v[k] = (float)pm[10 - k];
  }

  k_init<<<256, 256, 0, stream>>>((float*)d_ws);
  k_decode<<<NB, 256, 0, stream>>>(A);
}

// Round 5
// 145801.208 us; speedup vs baseline: 2.7558x; 1.0062x over previous
//
#include <hip/hip_runtime.h>
#include <cmath>

#define TDEC 250
#define NB 256
#define EPS_A 1e-6f

// ---------------- barrier area (unsigned words) ----------------
// arrive flag for block b at word b*32 (one cacheline each); gen at word 8192.
#define BAR_WORDS 8448

// ---------------- ws float offsets ----------------
#define OFF_CTX    8448                     // ctx_T   [768][64]
#define OFF_HATT   (OFF_CTX   + 49152)      // h_att_T [256][64]
#define OFF_H1     (OFF_HATT  + 16384)      // h1_T    [256][64]
#define OFF_H2     (OFF_H1    + 16384)      // h2_T    [256][64]
#define OFF_FRAME  (OFF_H2    + 16384)      // frame_T [400][64]
#define OFF_ALPHA  (OFF_FRAME + 25600)      // alpha   [64][512]
#define OFF_X      (OFF_ALPHA + 32768)      // x_T     [256][64]
#define OFF_X2     (OFF_X     + 16384)
#define OFF_X3     (OFF_X2    + 16384)
#define OFF_GICTX  (OFF_X3    + 16384)      // gi_ctx_T [768][64]
#define OFF_GHATT  (OFF_GICTX + 49152)      // gh_att_T [768][64]
#define OFF_GH1    (OFF_GHATT + 49152)
#define OFF_GH2    (OFF_GH1   + 49152)
#define OFF_PRE    (OFF_GH2   + 49152)      // pre_T [128][64]
#define OFF_GT     (OFF_PRE   + 8192)       // G_T   [168][64]
#define OFF_F8     (OFF_GT    + 10752)      // f8    [64][512][8]
#define OFF_LOGP   (OFF_F8    + 262144)     // [64][512]
#define OFF_E      (OFF_LOGP  + 32768)      // [64][512]

struct Prior { float v[11]; };

struct KArgs {
  const float *enc;
  const float *p1w,*p1b,*p2w,*p2b;
  const float *awi,*abi,*awh,*abh;
  const float *dWw,*dWb,*dVw,*dFw,*dUw,*dTw,*dTb,*dvw;
  const float *lw,*lb;
  const float *g1wi,*g1bi,*g1wh,*g1bh;
  const float *g2wi,*g2bi,*g2wh,*g2bh;
  const float *prw,*prb;
  float* ws; float* dout;
  Prior pr;
};

// ---------------- MALL-coherent (cache-bypassing) scalar access ----------------
// Agent-scope relaxed atomics compile to global_load/store with sc0/sc1 set:
// they bypass L1/L2 and are coherent at the Infinity Cache per-access, so NO
// cache-wide fence ops (buffer_wbl2 / buffer_inv) are ever needed.
__device__ __forceinline__ float gld(const float* p) {
  return __uint_as_float(__hip_atomic_load((const unsigned*)p, __ATOMIC_RELAXED, __HIP_MEMORY_SCOPE_AGENT));
}
__device__ __forceinline__ void gst(float* p, float v) {
  __hip_atomic_store((unsigned*)p, __float_as_uint(v), __ATOMIC_RELAXED, __HIP_MEMORY_SCOPE_AGENT);
}

// ---------------- init: zero barrier + states + alpha onehot ----------------
__global__ __launch_bounds__(256) void k_init(float* ws) {
  int idx = blockIdx.x * 256 + threadIdx.x;
  int total = OFF_ALPHA + 32768;
  for (int i = idx; i < total; i += gridDim.x * 256) {
    float v = 0.f;
    if (i >= OFF_ALPHA && (((i - OFF_ALPHA) & 511) == 0)) v = 1.f;
    ws[i] = v;
  }
}

// ---------------- flag-tree grid barrier: pure MALL flag traffic, no fences ----
// __syncthreads() drains every wave's vmcnt (bypass stores are then AT the MALL),
// so the flag store ordered after it publishes completed data. Consumers' data
// loads issue after the flag is observed and fetch fresh MALL data (bypass).
__device__ __forceinline__ void gridbar(unsigned* bar, unsigned g) {
  asm volatile("s_waitcnt vmcnt(0)" ::: "memory");
  __syncthreads();
  if (blockIdx.x == NB - 1) {
    int i = threadIdx.x;
    if (i < NB - 1) {
      while (__hip_atomic_load(&bar[i * 32], __ATOMIC_RELAXED, __HIP_MEMORY_SCOPE_AGENT) < g)
        __builtin_amdgcn_s_sleep(1);
    }
    __syncthreads();
    if (threadIdx.x == 0)
      __hip_atomic_store(&bar[8192], g, __ATOMIC_RELAXED, __HIP_MEMORY_SCOPE_AGENT);
  } else {
    if (threadIdx.x == 0) {
      __hip_atomic_store(&bar[blockIdx.x * 32], g, __ATOMIC_RELAXED, __HIP_MEMORY_SCOPE_AGENT);
      while (__hip_atomic_load(&bar[8192], __ATOMIC_RELAXED, __HIP_MEMORY_SCOPE_AGENT) < g)
        __builtin_amdgcn_s_sleep(1);
    }
  }
  __syncthreads();
}

// ---------------- generic tiled GEMM: outT[N][64] = W[N][K] x actT[K][64] ----------------
struct GemmCfg {
  const float* A0; const float* A1; int K0; int K;
  const float* W; int wstr; int wofs;
  const float* bias; float* outT;
  int N, J, jgN, LR, activ;      // activ 0 none, 1 relu, 2 tanh
  int store;                     // 1: also scatter to dout (proj)
  float* dout; int tq;
};

__device__ __forceinline__ void gstore(const GemmCfg& c, int jj, int b, float v) {
  if (c.activ == 1) v = fmaxf(v, 0.f);
  else if (c.activ == 2) v = tanhf(v);
  gst(c.outT + jj * 64 + b, v);
  if (c.store == 1)
    c.dout[(size_t)b * 100000 + (jj / 5) * 1250 + c.tq * 5 + (jj % 5)] = v;
}

__device__ void gemm_run(const GemmCfg& c, int rb, float* sm) {
  int R = 1 << c.LR;
  int jg = rb % c.jgN, rg = rb / c.jgN;
  int r0 = rg * R, j0 = jg * c.J;
  int Kp = c.K + 4;
  for (int idx = threadIdx.x; idx < (c.K << c.LR); idx += 256) {
    int k = idx >> c.LR, r = idx & (R - 1);
    float v = (k < c.K0) ? gld(c.A0 + k * 64 + r0 + r) : gld(c.A1 + (k - c.K0) * 64 + r0 + r);
    sm[r * Kp + k] = v;
  }
  __syncthreads();
  int k4n = c.K >> 2;
  if ((c.J & 1) == 0) {
    int Jh = c.J >> 1;
    int np = Jh << c.LR;
    for (int e = threadIdx.x; e < np; e += 256) {
      int r = e & (R - 1); int q = e >> c.LR;
      int ja = j0 + q, jb = ja + Jh;
      const float4* wa = (const float4*)(c.W + (size_t)ja * c.wstr + c.wofs);
      const float4* wb = (const float4*)(c.W + (size_t)jb * c.wstr + c.wofs);
      const float4* ar = (const float4*)(sm + r * Kp);
      float acca = c.bias ? c.bias[ja] : 0.f;
      float accb = c.bias ? c.bias[jb] : 0.f;
      for (int k4 = 0; k4 < k4n; ++k4) {
        float4 a = ar[k4];
        float4 x = wa[k4], y = wb[k4];
        acca = fmaf(a.x,x.x, fmaf(a.y,x.y, fmaf(a.z,x.z, fmaf(a.w,x.w, acca))));
        accb = fmaf(a.x,y.x, fmaf(a.y,y.y, fmaf(a.z,y.z, fmaf(a.w,y.w, accb))));
      }
      gstore(c, ja, r0 + r, acca);
      gstore(c, jb, r0 + r, accb);
    }
  } else {
    for (int e = threadIdx.x; e < (c.J << c.LR); e += 256) {
      int r = e & (R - 1); int jj = j0 + (e >> c.LR);
      if (jj < c.N) {
        const float4* wa = (const float4*)(c.W + (size_t)jj * c.wstr + c.wofs);
        const float4* ar = (const float4*)(sm + r * Kp);
        float acc = c.bias ? c.bias[jj] : 0.f;
        for (int k4 = 0; k4 < k4n; ++k4) {
          float4 a = ar[k4]; float4 x = wa[k4];
          acc = fmaf(a.x,x.x, fmaf(a.y,x.y, fmaf(a.z,x.z, fmaf(a.w,x.w, acc))));
        }
        gstore(c, jj, r0 + r, acc);
      }
    }
  }
}

// ---------------- striped GRU: block owns 16 gate-triples x 16 batch rows ----------------
__device__ void stripe_gru(const float* actT, int K, const float* W, int wstr, int wofs,
                           const float* giaddT, const float* bi,
                           const float* ghT, const float* bh,
                           float* hT, const float* xaddT, float* xnextT,
                           int rb, float* sm)
{
  int jg = rb & 15, rg = rb >> 4;
  int r0 = rg * 16, j0 = jg * 16;
  int Kp = K + 4;
  for (int idx = threadIdx.x; idx < (K << 4); idx += 256) {
    int k = idx >> 4, r = idx & 15;
    sm[r * Kp + k] = gld(actT + k * 64 + r0 + r);
  }
  __syncthreads();
  int e = threadIdx.x;
  int r = e & 15, q = e >> 4;
  int j = j0 + q, b = r0 + r;
  const float4* w0 = (const float4*)(W + (size_t)j * wstr + wofs);
  const float4* w1 = (const float4*)(W + (size_t)(j + 256) * wstr + wofs);
  const float4* w2 = (const float4*)(W + (size_t)(j + 512) * wstr + wofs);
  const float4* ar = (const float4*)(sm + r * Kp);
  float a0 = 0.f, a1 = 0.f, a2 = 0.f;
  for (int k4 = 0; k4 < (K >> 2); ++k4) {
    float4 a = ar[k4];
    float4 x = w0[k4], y = w1[k4], z4 = w2[k4];
    a0 = fmaf(a.x,x.x, fmaf(a.y,x.y, fmaf(a.z,x.z, fmaf(a.w,x.w, a0))));
    a1 = fmaf(a.x,y.x, fmaf(a.y,y.y, fmaf(a.z,y.z, fmaf(a.w,y.w, a1))));
    a2 = fmaf(a.x,z4.x, fmaf(a.y,z4.y, fmaf(a.z,z4.z, fmaf(a.w,z4.w, a2))));
  }
  if (giaddT) {
    a0 += gld(giaddT + j * 64 + b);
    a1 += gld(giaddT + (j + 256) * 64 + b);
    a2 += gld(giaddT + (j + 512) * 64 + b);
  }
  float gr = a0 + bi[j], gz = a1 + bi[j + 256], gn = a2 + bi[j + 512];
  float hr = gld(ghT + j * 64 + b) + bh[j];
  float hz = gld(ghT + (j + 256) * 64 + b) + bh[j + 256];
  float hn = gld(ghT + (j + 512) * 64 + b) + bh[j + 512];
  float rr = 1.f / (1.f + expf(-(gr + hr)));
  float zz = 1.f / (1.f + expf(-(gz + hz)));
  float nn = tanhf(gn + rr * hn);
  float h = gld(hT + j * 64 + b);
  float hnew = (1.f - zz) * nn + zz * h;
  gst(hT + j * 64 + b, hnew);
  if (xnextT) gst(xnextT + j * 64 + b, gld(xaddT + j * 64 + b) + hnew);
}

// ---------------- prenet L1+L2 fused, one block per batch row ----------------
__device__ void prenet_fused(const KArgs& A, int b, float* sm) {
  float* fr = sm;          // 400
  float* h1s = sm + 400;   // 256
  int tid = threadIdx.x;
  for (int k = tid; k < 400; k += 256) fr[k] = gld(A.ws + OFF_FRAME + k * 64 + b);
  __syncthreads();
  {
    const float4* wr = (const float4*)(A.p1w + (size_t)tid * 400);
    float a = A.p1b[tid];
#pragma unroll 4
    for (int k4 = 0; k4 < 100; ++k4) {
      float4 w = wr[k4];
      float4 x = *(const float4*)(&fr[k4 * 4]);
      a = fmaf(w.x, x.x, fmaf(w.y, x.y, fmaf(w.z, x.z, fmaf(w.w, x.w, a))));
    }
    h1s[tid] = fmaxf(a, 0.f);
  }
  __syncthreads();
  if (tid < 128) {
    const float4* wr = (const float4*)(A.p2w + (size_t)tid * 256);
    float a = A.p2b[tid];
#pragma unroll 4
    for (int k4 = 0; k4 < 64; ++k4) {
      float4 w = wr[k4];
      float4 x = *(const float4*)(&h1s[k4 * 4]);
      a = fmaf(w.x, x.x, fmaf(w.y, x.y, fmaf(w.z, x.z, fmaf(w.w, x.w, a))));
    }
    gst(A.ws + OFF_PRE + tid * 64 + b, fmaxf(a, 0.f));
  }
  __syncthreads();
}

// ---------------- attention GRU gates + dW MLP + dV, one block per batch row ----------------
__device__ void att_fused(const KArgs& A, int b, float* sm) {
  float* spre = sm;        // 128
  float* hs = sm + 128;    // 256
  float* g1s = sm + 384;   // 128
  int j = threadIdx.x;
  if (j < 128) spre[j] = gld(A.ws + OFF_PRE + j * 64 + b);
  __syncthreads();
  const float4* w0 = (const float4*)(A.awi + (size_t)j * 896 + 768);
  const float4* w1 = (const float4*)(A.awi + (size_t)(j + 256) * 896 + 768);
  const float4* w2 = (const float4*)(A.awi + (size_t)(j + 512) * 896 + 768);
  float a0 = 0.f, a1 = 0.f, a2 = 0.f;
#pragma unroll 4
  for (int k4 = 0; k4 < 32; ++k4) {
    float4 x = *(const float4*)(&spre[k4 * 4]);
    float4 p = w0[k4], q = w1[k4], s4 = w2[k4];
    a0 = fmaf(x.x,p.x, fmaf(x.y,p.y, fmaf(x.z,p.z, fmaf(x.w,p.w, a0))));
    a1 = fmaf(x.x,q.x, fmaf(x.y,q.y, fmaf(x.z,q.z, fmaf(x.w,q.w, a1))));
    a2 = fmaf(x.x,s4.x, fmaf(x.y,s4.y, fmaf(x.z,s4.z, fmaf(x.w,s4.w, a2))));
  }
  a0 += gld(A.ws + OFF_GICTX + j * 64 + b);
  a1 += gld(A.ws + OFF_GICTX + (j + 256) * 64 + b);
  a2 += gld(A.ws + OFF_GICTX + (j + 512) * 64 + b);
  float gr = a0 + A.abi[j], gz = a1 + A.abi[j + 256], gn = a2 + A.abi[j + 512];
  float hr = gld(A.ws + OFF_GHATT + j * 64 + b) + A.abh[j];
  float hz = gld(A.ws + OFF_GHATT + (j + 256) * 64 + b) + A.abh[j + 256];
  float hn = gld(A.ws + OFF_GHATT + (j + 512) * 64 + b) + A.abh[j + 512];
  float rr = 1.f / (1.f + expf(-(gr + hr)));
  float zz = 1.f / (1.f + expf(-(gz + hz)));
  float nn = tanhf(gn + rr * hn);
  float h = gld(A.ws + OFF_HATT + j * 64 + b);
  float hnew = (1.f - zz) * nn + zz * h;
  gst(A.ws + OFF_HATT + j * 64 + b, hnew);
  hs[j] = hnew;
  __syncthreads();
  if (j < 128) {
    const float4* wr = (const float4*)(A.dWw + (size_t)j * 256);
    float a = A.dWb[j];
#pragma unroll 4
    for (int k4 = 0; k4 < 64; ++k4) {
      float4 w = wr[k4];
      float4 x = *(const float4*)(&hs[k4 * 4]);
      a = fmaf(w.x, x.x, fmaf(w.y, x.y, fmaf(w.z, x.z, fmaf(w.w, x.w, a))));
    }
    g1s[j] = tanhf(a);
  }
  __syncthreads();
  if (j < 168) {
    const float4* wr = (const float4*)(A.dVw + (size_t)j * 128);
    float a = 0.f;
#pragma unroll 4
    for (int k4 = 0; k4 < 32; ++k4) {
      float4 w = wr[k4];
      float4 x = *(const float4*)(&g1s[k4 * 4]);
      a = fmaf(w.x, x.x, fmaf(w.y, x.y, fmaf(w.z, x.z, fmaf(w.w, x.w, a))));
    }
    gst(A.ws + OFF_GT + j * 64 + b, a);
  }
  __syncthreads();
}

// ---------------- static conv + prior (reads prev alpha) ----------------
__device__ void conv_fp(const KArgs& A, int item, float* sm) {
  int b = item >> 2, s0 = (item & 3) * 128;
  float* sal = sm;
  float* sdF = sm + 160;
  for (int i = threadIdx.x; i < 148; i += 256) {
    int sg = s0 - 10 + i;
    sal[i] = (sg >= 0 && sg < 512) ? gld(A.ws + OFF_ALPHA + b * 512 + sg) : 0.f;
  }
  for (int i = threadIdx.x; i < 168; i += 256) sdF[i] = A.dFw[i];
  __syncthreads();
  for (int q = threadIdx.x; q < 1024; q += 256) {
    int sl = q >> 3, ch = q & 7;
    float fa = 0.f;
#pragma unroll
    for (int k = 0; k < 21; ++k) fa = fmaf(sdF[ch * 21 + k], sal[sl + k], fa);
    gst(A.ws + OFF_F8 + ((size_t)b * 512 + s0 + sl) * 8 + ch, fa);
  }
  if (threadIdx.x < 128) {
    int sl = threadIdx.x;
    float p = 0.f;
#pragma unroll
    for (int k = 0; k < 11; ++k) p = fmaf(A.pr.v[k], sal[sl + k], p);
    gst(A.ws + OFF_LOGP + b * 512 + s0 + sl, logf(fmaxf(p, 1e-6f)));
  }
  __syncthreads();
}

// ---------------- dynamic conv + energy MLP ----------------
__device__ void dyn_e(const KArgs& A, float* sm) {
  int b = blockIdx.x >> 2, s0 = (blockIdx.x & 3) * 128;
  float* sal = sm;            // 148 (pad 152)
  float* sG  = sm + 152;      // 168
  float* sfp = sm + 320;      // 1152
  float* sgp = sfp + 1152;    // 1152
  float* sdU = sgp + 1152;    // 1024
  float* sdT = sdU + 1024;    // 1024
  float* sdtb = sdT + 1024;   // 128
  float* sdv = sdtb + 128;    // 128
  float* slp = sdv + 128;     // 128
  float* ses = slp + 128;     // 256
  int tid = threadIdx.x;
  for (int i = tid; i < 148; i += 256) {
    int sg = s0 - 10 + i;
    sal[i] = (sg >= 0 && sg < 512) ? gld(A.ws + OFF_ALPHA + b * 512 + sg) : 0.f;
  }
  for (int i = tid; i < 168; i += 256) sG[i] = gld(A.ws + OFF_GT + i * 64 + b);
  for (int i = tid; i < 1024; i += 256) {
    sdU[i] = A.dUw[i]; sdT[i] = A.dTw[i];
    int sl = i >> 3, ch = i & 7;
    sfp[sl * 9 + ch] = gld(A.ws + OFF_F8 + ((size_t)b * 512 + s0 + sl) * 8 + ch);
  }
  if (tid < 128) {
    sdtb[tid] = A.dTb[tid]; sdv[tid] = A.dvw[tid];
    slp[tid] = gld(A.ws + OFF_LOGP + b * 512 + s0 + tid);
  }
  __syncthreads();
  for (int q = tid; q < 1024; q += 256) {
    int sl = q >> 3, ch = q & 7;
    float ga = 0.f;
#pragma unroll
    for (int k = 0; k < 21; ++k) ga = fmaf(sG[ch * 21 + k], sal[sl + k], ga);
    sgp[sl * 9 + ch] = ga;
  }
  __syncthreads();
  int sl = tid & 127, half = tid >> 7;
  float f0[8], g0[8];
#pragma unroll
  for (int r2 = 0; r2 < 8; ++r2) { f0[r2] = sfp[sl * 9 + r2]; g0[r2] = sgp[sl * 9 + r2]; }
  float acc = 0.f;
  for (int cc = half * 64; cc < half * 64 + 64; ++cc) {
    float a = sdtb[cc];
#pragma unroll
    for (int r2 = 0; r2 < 8; ++r2) a = fmaf(sdU[cc * 8 + r2], f0[r2], fmaf(sdT[cc * 8 + r2], g0[r2], a));
    acc = fmaf(sdv[cc], tanhf(a), acc);
  }
  ses[half * 128 + sl] = acc;
  __syncthreads();
  if (tid < 128)
    gst(A.ws + OFF_E + b * 512 + s0 + tid, ses[tid] + ses[128 + tid] + slp[tid]);
  __syncthreads();
}

// ---------------- softmax + sparse context ----------------
__device__ void softmax_ctx(const KArgs& A, float* sm) {
  int b = blockIdx.x, tid = threadIdx.x;
  float* red = sm;                 // 4 (pad 8)
  int* wc = (int*)(sm + 8);        // 8
  float* lv = sm + 16;             // 512
  short* li = (short*)(sm + 528);  // 512 shorts
  float e0 = gld(A.ws + OFF_E + b * 512 + tid);
  float e1 = gld(A.ws + OFF_E + b * 512 + 256 + tid);
  float m = fmaxf(e0, e1);
  for (int o = 32; o; o >>= 1) m = fmaxf(m, __shfl_xor(m, o));
  int lane = tid & 63, wv = tid >> 6;
  if (lane == 0) red[wv] = m;
  __syncthreads();
  m = fmaxf(fmaxf(red[0], red[1]), fmaxf(red[2], red[3]));
  float p0 = expf(e0 - m), p1 = expf(e1 - m);
  float s = p0 + p1;
  for (int o = 32; o; o >>= 1) s += __shfl_xor(s, o);
  __syncthreads();
  if (lane == 0) red[wv] = s;
  __syncthreads();
  float inv = 1.f / (red[0] + red[1] + red[2] + red[3]);
  float a0 = p0 * inv, a1 = p1 * inv;
  gst(A.ws + OFF_ALPHA + b * 512 + tid, a0);
  gst(A.ws + OFF_ALPHA + b * 512 + 256 + tid, a1);
  unsigned long long m0 = __ballot(a0 > EPS_A);
  unsigned long long m1 = __ballot(a1 > EPS_A);
  if (lane == 0) { wc[wv] = (int)__popcll(m0); wc[4 + wv] = (int)__popcll(m1); }
  __syncthreads();
  int base0 = 0;
  for (int w = 0; w < wv; ++w) base0 += wc[w];
  int totalA = wc[0] + wc[1] + wc[2] + wc[3];
  int base1 = totalA;
  for (int w = 0; w < wv; ++w) base1 += wc[4 + w];
  int n = totalA + wc[4] + wc[5] + wc[6] + wc[7];
  unsigned long long below = (1ull << lane) - 1ull;
  if (a0 > EPS_A) { int p = base0 + (int)__popcll(m0 & below); li[p] = (short)tid; lv[p] = a0; }
  if (a1 > EPS_A) { int p = base1 + (int)__popcll(m1 & below); li[p] = (short)(256 + tid); lv[p] = a1; }
  __syncthreads();
  const float* encb = A.enc + (size_t)b * 512 * 768;
  for (int d = tid; d < 768; d += 256) {
    float acc = 0.f;
    for (int i = 0; i < n; ++i) acc = fmaf(lv[i], encb[(size_t)li[i] * 768 + d], acc);
    gst(A.ws + OFF_CTX + d * 64 + b, acc);
  }
  __syncthreads();
}

// ---------------- the persistent decoder ----------------
__global__ __launch_bounds__(256, 1) void k_decode(KArgs A) {
  __shared__ __align__(16) float sm[16448];
  float* ws = A.ws;
  unsigned* bar = (unsigned*)ws;
  int blk = blockIdx.x;
  unsigned g = 0;

  for (int t = 0; t <= TDEC; ++t) {
    // ---- P0: proj(t-1) || gi_ctx || gh_att || gh1 || gh2 ----
    if (blk < 64) {
      if (t > 0) {
        GemmCfg c{ws + OFF_X3, nullptr, 256, 256, A.prw, 256, 0, A.prb, ws + OFF_FRAME,
                  400, 25, 16, 4, 0, 1, A.dout, t - 1};
        gemm_run(c, blk, sm);
      }
    } else if (t < TDEC) {
      if (blk < 160) {
        GemmCfg c{ws + OFF_CTX, nullptr, 768, 768, A.awi, 896, 0, nullptr, ws + OFF_GICTX,
                  768, 32, 24, 4, 0, 0, nullptr, 0};
        gemm_run(c, blk - 64, sm);
      } else if (blk < 192) {
        GemmCfg c{ws + OFF_HATT, nullptr, 256, 256, A.awh, 256, 0, nullptr, ws + OFF_GHATT,
                  768, 48, 16, 5, 0, 0, nullptr, 0};
        gemm_run(c, blk - 160, sm);
      } else if (blk < 224) {
        GemmCfg c{ws + OFF_H1, nullptr, 256, 256, A.g1wh, 256, 0, nullptr, ws + OFF_GH1,
                  768, 48, 16, 5, 0, 0, nullptr, 0};
        gemm_run(c, blk - 192, sm);
      } else {
        GemmCfg c{ws + OFF_H2, nullptr, 256, 256, A.g2wh, 256, 0, nullptr, ws + OFF_GH2,
                  768, 48, 16, 5, 0, 0, nullptr, 0};
        gemm_run(c, blk - 224, sm);
      }
    }
    if (t == TDEC) break;
    gridbar(bar, ++g);

    // ---- P1: prenet L1+L2 (per-b) || static conv + prior ----
    if (blk < 64) {
      prenet_fused(A, blk, sm);
    } else {
      int rel = blk - 64;
      for (int item = rel; item < 256; item += 192) conv_fp(A, item, sm);
    }
    gridbar(bar, ++g);

    // ---- P2: attention GRU gates + dW + dV (per-b) ----
    if (blk < 64) att_fused(A, blk, sm);
    gridbar(bar, ++g);

    // ---- P3: dynamic conv + energy MLP ----
    dyn_e(A, sm);
    gridbar(bar, ++g);

    // ---- P4: softmax + sparse context ----
    if (blk < 64) softmax_ctx(A, sm);
    gridbar(bar, ++g);

    // ---- P5: x = [ctx; h_att] @ lw + lb ----
    if (blk < 64) {
      GemmCfg c{ws + OFF_CTX, ws + OFF_HATT, 768, 1024, A.lw, 1024, 0, A.lb, ws + OFF_X,
                256, 16, 16, 4, 0, 0, nullptr, 0};
      gemm_run(c, blk, sm);
    }
    gridbar(bar, ++g);

    // ---- P6: GRU1 (striped) -> h1, x2 ----
    if (blk < 64)
      stripe_gru(ws + OFF_X, 256, A.g1wi, 256, 0, nullptr, A.g1bi,
                 ws + OFF_GH1, A.g1bh, ws + OFF_H1, ws + OFF_X, ws + OFF_X2, blk, sm);
    gridbar(bar, ++g);

    // ---- P7: GRU2 (striped) -> h2, x3 ----
    if (blk < 64)
      stripe_gru(ws + OFF_X2, 256, A.g2wi, 256, 0, nullptr, A.g2bi,
                 ws + OFF_GH2, A.g2bh, ws + OFF_H2, ws + OFF_X2, ws + OFF_X3, blk, sm);
    gridbar(bar, ++g);
  }
}

// ---------------- host ----------------
extern "C" void kernel_launch(void* const* d_in, const int* in_sizes, int n_in,
                              void* d_out, int out_size, void* d_ws, size_t ws_size,
                              hipStream_t stream) {
  (void)in_sizes; (void)n_in; (void)out_size; (void)ws_size;
  KArgs A;
  A.enc  = (const float*)d_in[0];
  A.p1w  = (const float*)d_in[1];  A.p1b  = (const float*)d_in[2];
  A.p2w  = (const float*)d_in[3];  A.p2b  = (const float*)d_in[4];
  A.awi  = (const float*)d_in[5];  A.abi  = (const float*)d_in[6];
  A.awh  = (const float*)d_in[7];  A.abh  = (const float*)d_in[8];
  A.dWw  = (const float*)d_in[9];  A.dWb  = (const float*)d_in[10];
  A.dVw  = (const float*)d_in[11]; A.dFw  = (const float*)d_in[12];
  A.dUw  = (const float*)d_in[13]; A.dTw  = (const float*)d_in[14];
  A.dTb  = (const float*)d_in[15]; A.dvw  = (const float*)d_in[16];
  A.lw   = (const float*)d_in[17]; A.lb   = (const float*)d_in[18];
  A.g1wi = (const float*)d_in[19]; A.g1bi = (const float*)d_in[20];
  A.g1wh = (const float*)d_in[21]; A.g1bh = (const float*)d_in[22];
  A.g2wi = (const float*)d_in[23]; A.g2bi = (const float*)d_in[24];
  A.g2wh = (const float*)d_in[25]; A.g2bh = (const float*)d_in[26];
  A.prw  = (const float*)d_in[27]; A.prb  = (const float*)d_in[28];
  A.ws   = (float*)d_ws;
  A.dout = (float*)d_out;

  // beta-binomial prior pmf (n=10, a=0.1, b=0.9), flipped
  {
    double aP = 0.1, bP = 0.9;
    double logB0 = lgamma(aP) + lgamma(bP) - lgamma(aP + bP);
    double pm[11];
    for (int k = 0; k <= 10; ++k) {
      double logC = lgamma(11.0) - lgamma(k + 1.0) - lgamma(11.0 - k);
      double logBt = lgamma(k + aP) + lgamma(10.0 - k + bP) - lgamma(10.0 + aP + bP);
      pm[k] = exp(logC + logBt - logB0);
    }
    for (int k = 0; k < 11; ++k) A.pr.v[k] = (float)pm[10 - k];
  }

  k_init<<<256, 256, 0, stream>>>((float*)d_ws);
  k_decode<<<NB, 256, 0, stream>>>(A);
}

// Round 6
// 85808.936 us; speedup vs baseline: 4.6826x; 1.6991x over previous
//
#include <hip/hip_runtime.h>
#include <cmath>

#define TDEC 250
#define NB 256
#define EPS_A 1e-6f
#define CHUNK 128

// ---------------- ws float offsets ----------------
// barrier: flag for block b at word b*32; gen at word 8192. (floats 0..8447)
#define OFF_CTX    8448                     // ctx_T   [768][64]
#define OFF_HATT   (OFF_CTX   + 49152)      // h_att_T [256][64]
#define OFF_H1     (OFF_HATT  + 16384)
#define OFF_H2     (OFF_H1    + 16384)
#define OFF_FRAME  (OFF_H2    + 16384)      // frame_T [400][64]
#define OFF_ALPHA  (OFF_FRAME + 25600)      // alpha   [64][512]
#define OFF_X      (OFF_ALPHA + 32768)      // x_T     [256][64]
#define OFF_X2     (OFF_X     + 16384)
#define OFF_X3     (OFF_X2    + 16384)
#define OFF_GICTX  (OFF_X3    + 16384)      // gi_ctx_T [768][64]
#define OFF_GHATT  (OFF_GICTX + 49152)
#define OFF_GH1    (OFF_GHATT + 49152)
#define OFF_GH2    (OFF_GH1   + 49152)
#define OFF_PRE    (OFF_GH2   + 49152)      // pre_T [128][64]
#define OFF_GT     (OFF_PRE   + 8192)       // G_T   [168][64]
#define OFF_F8     (OFF_GT    + 10752)      // f8    [64][512][8]
#define OFF_LOGP   (OFF_F8    + 262144)     // [64][512]
#define OFF_E      (OFF_LOGP  + 32768)      // [64][512]
#define OFF_H1S    (OFF_E     + 32768)      // h1s_T [256][64]
#define OFF_T1     (OFF_H1S   + 16384)      // t1_T  [128][64]

struct Prior { float v[11]; };

struct KArgs {
  const float *enc;
  const float *p1w,*p1b,*p2w,*p2b;
  const float *awi,*abi,*awh,*abh;
  const float *dWw,*dWb,*dVw,*dFw,*dUw,*dTw,*dTb,*dvw;
  const float *lw,*lb;
  const float *g1wi,*g1bi,*g1wh,*g1bh;
  const float *g2wi,*g2bi,*g2wh,*g2bh;
  const float *prw,*prb;
  float* ws; float* dout;
  Prior pr;
};

// ---------------- MALL-coherent (cache-bypassing) scalar access ----------------
__device__ __forceinline__ float gld(const float* p) {
  return __uint_as_float(__hip_atomic_load((const unsigned*)p, __ATOMIC_RELAXED, __HIP_MEMORY_SCOPE_AGENT));
}
__device__ __forceinline__ void gst(float* p, float v) {
  __hip_atomic_store((unsigned*)p, __float_as_uint(v), __ATOMIC_RELAXED, __HIP_MEMORY_SCOPE_AGENT);
}

// ---------------- init ----------------
__global__ __launch_bounds__(256) void k_init(float* ws) {
  int idx = blockIdx.x * 256 + threadIdx.x;
  int total = OFF_ALPHA + 32768;
  for (int i = idx; i < total; i += gridDim.x * 256) {
    float v = 0.f;
    if (i >= OFF_ALPHA && (((i - OFF_ALPHA) & 511) == 0)) v = 1.f;
    ws[i] = v;
  }
}

// ---------------- flag-tree grid barrier (relaxed polls, no cache maintenance) --
__device__ __forceinline__ void gridbar(unsigned* bar, unsigned g) {
  asm volatile("s_waitcnt vmcnt(0)" ::: "memory");
  __syncthreads();
  if (blockIdx.x == NB - 1) {
    int i = threadIdx.x;
    if (i < NB - 1) {
      while (__hip_atomic_load(&bar[i * 32], __ATOMIC_RELAXED, __HIP_MEMORY_SCOPE_AGENT) < g)
        __builtin_amdgcn_s_sleep(1);
    }
    __syncthreads();
    if (threadIdx.x == 0)
      __hip_atomic_store(&bar[8192], g, __ATOMIC_RELAXED, __HIP_MEMORY_SCOPE_AGENT);
  } else {
    if (threadIdx.x == 0) {
      __hip_atomic_store(&bar[blockIdx.x * 32], g, __ATOMIC_RELAXED, __HIP_MEMORY_SCOPE_AGENT);
      while (__hip_atomic_load(&bar[8192], __ATOMIC_RELAXED, __HIP_MEMORY_SCOPE_AGENT) < g)
        __builtin_amdgcn_s_sleep(1);
    }
  }
  __syncthreads();
}

// ---------------- generic chunked GEMM: outT[N][64] = W[N][K] @ actT[K][64] ------
// 1024 threads. thread -> (jq = tid>>LR, r = tid&(R-1)); nout = (J<<LR)/1024 outputs.
struct GemmCfg {
  const float* A0; const float* A1; int K0; int K;
  const float* W; int wstr; int wofs;
  const float* bias; float* outT;
  int N, J, jgN, LR, activ;   // activ 0 none, 1 relu, 2 tanh
  int store; float* dout; int tq;
};

__device__ void gemm_run(const GemmCfg& c, int rb, float* sm) {
  const int R = 1 << c.LR;
  const int jg = rb % c.jgN, rg = rb / c.jgN;
  const int r0 = rg * R, j0 = jg * c.J;
  const int Kp = CHUNK + 4;
  const int tid = threadIdx.x;
  const int r = tid & (R - 1);
  const int jq = tid >> c.LR;
  const int jstep = 1024 >> c.LR;
  const int nout = (c.J << c.LR) >> 10;   // 1 or 2
  float acc[2];
#pragma unroll
  for (int o = 0; o < 2; ++o) {
    int jj = j0 + jq + o * jstep;
    acc[o] = (c.bias && jj < c.N) ? c.bias[jj] : 0.f;
  }
  for (int kc = 0; kc < c.K; kc += CHUNK) {
    const int cl = min(CHUNK, c.K - kc);
    __syncthreads();
    for (int idx = tid; idx < (cl << c.LR); idx += 1024) {
      int k = idx >> c.LR, rr = idx & (R - 1);
      int kk = kc + k;
      float v = (kk < c.K0) ? gld(c.A0 + kk * 64 + r0 + rr)
                            : gld(c.A1 + (kk - c.K0) * 64 + r0 + rr);
      sm[rr * Kp + k] = v;
    }
    __syncthreads();
    const float4* ar = (const float4*)(sm + r * Kp);
    for (int o = 0; o < nout; ++o) {
      int jj = j0 + jq + o * jstep;
      if (jj < c.N) {
        const float4* wr = (const float4*)(c.W + (size_t)jj * c.wstr + c.wofs + kc);
        float a = acc[o];
#pragma unroll 8
        for (int k4 = 0; k4 < (cl >> 2); ++k4) {
          float4 av = ar[k4]; float4 wv = wr[k4];
          a = fmaf(av.x,wv.x, fmaf(av.y,wv.y, fmaf(av.z,wv.z, fmaf(av.w,wv.w, a))));
        }
        acc[o] = a;
      }
    }
  }
  for (int o = 0; o < nout; ++o) {
    int jj = j0 + jq + o * jstep;
    if (jj < c.N) {
      float v = acc[o];
      if (c.activ == 1) v = fmaxf(v, 0.f);
      else if (c.activ == 2) v = tanhf(v);
      gst(c.outT + jj * 64 + r0 + r, v);
      if (c.store)
        c.dout[(size_t)(r0 + r) * 100000 + (jj / 5) * 1250 + c.tq * 5 + (jj % 5)] = v;
    }
  }
}

// ---------------- attention gate stripe: 16 blocks, thread=(j16, r64) ----------
__device__ void att_stripe(const KArgs& A, int rb, float* sm) {
  const int j = rb * 16 + (threadIdx.x >> 6);
  const int r = threadIdx.x & 63;
  const int Kp = CHUNK + 4;
  for (int idx = threadIdx.x; idx < 128 * 64; idx += 1024) {
    int k = idx >> 6, rr = idx & 63;
    sm[rr * Kp + k] = gld(A.ws + OFF_PRE + k * 64 + rr);
  }
  __syncthreads();
  const float4* ar = (const float4*)(sm + r * Kp);
  const float4* w0 = (const float4*)(A.awi + (size_t)j * 896 + 768);
  const float4* w1 = (const float4*)(A.awi + (size_t)(j + 256) * 896 + 768);
  const float4* w2 = (const float4*)(A.awi + (size_t)(j + 512) * 896 + 768);
  float a0 = 0.f, a1 = 0.f, a2 = 0.f;
#pragma unroll 4
  for (int k4 = 0; k4 < 32; ++k4) {
    float4 av = ar[k4];
    float4 x = w0[k4], y = w1[k4], z4 = w2[k4];
    a0 = fmaf(av.x,x.x, fmaf(av.y,x.y, fmaf(av.z,x.z, fmaf(av.w,x.w, a0))));
    a1 = fmaf(av.x,y.x, fmaf(av.y,y.y, fmaf(av.z,y.z, fmaf(av.w,y.w, a1))));
    a2 = fmaf(av.x,z4.x, fmaf(av.y,z4.y, fmaf(av.z,z4.z, fmaf(av.w,z4.w, a2))));
  }
  a0 += gld(A.ws + OFF_GICTX + j * 64 + r);
  a1 += gld(A.ws + OFF_GICTX + (j + 256) * 64 + r);
  a2 += gld(A.ws + OFF_GICTX + (j + 512) * 64 + r);
  float gr = a0 + A.abi[j], gz = a1 + A.abi[j + 256], gn = a2 + A.abi[j + 512];
  float hr = gld(A.ws + OFF_GHATT + j * 64 + r) + A.abh[j];
  float hz = gld(A.ws + OFF_GHATT + (j + 256) * 64 + r) + A.abh[j + 256];
  float hn = gld(A.ws + OFF_GHATT + (j + 512) * 64 + r) + A.abh[j + 512];
  float rr2 = 1.f / (1.f + expf(-(gr + hr)));
  float zz = 1.f / (1.f + expf(-(gz + hz)));
  float nn = tanhf(gn + rr2 * hn);
  float h = gld(A.ws + OFF_HATT + j * 64 + r);
  gst(A.ws + OFF_HATT + j * 64 + r, (1.f - zz) * nn + zz * h);
}

// ---------------- decoder GRU stripe: 16 blocks, thread=(j16, r64) -------------
__device__ void gru_stripe(const KArgs& A, const float* xT, const float* W,
                           const float* bi, const float* ghT, const float* bh,
                           float* hT, const float* xaddT, float* xnextT,
                           int rb, float* sm) {
  const int j = rb * 16 + (threadIdx.x >> 6);
  const int r = threadIdx.x & 63;
  const int Kp = CHUNK + 4;
  float a0 = 0.f, a1 = 0.f, a2 = 0.f;
  for (int kc = 0; kc < 256; kc += CHUNK) {
    __syncthreads();
    for (int idx = threadIdx.x; idx < 128 * 64; idx += 1024) {
      int k = idx >> 6, rr = idx & 63;
      sm[rr * Kp + k] = gld(xT + (kc + k) * 64 + rr);
    }
    __syncthreads();
    const float4* ar = (const float4*)(sm + r * Kp);
    const float4* w0 = (const float4*)(W + (size_t)j * 256 + kc);
    const float4* w1 = (const float4*)(W + (size_t)(j + 256) * 256 + kc);
    const float4* w2 = (const float4*)(W + (size_t)(j + 512) * 256 + kc);
#pragma unroll 4
    for (int k4 = 0; k4 < 32; ++k4) {
      float4 av = ar[k4];
      float4 x = w0[k4], y = w1[k4], z4 = w2[k4];
      a0 = fmaf(av.x,x.x, fmaf(av.y,x.y, fmaf(av.z,x.z, fmaf(av.w,x.w, a0))));
      a1 = fmaf(av.x,y.x, fmaf(av.y,y.y, fmaf(av.z,y.z, fmaf(av.w,y.w, a1))));
      a2 = fmaf(av.x,z4.x, fmaf(av.y,z4.y, fmaf(av.z,z4.z, fmaf(av.w,z4.w, a2))));
    }
  }
  float gr = a0 + bi[j], gz = a1 + bi[j + 256], gn = a2 + bi[j + 512];
  float hr = gld(ghT + j * 64 + r) + bh[j];
  float hz = gld(ghT + (j + 256) * 64 + r) + bh[j + 256];
  float hn = gld(ghT + (j + 512) * 64 + r) + bh[j + 512];
  float rr2 = 1.f / (1.f + expf(-(gr + hr)));
  float zz = 1.f / (1.f + expf(-(gz + hz)));
  float nn = tanhf(gn + rr2 * hn);
  float h = gld(hT + j * 64 + r);
  float hnew = (1.f - zz) * nn + zz * h;
  gst(hT + j * 64 + r, hnew);
  gst(xnextT + j * 64 + r, gld(xaddT + j * 64 + r) + hnew);
}

// ---------------- static conv + prior: 64 blocks (one per b) -------------------
__device__ void conv_fp(const KArgs& A, int b, float* sm) {
  float* sal = sm;          // 522 (pad 544)
  float* sdF = sm + 544;    // 168
  int tid = threadIdx.x;
  for (int i = tid; i < 522; i += 1024) {
    int sg = i - 10;
    sal[i] = (sg >= 0 && sg < 512) ? gld(A.ws + OFF_ALPHA + b * 512 + sg) : 0.f;
  }
  if (tid < 168) sdF[tid] = A.dFw[tid];
  __syncthreads();
  for (int q = tid; q < 4096; q += 1024) {
    int sl = q >> 3, ch = q & 7;
    float fa = 0.f;
#pragma unroll
    for (int k = 0; k < 21; ++k) fa = fmaf(sdF[ch * 21 + k], sal[sl + k], fa);
    gst(A.ws + OFF_F8 + ((size_t)b * 512 + sl) * 8 + ch, fa);
  }
  for (int sl = tid; sl < 512; sl += 1024) {
    float p = 0.f;
#pragma unroll
    for (int k = 0; k < 11; ++k) p = fmaf(A.pr.v[k], sal[sl + k], p);
    gst(A.ws + OFF_LOGP + b * 512 + sl, logf(fmaxf(p, 1e-6f)));
  }
}

// ---------------- dynamic conv + energy MLP: 256 blocks (b x 4 s-chunks) --------
__device__ void dyn_e(const KArgs& A, float* sm) {
  int b = blockIdx.x >> 2, s0 = (blockIdx.x & 3) * 128;
  float* sal = sm;            // 148 (pad 152)
  float* sG  = sm + 152;      // 168 (pad 172)
  float* sfp = sm + 324;      // 1152
  float* sgp = sm + 1476;     // 1152
  float* sdU = sm + 2628;     // 1024
  float* sdT = sm + 3652;     // 1024
  float* sdtb= sm + 4676;     // 128
  float* sdv = sm + 4804;     // 128
  float* slp = sm + 4932;     // 128
  float* ses = sm + 5060;     // 1024
  int tid = threadIdx.x;
  if (tid < 148) {
    int sg = s0 - 10 + tid;
    sal[tid] = (sg >= 0 && sg < 512) ? gld(A.ws + OFF_ALPHA + b * 512 + sg) : 0.f;
  }
  if (tid >= 256 && tid < 424) sG[tid - 256] = gld(A.ws + OFF_GT + (tid - 256) * 64 + b);
  sdU[tid] = A.dUw[tid];
  sdT[tid] = A.dTw[tid];
  if (tid >= 512 && tid < 640) sdtb[tid - 512] = A.dTb[tid - 512];
  if (tid >= 640 && tid < 768) sdv[tid - 640] = A.dvw[tid - 640];
  if (tid >= 768 && tid < 896) slp[tid - 768] = gld(A.ws + OFF_LOGP + b * 512 + s0 + tid - 768);
  {
    int sl = tid >> 3, ch = tid & 7;
    sfp[sl * 9 + ch] = gld(A.ws + OFF_F8 + ((size_t)b * 512 + s0 + sl) * 8 + ch);
  }
  __syncthreads();
  {
    int sl = tid >> 3, ch = tid & 7;
    float ga = 0.f;
#pragma unroll
    for (int k = 0; k < 21; ++k) ga = fmaf(sG[ch * 21 + k], sal[sl + k], ga);
    sgp[sl * 9 + ch] = ga;
  }
  __syncthreads();
  {
    int sl = tid & 127, cq = tid >> 7;   // cq 0..7, 16 c's each
    float f0[8], g0[8];
#pragma unroll
    for (int q = 0; q < 8; ++q) { f0[q] = sfp[sl * 9 + q]; g0[q] = sgp[sl * 9 + q]; }
    float acc = 0.f;
    for (int cc = cq * 16; cc < cq * 16 + 16; ++cc) {
      float a = sdtb[cc];
#pragma unroll
      for (int q = 0; q < 8; ++q) a = fmaf(sdU[cc * 8 + q], f0[q], fmaf(sdT[cc * 8 + q], g0[q], a));
      acc = fmaf(sdv[cc], tanhf(a), acc);
    }
    ses[cq * 128 + sl] = acc;
  }
  __syncthreads();
  if (tid < 128) {
    float e = ses[tid];
    for (int w = 1; w < 8; ++w) e += ses[w * 128 + tid];
    gst(A.ws + OFF_E + b * 512 + s0 + tid, e + slp[tid]);
  }
}

// ---------------- softmax + sparse context: 64 blocks (one per b) --------------
__device__ void softmax_ctx(const KArgs& A, float* sm) {
  int b = blockIdx.x, tid = threadIdx.x;
  float* red = sm;                 // 16
  int* wc = (int*)(sm + 16);       // 8
  float* lv = sm + 32;             // 512
  short* li = (short*)(sm + 544);  // 512 shorts
  int lane = tid & 63, wv = tid >> 6;
  float e0 = (tid < 512) ? gld(A.ws + OFF_E + b * 512 + tid) : -1e30f;
  float m = e0;
  for (int o = 32; o; o >>= 1) m = fmaxf(m, __shfl_xor(m, o));
  if (lane == 0) red[wv] = m;
  __syncthreads();
  m = red[0];
  for (int w = 1; w < 8; ++w) m = fmaxf(m, red[w]);
  float p0 = (tid < 512) ? expf(e0 - m) : 0.f;
  float s = p0;
  for (int o = 32; o; o >>= 1) s += __shfl_xor(s, o);
  __syncthreads();
  if (lane == 0) red[wv] = s;
  __syncthreads();
  float tot = red[0];
  for (int w = 1; w < 8; ++w) tot += red[w];
  float inv = 1.f / tot;
  float a0 = p0 * inv;
  if (tid < 512) gst(A.ws + OFF_ALPHA + b * 512 + tid, a0);
  unsigned long long mk = __ballot(tid < 512 && a0 > EPS_A);
  if (lane == 0 && wv < 8) wc[wv] = (int)__popcll(mk);
  __syncthreads();
  int base = 0;
  for (int w = 0; w < wv && w < 8; ++w) base += wc[w];
  int n = 0;
  for (int w = 0; w < 8; ++w) n += wc[w];
  unsigned long long below = (1ull << lane) - 1ull;
  if (tid < 512 && a0 > EPS_A) {
    int p = base + (int)__popcll(mk & below);
    li[p] = (short)tid; lv[p] = a0;
  }
  __syncthreads();
  const float* encb = A.enc + (size_t)b * 512 * 768;
  for (int d = tid; d < 768; d += 1024) {
    float acc = 0.f;
    for (int i = 0; i < n; ++i) acc = fmaf(lv[i], encb[(size_t)li[i] * 768 + d], acc);
    gst(A.ws + OFF_CTX + d * 64 + b, acc);
  }
}

// ---------------- the persistent decoder (1024 threads: 4 waves/SIMD) ----------
__global__ __launch_bounds__(1024, 4) void k_decode(KArgs A) {
  __shared__ __align__(16) float sm[8448];
  float* ws = A.ws;
  unsigned* bar = (unsigned*)ws;
  int blk = blockIdx.x;
  unsigned g = 0;

  for (int t = 0; t <= TDEC; ++t) {
    // ---- G1: proj(t-1) | gi_ctx | gh_att | gh1 | gh2 | conv_fp(alpha-) ----
    if (blk < 25) {
      if (t > 0) {
        GemmCfg c{ws + OFF_X3, nullptr, 256, 256, A.prw, 256, 0, A.prb, ws + OFF_FRAME,
                  400, 16, 25, 6, 0, 1, A.dout, t - 1};
        gemm_run(c, blk, sm);
      }
    } else if (t < TDEC) {
      if (blk < 73) {
        GemmCfg c{ws + OFF_CTX, nullptr, 768, 768, A.awi, 896, 0, nullptr, ws + OFF_GICTX,
                  768, 32, 24, 5, 0, 0, nullptr, 0};
        gemm_run(c, blk - 25, sm);
      } else if (blk < 97) {
        GemmCfg c{ws + OFF_HATT, nullptr, 256, 256, A.awh, 256, 0, nullptr, ws + OFF_GHATT,
                  768, 64, 12, 5, 0, 0, nullptr, 0};
        gemm_run(c, blk - 73, sm);
      } else if (blk < 121) {
        GemmCfg c{ws + OFF_H1, nullptr, 256, 256, A.g1wh, 256, 0, nullptr, ws + OFF_GH1,
                  768, 64, 12, 5, 0, 0, nullptr, 0};
        gemm_run(c, blk - 97, sm);
      } else if (blk < 145) {
        GemmCfg c{ws + OFF_H2, nullptr, 256, 256, A.g2wh, 256, 0, nullptr, ws + OFF_GH2,
                  768, 64, 12, 5, 0, 0, nullptr, 0};
        gemm_run(c, blk - 121, sm);
      } else if (blk < 209) {
        conv_fp(A, blk - 145, sm);
      }
    }
    if (t == TDEC) break;
    gridbar(bar, ++g);

    // ---- G2: prenet L1 ----
    if (blk < 16) {
      GemmCfg c{ws + OFF_FRAME, nullptr, 400, 400, A.p1w, 400, 0, A.p1b, ws + OFF_H1S,
                256, 16, 16, 6, 1, 0, nullptr, 0};
      gemm_run(c, blk, sm);
    }
    gridbar(bar, ++g);

    // ---- G3: prenet L2 ----
    if (blk < 8) {
      GemmCfg c{ws + OFF_H1S, nullptr, 256, 256, A.p2w, 256, 0, A.p2b, ws + OFF_PRE,
                128, 16, 8, 6, 1, 0, nullptr, 0};
      gemm_run(c, blk, sm);
    }
    gridbar(bar, ++g);

    // ---- G4: attention GRU gates (gi_pre + combine) ----
    if (blk < 16) att_stripe(A, blk, sm);
    gridbar(bar, ++g);

    // ---- G5: t1 = tanh(dW @ h_att + dWb) ----
    if (blk < 8) {
      GemmCfg c{ws + OFF_HATT, nullptr, 256, 256, A.dWw, 256, 0, A.dWb, ws + OFF_T1,
                128, 16, 8, 6, 2, 0, nullptr, 0};
      gemm_run(c, blk, sm);
    }
    gridbar(bar, ++g);

    // ---- G6: G = dV @ t1 ----
    if (blk < 11) {
      GemmCfg c{ws + OFF_T1, nullptr, 128, 128, A.dVw, 128, 0, nullptr, ws + OFF_GT,
                168, 16, 11, 6, 0, 0, nullptr, 0};
      gemm_run(c, blk, sm);
    }
    gridbar(bar, ++g);

    // ---- G7: dynamic conv + energy MLP ----
    dyn_e(A, sm);
    gridbar(bar, ++g);

    // ---- G8: softmax + sparse context ----
    if (blk < 64) softmax_ctx(A, sm);
    gridbar(bar, ++g);

    // ---- G9: x = [ctx; h_att] @ lw + lb ----
    if (blk < 16) {
      GemmCfg c{ws + OFF_CTX, ws + OFF_HATT, 768, 1024, A.lw, 1024, 0, A.lb, ws + OFF_X,
                256, 16, 16, 6, 0, 0, nullptr, 0};
      gemm_run(c, blk, sm);
    }
    gridbar(bar, ++g);

    // ---- G10: GRU1 -> h1, x2 ----
    if (blk < 16)
      gru_stripe(A, ws + OFF_X, A.g1wi, A.g1bi, ws + OFF_GH1, A.g1bh,
                 ws + OFF_H1, ws + OFF_X, ws + OFF_X2, blk, sm);
    gridbar(bar, ++g);

    // ---- G11: GRU2 -> h2, x3 ----
    if (blk < 16)
      gru_stripe(A, ws + OFF_X2, A.g2wi, A.g2bi, ws + OFF_GH2, A.g2bh,
                 ws + OFF_H2, ws + OFF_X2, ws + OFF_X3, blk, sm);
    gridbar(bar, ++g);
  }
}

// ---------------- host ----------------
extern "C" void kernel_launch(void* const* d_in, const int* in_sizes, int n_in,
                              void* d_out, int out_size, void* d_ws, size_t ws_size,
                              hipStream_t stream) {
  (void)in_sizes; (void)n_in; (void)out_size; (void)ws_size;
  KArgs A;
  A.enc  = (const float*)d_in[0];
  A.p1w  = (const float*)d_in[1];  A.p1b  = (const float*)d_in[2];
  A.p2w  = (const float*)d_in[3];  A.p2b  = (const float*)d_in[4];
  A.awi  = (const float*)d_in[5];  A.abi  = (const float*)d_in[6];
  A.awh  = (const float*)d_in[7];  A.abh  = (const float*)d_in[8];
  A.dWw  = (const float*)d_in[9];  A.dWb  = (const float*)d_in[10];
  A.dVw  = (const float*)d_in[11]; A.dFw  = (const float*)d_in[12];
  A.dUw  = (const float*)d_in[13]; A.dTw  = (const float*)d_in[14];
  A.dTb  = (const float*)d_in[15]; A.dvw  = (const float*)d_in[16];
  A.lw   = (const float*)d_in[17]; A.lb   = (const float*)d_in[18];
  A.g1wi = (const float*)d_in[19]; A.g1bi = (const float*)d_in[20];
  A.g1wh = (const float*)d_in[21]; A.g1bh = (const float*)d_in[22];
  A.g2wi = (const float*)d_in[23]; A.g2bi = (const float*)d_in[24];
  A.g2wh = (const float*)d_in[25]; A.g2bh = (const float*)d_in[26];
  A.prw  = (const float*)d_in[27]; A.prb  = (const float*)d_in[28];
  A.ws   = (float*)d_ws;
  A.dout = (float*)d_out;

  // beta-binomial prior pmf (n=10, a=0.1, b=0.9), flipped
  {
    double aP = 0.1, bP = 0.9;
    double logB0 = lgamma(aP) + lgamma(bP) - lgamma(aP + bP);
    double pm[11];
    for (int k = 0; k <= 10; ++k) {
      double logC = lgamma(11.0) - lgamma(k + 1.0) - lgamma(11.0 - k);
      double logBt = lgamma(k + aP) + lgamma(10.0 - k + bP) - lgamma(10.0 + aP + bP);
      pm[k] = exp(logC + logBt - logB0);
    }
    for (int k = 0; k < 11; ++k) A.pr.v[k] = (float)pm[10 - k];
  }

  k_init<<<256, 256, 0, stream>>>((float*)d_ws);
  k_decode<<<NB, 1024, 0, stream>>>(A);
}

// Round 7
// 58867.993 us; speedup vs baseline: 6.8255x; 1.4577x over previous
//
#include <hip/hip_runtime.h>
#include <cmath>

#define TDEC 250
#define EPS_A 1e-6f
#define CHUNK 128

// ---------------- block groups ----------------
#define GB_MEGA 0
#define GN_MEGA 64
#define GB_PB   64
#define GN_PB   25
#define GB_GI   89
#define GN_GI   24
#define GB_GA   113
#define GN_GA   24
#define GB_G1H  137
#define GN_G1H  24
#define GB_G2H  161
#define GN_G2H  24
#define GB_LW   185
#define GN_LW   32
#define GB_GRU1 217
#define GN_GRU1 16
#define GB_GRU2 233
#define GN_GRU2 16
#define NBLK    249

// ---------------- ws float offsets ----------------
#define OFF_FLAG   0          // 256 blocks x 32 words (flag line per block)
#define OFF_CTX    8192       // [768][64]
#define OFF_HATT   57344      // [256][64]
#define OFF_H1     73728
#define OFF_H2     90112
#define OFF_X3     106496
#define OFF_FRAME  122880     // [400][64]
#define ZERO_END   148480
#define OFF_X2     148480
#define OFF_XP0    164864
#define OFF_XP1    181248
#define OFF_GICTX  197632     // [768][64]
#define OFF_GHATT  246784
#define OFF_GH1    295936
#define OFF_GH2    345088

struct Prior { float v[11]; };

struct KArgs {
  const float *enc;
  const float *p1w,*p1b,*p2w,*p2b;
  const float *awi,*abi,*awh,*abh;
  const float *dWw,*dWb,*dVw,*dFw,*dUw,*dTw,*dTb,*dvw;
  const float *lw,*lb;
  const float *g1wi,*g1bi,*g1wh,*g1bh;
  const float *g2wi,*g2bi,*g2wh,*g2bh;
  const float *prw,*prb;
  float* ws; float* dout;
  Prior pr;
};

// ---------------- MALL-coherent (cache-bypassing) scalar access ----------------
__device__ __forceinline__ float gld(const float* p) {
  return __uint_as_float(__hip_atomic_load((const unsigned*)p, __ATOMIC_RELAXED, __HIP_MEMORY_SCOPE_AGENT));
}
__device__ __forceinline__ void gst(float* p, float v) {
  __hip_atomic_store((unsigned*)p, __float_as_uint(v), __ATOMIC_RELAXED, __HIP_MEMORY_SCOPE_AGENT);
}
__device__ __forceinline__ float sigm(float x) { return 1.f / (1.f + expf(-x)); }

// ---------------- init ----------------
__global__ __launch_bounds__(256) void k_init(float* ws) {
  int idx = blockIdx.x * 256 + threadIdx.x;
  for (int i = idx; i < ZERO_END; i += gridDim.x * 256) ws[i] = 0.f;
}

// ---------------- p2p flags ----------------
// producer: drain stores -> sync -> tid0 stores generation. consumer: poll flags, sync.
__device__ __forceinline__ void postf(unsigned* fl, int word, unsigned v) {
  asm volatile("s_waitcnt vmcnt(0)" ::: "memory");
  __syncthreads();
  if (threadIdx.x == 0)
    __hip_atomic_store(&fl[blockIdx.x * 32 + word], v, __ATOMIC_RELAXED, __HIP_MEMORY_SCOPE_AGENT);
}
__device__ __forceinline__ void waitf(unsigned* fl, int base, int cnt, int word, unsigned v) {
  if ((int)threadIdx.x < cnt) {
    while (__hip_atomic_load(&fl[(base + threadIdx.x) * 32 + word], __ATOMIC_RELAXED, __HIP_MEMORY_SCOPE_AGENT) < v)
      __builtin_amdgcn_s_sleep(1);
  }
  __syncthreads();
}

// ---------------- generic chunked GEMM: outT[N][64] = W[N][K] @ actT[K][64] ------
struct GemmCfg {
  const float* A0; const float* A1; int K0; int K;
  const float* W; int wstr; int wofs;
  const float* bias; float* outT;
  int N, J, jgN, LR;
  int store; float* dout; int tq;
};

__device__ void gemm_run(const GemmCfg& c, int rb, float* sm) {
  const int R = 1 << c.LR;
  const int jg = rb % c.jgN, rg = rb / c.jgN;
  const int r0 = rg * R, j0 = jg * c.J;
  const int Kp = CHUNK + 4;
  const int tid = threadIdx.x;
  const int r = tid & (R - 1);
  const int jq = tid >> c.LR;
  const int jstep = 1024 >> c.LR;
  const int nout = (c.J << c.LR) >> 10;   // 1 or 2
  float acc[2];
#pragma unroll
  for (int o = 0; o < 2; ++o) {
    int jj = j0 + jq + o * jstep;
    acc[o] = (c.bias && jj < c.N) ? c.bias[jj] : 0.f;
  }
  for (int kc = 0; kc < c.K; kc += CHUNK) {
    const int cl = min(CHUNK, c.K - kc);
    __syncthreads();
    for (int idx = tid; idx < (cl << c.LR); idx += 1024) {
      int k = idx >> c.LR, rr = idx & (R - 1);
      int kk = kc + k;
      float v = (kk < c.K0) ? gld(c.A0 + kk * 64 + r0 + rr)
                            : gld(c.A1 + (kk - c.K0) * 64 + r0 + rr);
      sm[rr * Kp + k] = v;
    }
    __syncthreads();
    const float4* ar = (const float4*)(sm + r * Kp);
    for (int o = 0; o < nout; ++o) {
      int jj = j0 + jq + o * jstep;
      if (jj < c.N) {
        const float4* wr = (const float4*)(c.W + (size_t)jj * c.wstr + c.wofs + kc);
        float a = acc[o];
#pragma unroll 8
        for (int k4 = 0; k4 < (cl >> 2); ++k4) {
          float4 av = ar[k4]; float4 wv = wr[k4];
          a = fmaf(av.x,wv.x, fmaf(av.y,wv.y, fmaf(av.z,wv.z, fmaf(av.w,wv.w, a))));
        }
        acc[o] = a;
      }
    }
  }
  for (int o = 0; o < nout; ++o) {
    int jj = j0 + jq + o * jstep;
    if (jj < c.N) {
      float v = acc[o];
      gst(c.outT + jj * 64 + r0 + r, v);
      if (c.store)
        c.dout[(size_t)(r0 + r) * 100000 + (jj / 5) * 1250 + c.tq * 5 + (jj % 5)] = v;
    }
  }
}

// ---------------- per-b megaphase ----------------
__device__ void mega(const KArgs& A, int b, int t, float* sm, unsigned* fl) {
  float* alpha = sm;            // 512 persistent
  float* hatt  = sm + 512;      // 256 persistent
  float* sal   = sm + 768;      // 544
  float* fr    = sm + 1312;     // 416
  float* h1s   = sm + 1728;     // 256
  float* pre   = sm + 1984;     // 128
  float* sgi   = sm + 2112;     // 768
  float* sgh   = sm + 2880;     // 768
  float* t1    = sm + 3648;     // 128
  float* Gl    = sm + 3776;     // 176
  float* sdF   = sm + 3952;     // 176 persistent
  float* sdU   = sm + 4128;     // 1024 persistent
  float* sdT   = sm + 5152;     // 1024 persistent
  float* sdtb  = sm + 6176;     // 128 persistent
  float* sdv   = sm + 6304;     // 128 persistent
  float* e     = sm + 6432;     // 528
  float* es    = sm + 6960;     // 1024
  float* red   = sm + 7984;     // 16
  int*   wc    = (int*)(sm + 8000); // 8 (+pad)
  float* lv    = sm + 8016;     // 512
  short* li    = (short*)(sm + 8528); // 512 shorts
  const int tid = threadIdx.x;

  if (t == 0) {
    if (tid < 512) alpha[tid] = (tid == 0) ? 1.f : 0.f;
    if (tid < 256) hatt[tid] = 0.f;
    if (tid < 168) sdF[tid] = A.dFw[tid];
    sdU[tid] = A.dUw[tid];
    sdT[tid] = A.dTw[tid];
    if (tid < 128) { sdtb[tid] = A.dTb[tid]; sdv[tid] = A.dvw[tid]; }
    __syncthreads();
  }
  // wait producers: frame(t), gi_ctx(t), gh_att(t)
  waitf(fl, GB_PB, GN_PB, 0, (unsigned)(t + 1));
  waitf(fl, GB_GI, GN_GI, 0, (unsigned)(t + 1));
  waitf(fl, GB_GA, GN_GA, 0, (unsigned)(t + 1));

  // S1: frame column + padded alpha copy
  if (tid < 400) fr[tid] = gld(A.ws + OFF_FRAME + tid * 64 + b);
  if (tid < 544) {
    int sg = tid - 10;
    sal[tid] = (sg >= 0 && sg < 512) ? alpha[sg] : 0.f;
  }
  __syncthreads();
  // S2: prenet L1 (j x 4 partials, shfl reduce)
  {
    int j = tid >> 2, part = tid & 3;
    const float4* wr = (const float4*)(A.p1w + (size_t)j * 400 + part * 100);
    const float4* xr = (const float4*)(fr + part * 100);
    float a = 0.f;
#pragma unroll 5
    for (int k4 = 0; k4 < 25; ++k4) {
      float4 w = wr[k4], x = xr[k4];
      a = fmaf(w.x,x.x, fmaf(w.y,x.y, fmaf(w.z,x.z, fmaf(w.w,x.w, a))));
    }
    a += __shfl_xor(a, 1); a += __shfl_xor(a, 2);
    if (part == 0) h1s[j] = fmaxf(a + A.p1b[j], 0.f);
  }
  __syncthreads();
  // S3: prenet L2
  if (tid < 512) {
    int j = tid >> 2, part = tid & 3;
    const float4* wr = (const float4*)(A.p2w + (size_t)j * 256 + part * 64);
    const float4* xr = (const float4*)(h1s + part * 64);
    float a = 0.f;
#pragma unroll 4
    for (int k4 = 0; k4 < 16; ++k4) {
      float4 w = wr[k4], x = xr[k4];
      a = fmaf(w.x,x.x, fmaf(w.y,x.y, fmaf(w.z,x.z, fmaf(w.w,x.w, a))));
    }
    a += __shfl_xor(a, 1); a += __shfl_xor(a, 2);
    if (part == 0) pre[j] = fmaxf(a + A.p2b[j], 0.f);
  }
  __syncthreads();
  // S4: gate pre-activations (768 rows)
  if (tid < 768) {
    int row = tid;
    const float4* wr = (const float4*)(A.awi + (size_t)row * 896 + 768);
    const float4* xr = (const float4*)pre;
    float a = 0.f;
#pragma unroll 8
    for (int k4 = 0; k4 < 32; ++k4) {
      float4 w = wr[k4], x = xr[k4];
      a = fmaf(w.x,x.x, fmaf(w.y,x.y, fmaf(w.z,x.z, fmaf(w.w,x.w, a))));
    }
    sgi[row] = a + gld(A.ws + OFF_GICTX + row * 64 + b) + A.abi[row];
    sgh[row] = gld(A.ws + OFF_GHATT + row * 64 + b) + A.abh[row];
  }
  __syncthreads();
  // S5: GRU combine -> h_att
  if (tid < 256) {
    int j = tid;
    float r = sigm(sgi[j] + sgh[j]);
    float z = sigm(sgi[256 + j] + sgh[256 + j]);
    float n = tanhf(sgi[512 + j] + r * sgh[512 + j]);
    float hnew = (1.f - z) * n + z * hatt[j];
    hatt[j] = hnew;
    gst(A.ws + OFF_HATT + j * 64 + b, hnew);
  }
  postf(fl, 1, (unsigned)(t + 1));   // hatt ready
  // S7: t1 = tanh(dW @ h_att + dWb)
  if (tid < 512) {
    int c = tid >> 2, part = tid & 3;
    const float4* wr = (const float4*)(A.dWw + (size_t)c * 256 + part * 64);
    const float4* xr = (const float4*)(hatt + part * 64);
    float a = 0.f;
#pragma unroll 4
    for (int k4 = 0; k4 < 16; ++k4) {
      float4 w = wr[k4], x = xr[k4];
      a = fmaf(w.x,x.x, fmaf(w.y,x.y, fmaf(w.z,x.z, fmaf(w.w,x.w, a))));
    }
    a += __shfl_xor(a, 1); a += __shfl_xor(a, 2);
    if (part == 0) t1[c] = tanhf(a + A.dWb[c]);
  }
  __syncthreads();
  // S8: G = dV @ t1
  if (tid < 168) {
    const float4* wr = (const float4*)(A.dVw + (size_t)tid * 128);
    const float4* xr = (const float4*)t1;
    float a = 0.f;
#pragma unroll 8
    for (int k4 = 0; k4 < 32; ++k4) {
      float4 w = wr[k4], x = xr[k4];
      a = fmaf(w.x,x.x, fmaf(w.y,x.y, fmaf(w.z,x.z, fmaf(w.w,x.w, a))));
    }
    Gl[tid] = a;
  }
  __syncthreads();
  // S9: static + dynamic conv fused with energy MLP (sl x half)
  {
    int sl = tid >> 1, half = tid & 1;
    float f0[8], g0[8];
#pragma unroll
    for (int q = 0; q < 8; ++q) {
      float fa = 0.f, ga = 0.f;
#pragma unroll
      for (int k = 0; k < 21; ++k) {
        float a = sal[sl + k];
        fa = fmaf(sdF[q * 21 + k], a, fa);
        ga = fmaf(Gl[q * 21 + k], a, ga);
      }
      f0[q] = fa; g0[q] = ga;
    }
    float acc = 0.f;
    for (int cc = half * 64; cc < half * 64 + 64; ++cc) {
      float a = sdtb[cc];
#pragma unroll
      for (int q = 0; q < 8; ++q)
        a = fmaf(sdU[cc * 8 + q], f0[q], fmaf(sdT[cc * 8 + q], g0[q], a));
      acc = fmaf(sdv[cc], tanhf(a), acc);
    }
    es[sl * 2 + half] = acc;
  }
  __syncthreads();
  // S10: e = mlp + log(prior)
  if (tid < 512) {
    float p = 0.f;
#pragma unroll
    for (int k = 0; k < 11; ++k) p = fmaf(A.pr.v[k], sal[tid + k], p);
    e[tid] = es[tid * 2] + es[tid * 2 + 1] + logf(fmaxf(p, 1e-6f));
  }
  __syncthreads();
  // S11: softmax + compaction + sparse ctx
  {
    int lane = tid & 63, wv = tid >> 6;
    float e0 = (tid < 512) ? e[tid] : -1e30f;
    float m = e0;
    for (int o = 32; o; o >>= 1) m = fmaxf(m, __shfl_xor(m, o));
    if (lane == 0) red[wv] = m;
    __syncthreads();
    m = red[0];
    for (int w = 1; w < 8; ++w) m = fmaxf(m, red[w]);
    float p0 = (tid < 512) ? expf(e0 - m) : 0.f;
    float s = p0;
    for (int o = 32; o; o >>= 1) s += __shfl_xor(s, o);
    __syncthreads();
    if (lane == 0) red[wv] = s;
    __syncthreads();
    float tot = red[0];
    for (int w = 1; w < 8; ++w) tot += red[w];
    float inv = 1.f / tot;
    float a0 = p0 * inv;
    if (tid < 512) alpha[tid] = a0;
    unsigned long long mk = __ballot(tid < 512 && a0 > EPS_A);
    if (lane == 0 && wv < 8) wc[wv] = (int)__popcll(mk);
    __syncthreads();
    int base = 0;
    for (int w = 0; w < wv && w < 8; ++w) base += wc[w];
    int n = 0;
    for (int w = 0; w < 8; ++w) n += wc[w];
    unsigned long long below = (1ull << lane) - 1ull;
    if (tid < 512 && a0 > EPS_A) {
      int p = base + (int)__popcll(mk & below);
      li[p] = (short)tid; lv[p] = a0;
    }
    __syncthreads();
    const float* encb = A.enc + (size_t)b * 512 * 768;
    for (int d = tid; d < 768; d += 1024) {
      float acc = 0.f;
      int i = 0;
      for (; i + 4 <= n; i += 4) {
        float v0 = encb[(size_t)li[i] * 768 + d];
        float v1 = encb[(size_t)li[i+1] * 768 + d];
        float v2 = encb[(size_t)li[i+2] * 768 + d];
        float v3 = encb[(size_t)li[i+3] * 768 + d];
        acc = fmaf(lv[i],v0, fmaf(lv[i+1],v1, fmaf(lv[i+2],v2, fmaf(lv[i+3],v3, acc))));
      }
      for (; i < n; ++i) acc = fmaf(lv[i], encb[(size_t)li[i] * 768 + d], acc);
      gst(A.ws + OFF_CTX + d * 64 + b, acc);
    }
  }
  postf(fl, 0, (unsigned)(t + 1));   // ctx ready (final)
}

// ---------------- GRU stripe: 16 blocks, thread=(j16, r64), h in register -------
__device__ void gru_stripe2(const KArgs& A, int rb, float* sm, float* hreg,
                            const float* xp0, const float* xp1, const float* lb,
                            const float* W, const float* bi, const float* bh,
                            const float* ghT, float* hOut, float* xnOut) {
  const int j = rb * 16 + (threadIdx.x >> 6);
  const int r = threadIdx.x & 63;
  const int Kp = CHUNK + 4;
  float xj = 0.f;
  float a0 = 0.f, a1 = 0.f, a2 = 0.f;
  for (int kc = 0; kc < 256; kc += CHUNK) {
    __syncthreads();
    for (int idx = threadIdx.x; idx < CHUNK * 64; idx += 1024) {
      int k = idx >> 6, rr = idx & 63;
      float v = gld(xp0 + (kc + k) * 64 + rr);
      if (xp1) v += gld(xp1 + (kc + k) * 64 + rr) + lb[kc + k];
      sm[rr * Kp + k] = v;
    }
    __syncthreads();
    if ((j >> 7) == (kc >> 7)) xj = sm[r * Kp + (j & 127)];
    const float4* ar = (const float4*)(sm + r * Kp);
    const float4* w0 = (const float4*)(W + (size_t)j * 256 + kc);
    const float4* w1 = (const float4*)(W + (size_t)(j + 256) * 256 + kc);
    const float4* w2 = (const float4*)(W + (size_t)(j + 512) * 256 + kc);
#pragma unroll 16
    for (int k4 = 0; k4 < (CHUNK >> 2); ++k4) {
      float4 av = ar[k4];
      float4 x = w0[k4], y = w1[k4], z4 = w2[k4];
      a0 = fmaf(av.x,x.x, fmaf(av.y,x.y, fmaf(av.z,x.z, fmaf(av.w,x.w, a0))));
      a1 = fmaf(av.x,y.x, fmaf(av.y,y.y, fmaf(av.z,y.z, fmaf(av.w,y.w, a1))));
      a2 = fmaf(av.x,z4.x, fmaf(av.y,z4.y, fmaf(av.z,z4.z, fmaf(av.w,z4.w, a2))));
    }
  }
  float gr = a0 + bi[j], gz = a1 + bi[j + 256], gn = a2 + bi[j + 512];
  float hr = gld(ghT + j * 64 + r) + bh[j];
  float hz = gld(ghT + (j + 256) * 64 + r) + bh[j + 256];
  float hn = gld(ghT + (j + 512) * 64 + r) + bh[j + 512];
  float rr2 = sigm(gr + hr);
  float zz = sigm(gz + hz);
  float nn = tanhf(gn + rr2 * hn);
  float hnew = (1.f - zz) * nn + zz * (*hreg);
  *hreg = hnew;
  gst(hOut + j * 64 + r, hnew);
  gst(xnOut + j * 64 + r, xj + hnew);
}

// ---------------- the persistent decoder (p2p flag pipeline) ----------------
__global__ __launch_bounds__(1024, 4) void k_decode(KArgs A) {
  __shared__ __align__(16) float sm[8832];
  float* ws = A.ws;
  unsigned* fl = (unsigned*)ws;
  const int blk = blockIdx.x;

  if (blk < GB_PB) {
    // ---- MEGA: one block per batch row ----
    for (int t = 0; t < TDEC; ++t) mega(A, blk, t, sm, fl);
  } else if (blk < GB_GI) {
    // ---- PB: proj(t-1) -> frame + dout ----
    int rb = blk - GB_PB;
    for (int t = 0; t <= TDEC; ++t) {
      waitf(fl, GB_GRU2, GN_GRU2, 0, (unsigned)t);
      if (t > 0) {
        GemmCfg c{ws + OFF_X3, nullptr, 256, 256, A.prw, 256, 0, A.prb, ws + OFF_FRAME,
                  400, 16, 25, 6, 1, A.dout, t - 1};
        gemm_run(c, rb, sm);
      }
      postf(fl, 0, (unsigned)(t + 1));
    }
  } else if (blk < GB_GA) {
    // ---- GI: gi_ctx = awi[:, :768] @ ctx(t-1) ----
    int rb = blk - GB_GI;
    for (int t = 0; t < TDEC; ++t) {
      waitf(fl, GB_MEGA, GN_MEGA, 0, (unsigned)t);
      GemmCfg c{ws + OFF_CTX, nullptr, 768, 768, A.awi, 896, 0, nullptr, ws + OFF_GICTX,
                768, 32, 24, 6, 0, nullptr, 0};
      gemm_run(c, rb, sm);
      postf(fl, 0, (unsigned)(t + 1));
    }
  } else if (blk < GB_G1H) {
    // ---- GA: gh_att = awh @ h_att(t-1) ----
    int rb = blk - GB_GA;
    for (int t = 0; t < TDEC; ++t) {
      waitf(fl, GB_MEGA, GN_MEGA, 1, (unsigned)t);
      GemmCfg c{ws + OFF_HATT, nullptr, 256, 256, A.awh, 256, 0, nullptr, ws + OFF_GHATT,
                768, 32, 24, 6, 0, nullptr, 0};
      gemm_run(c, rb, sm);
      postf(fl, 0, (unsigned)(t + 1));
    }
  } else if (blk < GB_G2H) {
    // ---- G1H: gh1 = g1wh @ h1(t-1) ----
    int rb = blk - GB_G1H;
    for (int t = 0; t < TDEC; ++t) {
      waitf(fl, GB_GRU1, GN_GRU1, 0, (unsigned)t);
      GemmCfg c{ws + OFF_H1, nullptr, 256, 256, A.g1wh, 256, 0, nullptr, ws + OFF_GH1,
                768, 32, 24, 6, 0, nullptr, 0};
      gemm_run(c, rb, sm);
      postf(fl, 0, (unsigned)(t + 1));
    }
  } else if (blk < GB_LW) {
    // ---- G2H: gh2 = g2wh @ h2(t-1) ----
    int rb = blk - GB_G2H;
    for (int t = 0; t < TDEC; ++t) {
      waitf(fl, GB_GRU2, GN_GRU2, 0, (unsigned)t);
      GemmCfg c{ws + OFF_H2, nullptr, 256, 256, A.g2wh, 256, 0, nullptr, ws + OFF_GH2,
                768, 32, 24, 6, 0, nullptr, 0};
      gemm_run(c, rb, sm);
      postf(fl, 0, (unsigned)(t + 1));
    }
  } else if (blk < GB_GRU1) {
    // ---- LW: x-partials = lw @ [ctx; hatt] (k-split 2) ----
    int rb = blk - GB_LW;
    int kt = rb >> 4, jb = rb & 15;
    for (int t = 0; t < TDEC; ++t) {
      waitf(fl, GB_MEGA, GN_MEGA, 0, (unsigned)(t + 1));
      if (kt == 0) {
        GemmCfg c{ws + OFF_CTX, nullptr, 512, 512, A.lw, 1024, 0, nullptr, ws + OFF_XP0,
                  256, 16, 16, 6, 0, nullptr, 0};
        gemm_run(c, jb, sm);
      } else {
        GemmCfg c{ws + OFF_CTX + 512 * 64, ws + OFF_HATT, 256, 512, A.lw, 1024, 512, nullptr,
                  ws + OFF_XP1, 256, 16, 16, 6, 0, nullptr, 0};
        gemm_run(c, jb, sm);
      }
      postf(fl, 0, (unsigned)(t + 1));
    }
  } else if (blk < GB_GRU2) {
    // ---- GRU1 ----
    int rb = blk - GB_GRU1;
    float hreg = 0.f;
    for (int t = 0; t < TDEC; ++t) {
      waitf(fl, GB_LW, GN_LW, 0, (unsigned)(t + 1));
      waitf(fl, GB_G1H, GN_G1H, 0, (unsigned)(t + 1));
      gru_stripe2(A, rb, sm, &hreg, ws + OFF_XP0, ws + OFF_XP1, A.lb,
                  A.g1wi, A.g1bi, A.g1bh, ws + OFF_GH1, ws + OFF_H1, ws + OFF_X2);
      postf(fl, 0, (unsigned)(t + 1));
    }
  } else if (blk < NBLK) {
    // ---- GRU2 ----
    int rb = blk - GB_GRU2;
    float hreg = 0.f;
    for (int t = 0; t < TDEC; ++t) {
      waitf(fl, GB_GRU1, GN_GRU1, 0, (unsigned)(t + 1));
      waitf(fl, GB_G2H, GN_G2H, 0, (unsigned)(t + 1));
      gru_stripe2(A, rb, sm, &hreg, ws + OFF_X2, nullptr, nullptr,
                  A.g2wi, A.g2bi, A.g2bh, ws + OFF_GH2, ws + OFF_H2, ws + OFF_X3);
      postf(fl, 0, (unsigned)(t + 1));
    }
  }
}

// ---------------- host ----------------
extern "C" void kernel_launch(void* const* d_in, const int* in_sizes, int n_in,
                              void* d_out, int out_size, void* d_ws, size_t ws_size,
                              hipStream_t stream) {
  (void)in_sizes; (void)n_in; (void)out_size; (void)ws_size;
  KArgs A;
  A.enc  = (const float*)d_in[0];
  A.p1w  = (const float*)d_in[1];  A.p1b  = (const float*)d_in[2];
  A.p2w  = (const float*)d_in[3];  A.p2b  = (const float*)d_in[4];
  A.awi  = (const float*)d_in[5];  A.abi  = (const float*)d_in[6];
  A.awh  = (const float*)d_in[7];  A.abh  = (const float*)d_in[8];
  A.dWw  = (const float*)d_in[9];  A.dWb  = (const float*)d_in[10];
  A.dVw  = (const float*)d_in[11]; A.dFw  = (const float*)d_in[12];
  A.dUw  = (const float*)d_in[13]; A.dTw  = (const float*)d_in[14];
  A.dTb  = (const float*)d_in[15]; A.dvw  = (const float*)d_in[16];
  A.lw   = (const float*)d_in[17]; A.lb   = (const float*)d_in[18];
  A.g1wi = (const float*)d_in[19]; A.g1bi = (const float*)d_in[20];
  A.g1wh = (const float*)d_in[21]; A.g1bh = (const float*)d_in[22];
  A.g2wi = (const float*)d_in[23]; A.g2bi = (const float*)d_in[24];
  A.g2wh = (const float*)d_in[25]; A.g2bh = (const float*)d_in[26];
  A.prw  = (const float*)d_in[27]; A.prb  = (const float*)d_in[28];
  A.ws   = (float*)d_ws;
  A.dout = (float*)d_out;

  // beta-binomial prior pmf (n=10, a=0.1, b=0.9), flipped
  {
    double aP = 0.1, bP = 0.9;
    double logB0 = lgamma(aP) + lgamma(bP) - lgamma(aP + bP);
    double pm[11];
    for (int k = 0; k <= 10; ++k) {
      double logC = lgamma(11.0) - lgamma(k + 1.0) - lgamma(11.0 - k);
      double logBt = lgamma(k + aP) + lgamma(10.0 - k + bP) - lgamma(10.0 + aP + bP);
      pm[k] = exp(logC + logBt - logB0);
    }
    for (int k = 0; k < 11; ++k) A.pr.v[k] = (float)pm[10 - k];
  }

  k_init<<<256, 256, 0, stream>>>((float*)d_ws);
  k_decode<<<NBLK, 1024, 0, stream>>>(A);
}

// Round 9
// 50263.431 us; speedup vs baseline: 7.9940x; 1.1712x over previous
//
#include <hip/hip_runtime.h>
#include <cmath>

#define TDEC 250
#define EPS_A 1e-6f

// ---------------- block groups ----------------
#define GB_GI   64
#define GN_GI   48
#define GB_GA   112
#define GN_GA   16
#define GB_G1H  128
#define GN_G1H  16
#define GB_G2H  144
#define GN_G2H  16
#define NBLK    160

// ---------------- ws float offsets ----------------
// flag line per block: 32 words each, words 0..3 used (MEGA: 0=ctx,1=hatt,2=h1,3=h2)
#define OFF_CTXB   8192      // [64][768]
#define OFF_HATTB  57344     // [64][256]
#define OFF_H1B    73728
#define OFF_H2B    90112
#define OFF_GIB    106496    // [64][768]
#define OFF_GAB    155648
#define OFF_G1HB   204800
#define OFF_G2HB   253952
#define ZERO_END   106496

struct Prior { float v[11]; };

struct KArgs {
  const float *enc;
  const float *p1w,*p1b,*p2w,*p2b;
  const float *awi,*abi,*awh,*abh;
  const float *dWw,*dWb,*dVw,*dFw,*dUw,*dTw,*dTb,*dvw;
  const float *lw,*lb;
  const float *g1wi,*g1bi,*g1wh,*g1bh;
  const float *g2wi,*g2bi,*g2wh,*g2bh;
  const float *prw,*prb;
  float* ws; float* dout;
  Prior pr;
};

#define FMA4(a, av, wv) a = fmaf((av).x,(wv).x, fmaf((av).y,(wv).y, fmaf((av).z,(wv).z, fmaf((av).w,(wv).w,(a)))))

// ---------------- MALL-coherent (cache-bypassing) scalar access ----------------
__device__ __forceinline__ float gld(const float* p) {
  return __uint_as_float(__hip_atomic_load((const unsigned*)p, __ATOMIC_RELAXED, __HIP_MEMORY_SCOPE_AGENT));
}
__device__ __forceinline__ void gst(float* p, float v) {
  __hip_atomic_store((unsigned*)p, __float_as_uint(v), __ATOMIC_RELAXED, __HIP_MEMORY_SCOPE_AGENT);
}
__device__ __forceinline__ float sigm(float x) { return 1.f / (1.f + expf(-x)); }

// ---------------- init ----------------
__global__ __launch_bounds__(256) void k_init(float* ws) {
  int idx = blockIdx.x * 256 + threadIdx.x;
  for (int i = idx; i < ZERO_END; i += gridDim.x * 256) ws[i] = 0.f;
}

// ---------------- flags ----------------
__device__ __forceinline__ void postw(unsigned* fl, int word, unsigned v) {
  asm volatile("s_waitcnt vmcnt(0)" ::: "memory");
  __syncthreads();
  if (threadIdx.x == 0)
    __hip_atomic_store(&fl[blockIdx.x * 32 + word], v, __ATOMIC_RELAXED, __HIP_MEMORY_SCOPE_AGENT);
}
template <int SLP>
__device__ __forceinline__ void pollge(unsigned* fl, int line, int word, unsigned v) {
  while (__hip_atomic_load(&fl[line * 32 + word], __ATOMIC_RELAXED, __HIP_MEMORY_SCOPE_AGENT) < v)
    __builtin_amdgcn_s_sleep(SLP);
}

// ---------------- the persistent decoder ----------------
__global__ __launch_bounds__(1024, 1) void k_decode(KArgs A) {
  __shared__ __align__(16) float sm[10816];
  float* ws = A.ws;
  unsigned* fl = (unsigned*)ws;
  const int blk = blockIdx.x;
  const int tid = threadIdx.x;

  if (blk < 64) {
    // =================== MEGA: one block per batch row, full critical path ===================
    const int b = blk;
    float* alpha = sm;          // 512 persistent
    float* hatt  = sm + 512;    // 256
    float* h1    = sm + 768;
    float* h2    = sm + 1024;
    float* fr    = sm + 1280;   // 416 (400 used)
    float* ctx   = sm + 1696;   // 768
    float* x     = sm + 2464;   // 256
    float* x2    = sm + 2720;
    float* x3    = sm + 2976;
    float* sdF   = sm + 3232;   // 176
    float* sdU   = sm + 3408;   // 1024
    float* sdT   = sm + 4432;   // 1024
    float* sdtb  = sm + 5456;   // 128
    float* sdv   = sm + 5584;   // 128
    float* sal   = sm + 5712;   // 544
    float* h1s   = sm + 6256;   // 256
    float* pre   = sm + 6512;   // 128
    float* sgi   = sm + 6640;   // 768
    float* sgh   = sm + 7408;   // 768
    float* t1    = sm + 8176;   // 128
    float* Gl    = sm + 8304;   // 176
    float* es    = sm + 8480;   // 1024
    float* e     = sm + 9504;   // 512
    float* red   = sm + 10016;  // 16
    int*   wc    = (int*)(sm + 10032);  // 8
    float* lv    = sm + 10048;  // 512
    short* li    = (short*)(sm + 10560); // 512 shorts

    // one-time init
    if (tid < 512) alpha[tid] = (tid == 0) ? 1.f : 0.f;
    if (tid < 256) { hatt[tid] = 0.f; h1[tid] = 0.f; h2[tid] = 0.f; }
    if (tid < 416) fr[tid] = 0.f;
    if (tid < 176) sdF[tid] = (tid < 168) ? A.dFw[tid] : 0.f;
    sdU[tid] = A.dUw[tid];
    sdT[tid] = A.dTw[tid];
    if (tid < 128) { sdtb[tid] = A.dTb[tid]; sdv[tid] = A.dvw[tid]; }
    __syncthreads();

    for (int t = 0; t < TDEC; ++t) {
      // ---- S1: padded alpha ----
      if (tid < 544) { int sg = tid - 10; sal[tid] = (sg >= 0 && sg < 512) ? alpha[sg] : 0.f; }
      __syncthreads();
      // ---- S2: prenet L1 (256 j x 4 parts) ----
      {
        int j = tid >> 2, part = tid & 3;
        const float4* wr = (const float4*)(A.p1w + (size_t)j * 400 + part * 100);
        const float4* xr = (const float4*)(fr + part * 100);
        float a = 0.f;
#pragma unroll
        for (int k4 = 0; k4 < 25; ++k4) { float4 av = xr[k4], wv = wr[k4]; FMA4(a, av, wv); }
        a += __shfl_xor(a, 1); a += __shfl_xor(a, 2);
        if (part == 0) h1s[j] = fmaxf(a + A.p1b[j], 0.f);
      }
      __syncthreads();
      // ---- S3: prenet L2 (128 j x 8 parts) ----
      {
        int j = tid >> 3, part = tid & 7;
        const float4* wr = (const float4*)(A.p2w + (size_t)j * 256 + part * 32);
        const float4* xr = (const float4*)(h1s + part * 32);
        float a = 0.f;
#pragma unroll
        for (int k4 = 0; k4 < 8; ++k4) { float4 av = xr[k4], wv = wr[k4]; FMA4(a, av, wv); }
        a += __shfl_xor(a, 1); a += __shfl_xor(a, 2); a += __shfl_xor(a, 4);
        if (part == 0) pre[j] = fmaxf(a + A.p2b[j], 0.f);
      }
      // ---- S4: wait GI+GA, gate pre-activations ----
      if (tid < GN_GI) pollge<2>(fl, GB_GI + tid, 0, (unsigned)(t + 1));
      else if (tid < GN_GI + GN_GA) pollge<2>(fl, GB_GA + tid - GN_GI, 0, (unsigned)(t + 1));
      __syncthreads();
      if (tid < 768) {
        const float4* wr = (const float4*)(A.awi + (size_t)tid * 896 + 768);
        const float4* xr = (const float4*)pre;
        float a = 0.f;
#pragma unroll 8
        for (int k4 = 0; k4 < 32; ++k4) { float4 av = xr[k4], wv = wr[k4]; FMA4(a, av, wv); }
        sgi[tid] = a + gld(ws + OFF_GIB + b * 768 + tid) + A.abi[tid];
        sgh[tid] = gld(ws + OFF_GAB + b * 768 + tid) + A.abh[tid];
      }
      __syncthreads();
      // ---- S5: attention GRU combine -> hatt ----
      if (tid < 256) {
        float r = sigm(sgi[tid] + sgh[tid]);
        float z = sigm(sgi[256 + tid] + sgh[256 + tid]);
        float n = tanhf(sgi[512 + tid] + r * sgh[512 + tid]);
        float hnew = (1.f - z) * n + z * hatt[tid];
        hatt[tid] = hnew;
        gst(ws + OFF_HATTB + b * 256 + tid, hnew);
      }
      postw(fl, 1, (unsigned)(t + 1));
      // ---- S7: t1 = tanh(dW @ hatt + dWb) (128 j x 8 parts) ----
      {
        int j = tid >> 3, part = tid & 7;
        const float4* wr = (const float4*)(A.dWw + (size_t)j * 256 + part * 32);
        const float4* xr = (const float4*)(hatt + part * 32);
        float a = 0.f;
#pragma unroll
        for (int k4 = 0; k4 < 8; ++k4) { float4 av = xr[k4], wv = wr[k4]; FMA4(a, av, wv); }
        a += __shfl_xor(a, 1); a += __shfl_xor(a, 2); a += __shfl_xor(a, 4);
        if (part == 0) t1[j] = tanhf(a + A.dWb[j]);
      }
      __syncthreads();
      // ---- S8: G = dV @ t1 ----
      if (tid < 168) {
        const float4* wr = (const float4*)(A.dVw + (size_t)tid * 128);
        const float4* xr = (const float4*)t1;
        float a = 0.f;
#pragma unroll 8
        for (int k4 = 0; k4 < 32; ++k4) { float4 av = xr[k4], wv = wr[k4]; FMA4(a, av, wv); }
        Gl[tid] = a;
      }
      __syncthreads();
      // ---- S9: static+dynamic conv fused with energy MLP ----
      {
        int sl = tid >> 1, half = tid & 1;
        float f0[8], g0[8];
#pragma unroll
        for (int q = 0; q < 8; ++q) {
          float fa = 0.f, ga = 0.f;
#pragma unroll
          for (int k = 0; k < 21; ++k) {
            float a = sal[sl + k];
            fa = fmaf(sdF[q * 21 + k], a, fa);
            ga = fmaf(Gl[q * 21 + k], a, ga);
          }
          f0[q] = fa; g0[q] = ga;
        }
        float acc = 0.f;
        for (int cc = half * 64; cc < half * 64 + 64; ++cc) {
          float a = sdtb[cc];
#pragma unroll
          for (int q = 0; q < 8; ++q)
            a = fmaf(sdU[cc * 8 + q], f0[q], fmaf(sdT[cc * 8 + q], g0[q], a));
          acc = fmaf(sdv[cc], tanhf(a), acc);
        }
        es[sl * 2 + half] = acc;
      }
      __syncthreads();
      // ---- S10: e = mlp + log(prior) ----
      if (tid < 512) {
        float p = 0.f;
#pragma unroll
        for (int k = 0; k < 11; ++k) p = fmaf(A.pr.v[k], sal[tid + k], p);
        e[tid] = es[tid * 2] + es[tid * 2 + 1] + logf(fmaxf(p, 1e-6f));
      }
      __syncthreads();
      // ---- S11: softmax + compaction + sparse ctx ----
      {
        int lane = tid & 63, wv = tid >> 6;
        float e0 = (tid < 512) ? e[tid] : -1e30f;
        float m = e0;
        for (int o = 32; o; o >>= 1) m = fmaxf(m, __shfl_xor(m, o));
        if (lane == 0) red[wv] = m;
        __syncthreads();
        m = red[0];
        for (int w = 1; w < 8; ++w) m = fmaxf(m, red[w]);
        float p0 = (tid < 512) ? expf(e0 - m) : 0.f;
        float s = p0;
        for (int o = 32; o; o >>= 1) s += __shfl_xor(s, o);
        __syncthreads();
        if (lane == 0) red[wv] = s;
        __syncthreads();
        float tot = red[0];
        for (int w = 1; w < 8; ++w) tot += red[w];
        float inv = 1.f / tot;
        float a0 = p0 * inv;
        if (tid < 512) alpha[tid] = a0;
        unsigned long long mk = __ballot(tid < 512 && a0 > EPS_A);
        if (lane == 0 && wv < 8) wc[wv] = (int)__popcll(mk);
        __syncthreads();
        int base = 0;
        for (int w = 0; w < wv && w < 8; ++w) base += wc[w];
        int n = 0;
        for (int w = 0; w < 8; ++w) n += wc[w];
        unsigned long long below = (1ull << lane) - 1ull;
        if (tid < 512 && a0 > EPS_A) {
          int p = base + (int)__popcll(mk & below);
          li[p] = (short)tid; lv[p] = a0;
        }
        __syncthreads();
        const float* encb = A.enc + (size_t)b * 512 * 768;
        if (tid < 768) {
          float acc = 0.f;
          int i = 0;
          for (; i + 4 <= n; i += 4) {
            float v0 = encb[(size_t)li[i] * 768 + tid];
            float v1 = encb[(size_t)li[i+1] * 768 + tid];
            float v2 = encb[(size_t)li[i+2] * 768 + tid];
            float v3 = encb[(size_t)li[i+3] * 768 + tid];
            acc = fmaf(lv[i],v0, fmaf(lv[i+1],v1, fmaf(lv[i+2],v2, fmaf(lv[i+3],v3, acc))));
          }
          for (; i < n; ++i) acc = fmaf(lv[i], encb[(size_t)li[i] * 768 + tid], acc);
          ctx[tid] = acc;
          gst(ws + OFF_CTXB + b * 768 + tid, acc);
        }
      }
      postw(fl, 0, (unsigned)(t + 1));
      // ---- S12: x = lw @ [ctx; hatt] + lb (256 j x 4 parts) ----
      {
        int j = tid >> 2, part = tid & 3;
        const float* xsrc = (part < 3) ? (ctx + part * 256) : hatt;
        const float4* wr = (const float4*)(A.lw + (size_t)j * 1024 + part * 256);
        const float4* xr = (const float4*)xsrc;
        float a = 0.f;
#pragma unroll 8
        for (int k4 = 0; k4 < 64; ++k4) { float4 av = xr[k4], wv = wr[k4]; FMA4(a, av, wv); }
        a += __shfl_xor(a, 1); a += __shfl_xor(a, 2);
        if (part == 0) x[j] = a + A.lb[j];
      }
      // ---- S13: GRU1 ----
      if (tid < GN_G1H) pollge<2>(fl, GB_G1H + tid, 0, (unsigned)(t + 1));
      __syncthreads();
      if (tid < 768) {
        const float4* wr = (const float4*)(A.g1wi + (size_t)tid * 256);
        const float4* xr = (const float4*)x;
        float a = 0.f;
#pragma unroll 8
        for (int k4 = 0; k4 < 64; ++k4) { float4 av = xr[k4], wv = wr[k4]; FMA4(a, av, wv); }
        sgi[tid] = a + A.g1bi[tid];
        sgh[tid] = gld(ws + OFF_G1HB + b * 768 + tid) + A.g1bh[tid];
      }
      __syncthreads();
      if (tid < 256) {
        float r = sigm(sgi[tid] + sgh[tid]);
        float z = sigm(sgi[256 + tid] + sgh[256 + tid]);
        float n = tanhf(sgi[512 + tid] + r * sgh[512 + tid]);
        float hnew = (1.f - z) * n + z * h1[tid];
        h1[tid] = hnew;
        gst(ws + OFF_H1B + b * 256 + tid, hnew);
        x2[tid] = x[tid] + hnew;
      }
      postw(fl, 2, (unsigned)(t + 1));
      // ---- S14: GRU2 ----
      if (tid < GN_G2H) pollge<2>(fl, GB_G2H + tid, 0, (unsigned)(t + 1));
      __syncthreads();
      if (tid < 768) {
        const float4* wr = (const float4*)(A.g2wi + (size_t)tid * 256);
        const float4* xr = (const float4*)x2;
        float a = 0.f;
#pragma unroll 8
        for (int k4 = 0; k4 < 64; ++k4) { float4 av = xr[k4], wv = wr[k4]; FMA4(a, av, wv); }
        sgi[tid] = a + A.g2bi[tid];
        sgh[tid] = gld(ws + OFF_G2HB + b * 768 + tid) + A.g2bh[tid];
      }
      __syncthreads();
      if (tid < 256) {
        float r = sigm(sgi[tid] + sgh[tid]);
        float z = sigm(sgi[256 + tid] + sgh[256 + tid]);
        float n = tanhf(sgi[512 + tid] + r * sgh[512 + tid]);
        float hnew = (1.f - z) * n + z * h2[tid];
        h2[tid] = hnew;
        gst(ws + OFF_H2B + b * 256 + tid, hnew);
        x3[tid] = x2[tid] + hnew;
      }
      postw(fl, 3, (unsigned)(t + 1));
      // ---- S15: proj -> dout + next frame (400 j x 2 parts) ----
      if (tid < 800) {
        int j = tid >> 1, part = tid & 1;
        const float4* wr = (const float4*)(A.prw + (size_t)j * 256 + part * 128);
        const float4* xr = (const float4*)(x3 + part * 128);
        float a = 0.f;
#pragma unroll 8
        for (int k4 = 0; k4 < 32; ++k4) { float4 av = xr[k4], wv = wr[k4]; FMA4(a, av, wv); }
        a += __shfl_xor(a, 1);
        if (part == 0) {
          float v = a + A.prb[j];
          fr[j] = v;
          A.dout[(size_t)b * 100000 + (j / 5) * 1250 + t * 5 + (j % 5)] = v;
        }
      }
      __syncthreads();
    }
  } else {
    // =================== helpers: state-dependent GEMMs, off critical path ===================
    int j0, nj, K, word;
    const float* W; int wstr; const float* act; float* out;
    if (blk < GB_GA)       { int rb = blk - GB_GI;  j0 = rb * 16; nj = 16; K = 768; W = A.awi;  wstr = 896; act = ws + OFF_CTXB;  out = ws + OFF_GIB;  word = 0; }
    else if (blk < GB_G1H) { int rb = blk - GB_GA;  j0 = rb * 48; nj = 48; K = 256; W = A.awh;  wstr = 256; act = ws + OFF_HATTB; out = ws + OFF_GAB;  word = 1; }
    else if (blk < GB_G2H) { int rb = blk - GB_G1H; j0 = rb * 48; nj = 48; K = 256; W = A.g1wh; wstr = 256; act = ws + OFF_H1B;   out = ws + OFF_G1HB; word = 2; }
    else                   { int rb = blk - GB_G2H; j0 = rb * 48; nj = 48; K = 256; W = A.g2wh; wstr = 256; act = ws + OFF_H2B;   out = ws + OFF_G2HB; word = 3; }
    const int r = tid & 63, jq = tid >> 6;
    for (int t = 0; t < TDEC; ++t) {
      if (t > 0 && tid < 64) pollge<16>(fl, tid, word, (unsigned)t);
      __syncthreads();
      float acc0 = 0.f, acc1 = 0.f, acc2 = 0.f;
      for (int kc = 0; kc < K; kc += 128) {
        __syncthreads();
        for (int idx = tid; idx < 8192; idx += 1024) {
          int rr = idx >> 7, k = idx & 127;
          sm[rr * 132 + k] = gld(act + rr * K + kc + k);
        }
        __syncthreads();
        const float4* ar = (const float4*)(sm + r * 132);
        {
          const float4* wr = (const float4*)(W + (size_t)(j0 + jq) * wstr + kc);
          float a = acc0;
#pragma unroll 8
          for (int k4 = 0; k4 < 32; ++k4) { float4 av = ar[k4], wv = wr[k4]; FMA4(a, av, wv); }
          acc0 = a;
        }
        if (nj > 16) {
          const float4* wr1 = (const float4*)(W + (size_t)(j0 + jq + 16) * wstr + kc);
          const float4* wr2 = (const float4*)(W + (size_t)(j0 + jq + 32) * wstr + kc);
          float a1 = acc1, a2 = acc2;
#pragma unroll 8
          for (int k4 = 0; k4 < 32; ++k4) {
            float4 av = ar[k4];
            float4 w1 = wr1[k4], w2 = wr2[k4];
            FMA4(a1, av, w1); FMA4(a2, av, w2);
          }
          acc1 = a1; acc2 = a2;
        }
      }
      gst(out + r * 768 + j0 + jq, acc0);
      if (nj > 16) {
        gst(out + r * 768 + j0 + jq + 16, acc1);
        gst(out + r * 768 + j0 + jq + 32, acc2);
      }
      postw(fl, 0, (unsigned)(t + 1));
    }
  }
}

// ---------------- host ----------------
extern "C" void kernel_launch(void* const* d_in, const int* in_sizes, int n_in,
                              void* d_out, int out_size, void* d_ws, size_t ws_size,
                              hipStream_t stream) {
  (void)in_sizes; (void)n_in; (void)out_size; (void)ws_size;
  KArgs A;
  A.enc  = (const float*)d_in[0];
  A.p1w  = (const float*)d_in[1];  A.p1b  = (const float*)d_in[2];
  A.p2w  = (const float*)d_in[3];  A.p2b  = (const float*)d_in[4];
  A.awi  = (const float*)d_in[5];  A.abi  = (const float*)d_in[6];
  A.awh  = (const float*)d_in[7];  A.abh  = (const float*)d_in[8];
  A.dWw  = (const float*)d_in[9];  A.dWb  = (const float*)d_in[10];
  A.dVw  = (const float*)d_in[11]; A.dFw  = (const float*)d_in[12];
  A.dUw  = (const float*)d_in[13]; A.dTw  = (const float*)d_in[14];
  A.dTb  = (const float*)d_in[15]; A.dvw  = (const float*)d_in[16];
  A.lw   = (const float*)d_in[17]; A.lb   = (const float*)d_in[18];
  A.g1wi = (const float*)d_in[19]; A.g1bi = (const float*)d_in[20];
  A.g1wh = (const float*)d_in[21]; A.g1bh = (const float*)d_in[22];
  A.g2wi = (const float*)d_in[23]; A.g2bi = (const float*)d_in[24];
  A.g2wh = (const float*)d_in[25]; A.g2bh = (const float*)d_in[26];
  A.prw  = (const float*)d_in[27]; A.prb  = (const float*)d_in[28];
  A.ws   = (float*)d_ws;
  A.dout = (float*)d_out;

  // beta-binomial prior pmf (n=10, a=0.1, b=0.9), flipped
  {
    double aP = 0.1, bP = 0.9;
    double logB0 = lgamma(aP) + lgamma(bP) - lgamma(aP + bP);
    double pm[11];
    for (int k = 0; k <= 10; ++k) {
      double logC = lgamma(11.0) - lgamma(k + 1.0) - lgamma(11.0 - k);
      double logBt = lgamma(k + aP) + lgamma(10.0 - k + bP) - lgamma(10.0 + aP + bP);
      pm[k] = exp(logC + logBt - logB0);
    }
    for (int k = 0; k < 11; ++k) A.pr.v[k] = (float)pm[10 - k];
  }

  k_init<<<256, 256, 0, stream>>>((float*)d_ws);
  k_decode<<<NBLK, 1024, 0, stream>>>(A);
}

// Round 10
// 48761.221 us; speedup vs baseline: 8.2403x; 1.0308x over previous
//
#include <hip/hip_runtime.h>
#include <cmath>

#define TDEC 250
#define EPS_A 1e-6f

// ---------------- ws float offsets (flags in words 0..8191) ----------------
#define B_CTX(p)   (8192   + (p)*49152)   // [64][768]
#define B_HATT(p)  (106496 + (p)*16384)   // [64][256]
#define B_H1(p)    (139264 + (p)*16384)
#define B_H2(p)    (172032 + (p)*16384)
#define B_X(p)     (204800 + (p)*16384)
#define B_X2(p)    (237568 + (p)*16384)
#define B_X3(p)    (270336 + (p)*16384)
#define B_FR(p)    (303104 + (p)*25600)   // [64][400]
#define B_H1S(p)   (354304 + (p)*16384)
#define B_PRE(p)   (387072 + (p)*8192)    // [64][128]
#define B_GIC(p)   (403456 + (p)*49152)
#define B_GIP(p)   (501760 + (p)*49152)
#define B_GH(p)    (600064 + (p)*49152)
#define ZERO_END   354304

struct Prior { float v[11]; };

struct KArgs {
  const float *enc;
  const float *p1w,*p1b,*p2w,*p2b;
  const float *awi,*abi,*awh,*abh;
  const float *dWw,*dWb,*dVw,*dFw,*dUw,*dTw,*dTb,*dvw;
  const float *lw,*lb;
  const float *g1wi,*g1bi,*g1wh,*g1bh;
  const float *g2wi,*g2bi,*g2wh,*g2bh;
  const float *prw,*prb;
  float* ws; float* dout;
  Prior pr;
};

#define FMA4(a, av, wv) a = fmaf((av).x,(wv).x, fmaf((av).y,(wv).y, fmaf((av).z,(wv).z, fmaf((av).w,(wv).w,(a)))))

__device__ __forceinline__ float gld(const float* p) {
  return __uint_as_float(__hip_atomic_load((const unsigned*)p, __ATOMIC_RELAXED, __HIP_MEMORY_SCOPE_AGENT));
}
__device__ __forceinline__ void gst(float* p, float v) {
  __hip_atomic_store((unsigned*)p, __float_as_uint(v), __ATOMIC_RELAXED, __HIP_MEMORY_SCOPE_AGENT);
}
__device__ __forceinline__ float sigm(float x) { return 1.f / (1.f + expf(-x)); }

__global__ __launch_bounds__(256) void k_init(float* ws) {
  int idx = blockIdx.x * 256 + threadIdx.x;
  for (int i = idx; i < ZERO_END; i += gridDim.x * 256) ws[i] = 0.f;
}

__device__ __forceinline__ void postw(unsigned* fl, int word, unsigned v) {
  asm volatile("s_waitcnt vmcnt(0)" ::: "memory");
  __syncthreads();
  if (threadIdx.x == 0)
    __hip_atomic_store(&fl[blockIdx.x * 32 + word], v, __ATOMIC_RELAXED, __HIP_MEMORY_SCOPE_AGENT);
}
template <int SLP>
__device__ __forceinline__ void pollge(unsigned* fl, int line, int word, unsigned v) {
  while (__hip_atomic_load(&fl[line * 32 + word], __ATOMIC_RELAXED, __HIP_MEMORY_SCOPE_AGENT) < v)
    __builtin_amdgcn_s_sleep(SLP);
}

// ---------------- GRU block group (32 blocks: 4bg x 8jg, 16b x 32j) -------------
__device__ void gru_block(const KArgs& A, float* sm, unsigned* fl, float* ws,
                          int bg, int jg, int selfL0, int prodL0,
                          const float* Wh, const float* Wi, const float* bi, const float* bh,
                          int offH0, int offXin0, int offXout0) {
  const int tid = threadIdx.x;
  const int B = bg * 16, J0 = jg * 32;
  float* hp   = sm;          // [16][260]
  float* gh1l = sm + 4160;   // [96][16]
  float* xs   = sm + 5696;   // [16][260]
  float* gil  = sm + 9856;   // [96][16]
  for (int t = 0; t < TDEC; ++t) {
    const int p = t & 1;
    // shadow: gh = Wh @ h(t-1)
    if (tid < 8) pollge<4>(fl, selfL0 + tid, 0, (unsigned)t);
    __syncthreads();
    for (int idx = tid; idx < 4096; idx += 1024) {
      int bb = idx >> 8, k = idx & 255;
      hp[bb * 260 + k] = gld(ws + offH0 + (p ^ 1) * 16384 + (B + bb) * 256 + k);
    }
    __syncthreads();
#pragma unroll
    for (int pass = 0; pass < 2; ++pass) {
      if (tid < 768) {
        int lr = pass * 48 + (tid >> 4), bb = tid & 15;
        int wrow = (lr >> 5) * 256 + J0 + (lr & 31);
        const float4* wr = (const float4*)(Wh + (size_t)wrow * 256);
        const float4* xr = (const float4*)(hp + bb * 260);
        float a = 0.f;
#pragma unroll 8
        for (int k4 = 0; k4 < 64; ++k4) { float4 av = xr[k4], wv = wr[k4]; FMA4(a, av, wv); }
        gh1l[lr * 16 + bb] = a + bh[wrow];
      }
    }
    // main: wait x
    if (tid < 8) pollge<1>(fl, prodL0 + tid, 0, (unsigned)(t + 1));
    __syncthreads();
    for (int idx = tid; idx < 4096; idx += 1024) {
      int bb = idx >> 8, k = idx & 255;
      xs[bb * 260 + k] = gld(ws + offXin0 + p * 16384 + (B + bb) * 256 + k);
    }
    __syncthreads();
#pragma unroll
    for (int pass = 0; pass < 2; ++pass) {
      if (tid < 768) {
        int lr = pass * 48 + (tid >> 4), bb = tid & 15;
        int wrow = (lr >> 5) * 256 + J0 + (lr & 31);
        const float4* wr = (const float4*)(Wi + (size_t)wrow * 256);
        const float4* xr = (const float4*)(xs + bb * 260);
        float a = 0.f;
#pragma unroll 8
        for (int k4 = 0; k4 < 64; ++k4) { float4 av = xr[k4], wv = wr[k4]; FMA4(a, av, wv); }
        gil[lr * 16 + bb] = a + bi[wrow];
      }
    }
    __syncthreads();
    if (tid < 512) {
      int lj = tid >> 4, bb = tid & 15;
      float r = sigm(gil[lj * 16 + bb] + gh1l[lj * 16 + bb]);
      float z = sigm(gil[(32 + lj) * 16 + bb] + gh1l[(32 + lj) * 16 + bb]);
      float n = tanhf(gil[(64 + lj) * 16 + bb] + r * gh1l[(64 + lj) * 16 + bb]);
      float hprev = hp[bb * 260 + J0 + lj];
      float hnew = (1.f - z) * n + z * hprev;
      gst(ws + offH0 + p * 16384 + (B + bb) * 256 + J0 + lj, hnew);
      gst(ws + offXout0 + p * 16384 + (B + bb) * 256 + J0 + lj, xs[bb * 260 + J0 + lj] + hnew);
    }
    postw(fl, 0, (unsigned)(t + 1));
  }
}

// ---------------- the persistent decoder ----------------
__global__ __launch_bounds__(1024, 1) void k_decode(KArgs A) {
  __shared__ __align__(16) float sm[30208];
  float* ws = A.ws;
  unsigned* fl = (unsigned*)ws;
  const int blk = blockIdx.x;
  const int tid = threadIdx.x;

  if (blk < 64) {
    // =================== MEGA: attention core, per-b ===================
    const int b = blk, bg = b >> 4;
    float* alpha = sm;            // 512
    float* hattl = sm + 512;      // 256
    float* sal   = sm + 768;      // 544
    float* sgi   = sm + 1312;     // 768
    float* sgh   = sm + 2080;     // 768
    float* t1    = sm + 2848;     // 128
    float* Gl    = sm + 2976;     // 176
    float* sdF   = sm + 3152;     // 176
    float* sdU   = sm + 3328;     // 1024
    float* sdT   = sm + 4352;     // 1024
    float* sdtb  = sm + 5376;     // 128
    float* sdv   = sm + 5504;     // 128
    float* es    = sm + 5632;     // 1024
    float* e     = sm + 6656;     // 512
    float* red   = sm + 7168;     // 16
    int*   wc    = (int*)(sm + 7184); // 8
    float* lv    = sm + 7192;     // 512
    short* li    = (short*)(sm + 7704); // 512 shorts (256 floats)
    float* sdV   = sm + 7960;     // 168 x 132 = 22176

    if (tid < 512) alpha[tid] = (tid == 0) ? 1.f : 0.f;
    if (tid < 256) hattl[tid] = 0.f;
    if (tid < 176) sdF[tid] = (tid < 168) ? A.dFw[tid] : 0.f;
    sdU[tid] = A.dUw[tid];
    sdT[tid] = A.dTw[tid];
    if (tid < 128) { sdtb[tid] = A.dTb[tid]; sdv[tid] = A.dvw[tid]; }
    for (int i = tid; i < 21504; i += 1024) sdV[(i >> 7) * 132 + (i & 127)] = A.dVw[i];
    __syncthreads();

    for (int t = 0; t < TDEC; ++t) {
      const int p = t & 1;
      if (tid < 544) { int sg = tid - 10; sal[tid] = (sg >= 0 && sg < 512) ? alpha[sg] : 0.f; }
      if (tid >= 576 && tid < 584) pollge<1>(fl, 216 + bg * 8 + (tid - 576), 0, (unsigned)(t + 1));
      else if (tid >= 584 && tid < 588) pollge<1>(fl, 200 + bg * 4 + (tid - 584), 0, (unsigned)(t + 1));
      else if (tid >= 588 && tid < 590) pollge<1>(fl, 248 + bg * 2 + (tid - 588), 0, (unsigned)(t + 1));
      __syncthreads();
      if (tid < 768) {
        sgi[tid] = gld(ws + B_GIC(p) + b * 768 + tid) + gld(ws + B_GIP(p) + b * 768 + tid) + A.abi[tid];
        sgh[tid] = gld(ws + B_GH(p) + b * 768 + tid) + A.abh[tid];
      }
      __syncthreads();
      if (tid < 256) {
        float r = sigm(sgi[tid] + sgh[tid]);
        float z = sigm(sgi[256 + tid] + sgh[256 + tid]);
        float n = tanhf(sgi[512 + tid] + r * sgh[512 + tid]);
        float hnew = (1.f - z) * n + z * hattl[tid];
        hattl[tid] = hnew;
        gst(ws + B_HATT(p) + b * 256 + tid, hnew);
      }
      postw(fl, 1, (unsigned)(t + 1));
      // t1 = tanh(dW @ hatt + dWb): 128 j x 8 interleaved parts
      {
        int j = tid >> 3, part = tid & 7;
        const float4* wr = (const float4*)(A.dWw + (size_t)j * 256);
        const float4* xr = (const float4*)hattl;
        float a = 0.f;
#pragma unroll
        for (int kk = 0; kk < 8; ++kk) {
          int i4 = part + kk * 8;
          float4 av = xr[i4], wv = wr[i4];
          FMA4(a, av, wv);
        }
        a += __shfl_xor(a, 1); a += __shfl_xor(a, 2); a += __shfl_xor(a, 4);
        if (part == 0) t1[j] = tanhf(a + A.dWb[j]);
      }
      __syncthreads();
      // G = dV @ t1 (dV in LDS)
      if (tid < 168) {
        const float4* wr = (const float4*)(sdV + tid * 132);
        const float4* xr = (const float4*)t1;
        float a = 0.f;
#pragma unroll 8
        for (int k4 = 0; k4 < 32; ++k4) { float4 av = xr[k4], wv = wr[k4]; FMA4(a, av, wv); }
        Gl[tid] = a;
      }
      __syncthreads();
      // static+dynamic conv fused with energy MLP
      {
        int sl = tid >> 1, half = tid & 1;
        float f0[8], g0[8];
#pragma unroll
        for (int q = 0; q < 8; ++q) {
          float fa = 0.f, ga = 0.f;
#pragma unroll
          for (int k = 0; k < 21; ++k) {
            float a = sal[sl + k];
            fa = fmaf(sdF[q * 21 + k], a, fa);
            ga = fmaf(Gl[q * 21 + k], a, ga);
          }
          f0[q] = fa; g0[q] = ga;
        }
        float acc = 0.f;
        for (int cc = half * 64; cc < half * 64 + 64; ++cc) {
          float a = sdtb[cc];
#pragma unroll
          for (int q = 0; q < 8; ++q)
            a = fmaf(sdU[cc * 8 + q], f0[q], fmaf(sdT[cc * 8 + q], g0[q], a));
          acc = fmaf(sdv[cc], tanhf(a), acc);
        }
        es[sl * 2 + half] = acc;
      }
      __syncthreads();
      if (tid < 512) {
        float pr = 0.f;
#pragma unroll
        for (int k = 0; k < 11; ++k) pr = fmaf(A.pr.v[k], sal[tid + k], pr);
        e[tid] = es[tid * 2] + es[tid * 2 + 1] + logf(fmaxf(pr, 1e-6f));
      }
      __syncthreads();
      // softmax + compaction + sparse ctx
      {
        int lane = tid & 63, wv = tid >> 6;
        float e0 = (tid < 512) ? e[tid] : -1e30f;
        float m = e0;
        for (int o = 32; o; o >>= 1) m = fmaxf(m, __shfl_xor(m, o));
        if (lane == 0) red[wv] = m;
        __syncthreads();
        m = red[0];
        for (int w = 1; w < 8; ++w) m = fmaxf(m, red[w]);
        float p0 = (tid < 512) ? expf(e0 - m) : 0.f;
        float s = p0;
        for (int o = 32; o; o >>= 1) s += __shfl_xor(s, o);
        __syncthreads();
        if (lane == 0) red[wv] = s;
        __syncthreads();
        float tot = red[0];
        for (int w = 1; w < 8; ++w) tot += red[w];
        float inv = 1.f / tot;
        float a0 = p0 * inv;
        if (tid < 512) alpha[tid] = a0;
        unsigned long long mk = __ballot(tid < 512 && a0 > EPS_A);
        if (lane == 0 && wv < 8) wc[wv] = (int)__popcll(mk);
        __syncthreads();
        int base = 0;
        for (int w = 0; w < wv && w < 8; ++w) base += wc[w];
        int n = 0;
        for (int w = 0; w < 8; ++w) n += wc[w];
        unsigned long long below = (1ull << lane) - 1ull;
        if (tid < 512 && a0 > EPS_A) {
          int pp = base + (int)__popcll(mk & below);
          li[pp] = (short)tid; lv[pp] = a0;
        }
        __syncthreads();
        const float* encb = A.enc + (size_t)b * 512 * 768;
        if (tid < 768) {
          float acc = 0.f;
          int i = 0;
          for (; i + 4 <= n; i += 4) {
            float v0 = encb[(size_t)li[i] * 768 + tid];
            float v1 = encb[(size_t)li[i+1] * 768 + tid];
            float v2 = encb[(size_t)li[i+2] * 768 + tid];
            float v3 = encb[(size_t)li[i+3] * 768 + tid];
            acc = fmaf(lv[i],v0, fmaf(lv[i+1],v1, fmaf(lv[i+2],v2, fmaf(lv[i+3],v3, acc))));
          }
          for (; i < n; ++i) acc = fmaf(lv[i], encb[(size_t)li[i] * 768 + tid], acc);
          gst(ws + B_CTX(p) + b * 768 + tid, acc);
        }
      }
      postw(fl, 0, (unsigned)(t + 1));
    }
  } else if (blk < 96) {
    // ---- LW: x = lw @ [ctx; hatt] + lb ----
    int rb = blk - 64, bg = rb >> 3, jg = rb & 7;
    int B = bg * 16, J0 = jg * 32;
    float* act = sm;   // [16][1028]
    for (int t = 0; t < TDEC; ++t) {
      const int p = t & 1;
      if (tid < 16) pollge<1>(fl, bg * 16 + tid, 0, (unsigned)(t + 1));
      __syncthreads();
      for (int idx = tid; idx < 16384; idx += 1024) {
        int bb = idx >> 10, k = idx & 1023;
        float v = (k < 768) ? gld(ws + B_CTX(p) + (B + bb) * 768 + k)
                            : gld(ws + B_HATT(p) + (B + bb) * 256 + k - 768);
        act[bb * 1028 + k] = v;
      }
      __syncthreads();
      {
        int lj = tid >> 5, bb = (tid >> 1) & 15, part = tid & 1;
        const float4* wr = (const float4*)(A.lw + (size_t)(J0 + lj) * 1024 + part * 512);
        const float4* xr = (const float4*)(act + bb * 1028 + part * 512);
        float a = 0.f;
#pragma unroll 8
        for (int k4 = 0; k4 < 128; ++k4) { float4 av = xr[k4], wv = wr[k4]; FMA4(a, av, wv); }
        a += __shfl_xor(a, 1);
        if (part == 0) gst(ws + B_X(p) + (B + bb) * 256 + J0 + lj, a + A.lb[J0 + lj]);
      }
      postw(fl, 0, (unsigned)(t + 1));
    }
  } else if (blk < 128) {
    int rb = blk - 96;
    gru_block(A, sm, fl, ws, rb >> 3, rb & 7, 96 + (rb >> 3) * 8, 64 + (rb >> 3) * 8,
              A.g1wh, A.g1wi, A.g1bi, A.g1bh, B_H1(0), B_X(0), B_X2(0));
  } else if (blk < 160) {
    int rb = blk - 128;
    gru_block(A, sm, fl, ws, rb >> 3, rb & 7, 128 + (rb >> 3) * 8, 96 + (rb >> 3) * 8,
              A.g2wh, A.g2wi, A.g2bi, A.g2bh, B_H2(0), B_X2(0), B_X3(0));
  } else if (blk < 176) {
    // ---- PROJ: frame(t+1) = prw @ x3 + prb; dout row t ----
    int rb = blk - 160, bg = rb >> 2, jg = rb & 3;
    int B = bg * 16, J0 = jg * 100;
    float* xs = sm;   // [16][260]
    for (int t = 0; t < TDEC; ++t) {
      const int p = t & 1;
      if (tid < 8) pollge<1>(fl, 128 + bg * 8 + tid, 0, (unsigned)(t + 1));
      __syncthreads();
      for (int idx = tid; idx < 4096; idx += 1024) {
        int bb = idx >> 8, k = idx & 255;
        xs[bb * 260 + k] = gld(ws + B_X3(p) + (B + bb) * 256 + k);
      }
      __syncthreads();
#pragma unroll
      for (int pass = 0; pass < 2; ++pass) {
        int bb = pass * 8 + (tid & 7), lj = tid >> 3;
        if (lj < 100) {
          int row = J0 + lj;
          const float4* wr = (const float4*)(A.prw + (size_t)row * 256);
          const float4* xr = (const float4*)(xs + bb * 260);
          float a = 0.f;
#pragma unroll 8
          for (int k4 = 0; k4 < 64; ++k4) { float4 av = xr[k4], wv = wr[k4]; FMA4(a, av, wv); }
          float v = a + A.prb[row];
          gst(ws + B_FR((t + 1) & 1) + (B + bb) * 400 + row, v);
          A.dout[(size_t)(B + bb) * 100000 + (row / 5) * 1250 + t * 5 + (row % 5)] = v;
        }
      }
      postw(fl, 0, (unsigned)(t + 1));
    }
  } else if (blk < 192) {
    // ---- PRE1: h1s = relu(p1w @ frame + p1b) ----
    int rb = blk - 176, bg = rb >> 2, jg = rb & 3;
    int B = bg * 16, J0 = jg * 64;
    float* frl = sm;  // [16][404]
    for (int t = 0; t < TDEC; ++t) {
      const int p = t & 1;
      if (tid < 4) pollge<1>(fl, 160 + bg * 4 + tid, 0, (unsigned)t);
      __syncthreads();
      for (int idx = tid; idx < 6400; idx += 1024) {
        int bb = idx / 400, k = idx - bb * 400;
        frl[bb * 404 + k] = gld(ws + B_FR(p) + (B + bb) * 400 + k);
      }
      __syncthreads();
      {
        int bb = tid & 15, lj = tid >> 4;
        int row = J0 + lj;
        const float4* wr = (const float4*)(A.p1w + (size_t)row * 400);
        const float4* xr = (const float4*)(frl + bb * 404);
        float a = 0.f;
#pragma unroll 8
        for (int k4 = 0; k4 < 100; ++k4) { float4 av = xr[k4], wv = wr[k4]; FMA4(a, av, wv); }
        gst(ws + B_H1S(p) + (B + bb) * 256 + row, fmaxf(a + A.p1b[row], 0.f));
      }
      postw(fl, 0, (unsigned)(t + 1));
    }
  } else if (blk < 200) {
    // ---- PRE2: pre = relu(p2w @ h1s + p2b) ----
    int rb = blk - 192, bg = rb >> 1, jg = rb & 1;
    int B = bg * 16, J0 = jg * 64;
    float* hl = sm;  // [16][260]
    for (int t = 0; t < TDEC; ++t) {
      const int p = t & 1;
      if (tid < 4) pollge<1>(fl, 176 + bg * 4 + tid, 0, (unsigned)(t + 1));
      __syncthreads();
      for (int idx = tid; idx < 4096; idx += 1024) {
        int bb = idx >> 8, k = idx & 255;
        hl[bb * 260 + k] = gld(ws + B_H1S(p) + (B + bb) * 256 + k);
      }
      __syncthreads();
      {
        int bb = tid & 15, lj = tid >> 4;
        int row = J0 + lj;
        const float4* wr = (const float4*)(A.p2w + (size_t)row * 256);
        const float4* xr = (const float4*)(hl + bb * 260);
        float a = 0.f;
#pragma unroll 8
        for (int k4 = 0; k4 < 64; ++k4) { float4 av = xr[k4], wv = wr[k4]; FMA4(a, av, wv); }
        gst(ws + B_PRE(p) + (B + bb) * 128 + row, fmaxf(a + A.p2b[row], 0.f));
      }
      postw(fl, 0, (unsigned)(t + 1));
    }
  } else if (blk < 216) {
    // ---- GIPREp: gip = awi[:,768:] @ pre ----
    int rb = blk - 200, bg = rb >> 2, jg = rb & 3;
    int B = bg * 16, R0 = jg * 192;
    float* pl = sm;  // [16][132]
    for (int t = 0; t < TDEC; ++t) {
      const int p = t & 1;
      if (tid < 2) pollge<1>(fl, 192 + bg * 2 + tid, 0, (unsigned)(t + 1));
      __syncthreads();
      for (int idx = tid; idx < 2048; idx += 1024) {
        int bb = idx >> 7, k = idx & 127;
        pl[bb * 132 + k] = gld(ws + B_PRE(p) + (B + bb) * 128 + k);
      }
      __syncthreads();
#pragma unroll
      for (int pass = 0; pass < 3; ++pass) {
        int rr = pass * 64 + (tid >> 4), bb = tid & 15;
        int row = R0 + rr;
        const float4* wr = (const float4*)(A.awi + (size_t)row * 896 + 768);
        const float4* xr = (const float4*)(pl + bb * 132);
        float a = 0.f;
#pragma unroll 8
        for (int k4 = 0; k4 < 32; ++k4) { float4 av = xr[k4], wv = wr[k4]; FMA4(a, av, wv); }
        gst(ws + B_GIP(p) + (B + bb) * 768 + row, a);
      }
      postw(fl, 0, (unsigned)(t + 1));
    }
  } else if (blk < 248) {
    // ---- GIPREc: gic = awi[:, :768] @ ctx(t-1)  (shadow) ----
    int rb = blk - 216, bg = rb >> 3, jg = rb & 7;
    int B = bg * 16, R0 = jg * 96;
    float* cl = sm;  // [16][772]
    for (int t = 0; t < TDEC; ++t) {
      const int p = t & 1;
      if (tid < 16) pollge<4>(fl, bg * 16 + tid, 0, (unsigned)t);
      __syncthreads();
      for (int idx = tid; idx < 12288; idx += 1024) {
        int bb = idx / 768, k = idx - bb * 768;
        cl[bb * 772 + k] = gld(ws + B_CTX(p ^ 1) + (B + bb) * 768 + k);
      }
      __syncthreads();
#pragma unroll
      for (int pass = 0; pass < 2; ++pass) {
        if (tid < 768) {
          int rr = pass * 48 + (tid >> 4), bb = tid & 15;
          int row = R0 + rr;
          const float4* wr = (const float4*)(A.awi + (size_t)row * 896);
          const float4* xr = (const float4*)(cl + bb * 772);
          float a = 0.f;
#pragma unroll 8
          for (int k4 = 0; k4 < 192; ++k4) { float4 av = xr[k4], wv = wr[k4]; FMA4(a, av, wv); }
          gst(ws + B_GIC(p) + (B + bb) * 768 + row, a);
        }
      }
      postw(fl, 0, (unsigned)(t + 1));
    }
  } else {
    // ---- GA: gh = awh @ hatt(t-1)  (shadow) ----
    int rb = blk - 248, bg = rb >> 1, jg = rb & 1;
    int B = bg * 16, R0 = jg * 384;
    float* hl = sm;  // [16][260]
    for (int t = 0; t < TDEC; ++t) {
      const int p = t & 1;
      if (tid < 16) pollge<4>(fl, bg * 16 + tid, 1, (unsigned)t);
      __syncthreads();
      for (int idx = tid; idx < 4096; idx += 1024) {
        int bb = idx >> 8, k = idx & 255;
        hl[bb * 260 + k] = gld(ws + B_HATT(p ^ 1) + (B + bb) * 256 + k);
      }
      __syncthreads();
#pragma unroll
      for (int pass = 0; pass < 6; ++pass) {
        int rr = pass * 64 + (tid >> 4), bb = tid & 15;
        int row = R0 + rr;
        const float4* wr = (const float4*)(A.awh + (size_t)row * 256);
        const float4* xr = (const float4*)(hl + bb * 260);
        float a = 0.f;
#pragma unroll 8
        for (int k4 = 0; k4 < 64; ++k4) { float4 av = xr[k4], wv = wr[k4]; FMA4(a, av, wv); }
        gst(ws + B_GH(p) + (B + bb) * 768 + row, a);
      }
      postw(fl, 0, (unsigned)(t + 1));
    }
  }
}

// ---------------- host ----------------
extern "C" void kernel_launch(void* const* d_in, const int* in_sizes, int n_in,
                              void* d_out, int out_size, void* d_ws, size_t ws_size,
                              hipStream_t stream) {
  (void)in_sizes; (void)n_in; (void)out_size; (void)ws_size;
  KArgs A;
  A.enc  = (const float*)d_in[0];
  A.p1w  = (const float*)d_in[1];  A.p1b  = (const float*)d_in[2];
  A.p2w  = (const float*)d_in[3];  A.p2b  = (const float*)d_in[4];
  A.awi  = (const float*)d_in[5];  A.abi  = (const float*)d_in[6];
  A.awh  = (const float*)d_in[7];  A.abh  = (const float*)d_in[8];
  A.dWw  = (const float*)d_in[9];  A.dWb  = (const float*)d_in[10];
  A.dVw  = (const float*)d_in[11]; A.dFw  = (const float*)d_in[12];
  A.dUw  = (const float*)d_in[13]; A.dTw  = (const float*)d_in[14];
  A.dTb  = (const float*)d_in[15]; A.dvw  = (const float*)d_in[16];
  A.lw   = (const float*)d_in[17]; A.lb   = (const float*)d_in[18];
  A.g1wi = (const float*)d_in[19]; A.g1bi = (const float*)d_in[20];
  A.g1wh = (const float*)d_in[21]; A.g1bh = (const float*)d_in[22];
  A.g2wi = (const float*)d_in[23]; A.g2bi = (const float*)d_in[24];
  A.g2wh = (const float*)d_in[25]; A.g2bh = (const float*)d_in[26];
  A.prw  = (const float*)d_in[27]; A.prb  = (const float*)d_in[28];
  A.ws   = (float*)d_ws;
  A.dout = (float*)d_out;

  // beta-binomial prior pmf (n=10, a=0.1, b=0.9), flipped
  {
    double aP = 0.1, bP = 0.9;
    double logB0 = lgamma(aP) + lgamma(bP) - lgamma(aP + bP);
    double pm[11];
    for (int k = 0; k <= 10; ++k) {
      double logC = lgamma(11.0) - lgamma(k + 1.0) - lgamma(11.0 - k);
      double logBt = lgamma(k + aP) + lgamma(10.0 - k + bP) - lgamma(10.0 + aP + bP);
      pm[k] = exp(logC + logBt - logB0);
    }
    for (int k = 0; k < 11; ++k) A.pr.v[k] = (float)pm[10 - k];
  }

  k_init<<<256, 256, 0, stream>>>((float*)d_ws);
  k_decode<<<256, 1024, 0, stream>>>(A);
}

// Round 11
// 43821.967 us; speedup vs baseline: 9.1690x; 1.1127x over previous
//
#include <hip/hip_runtime.h>
#include <cmath>

#define TDEC 250
#define EPS_A 1e-6f

// ---------------- block groups ----------------
#define NB_GRU1 64   // 32 blocks: 4bg x 8jg
#define NB_GRU2 96   // 32
#define NB_PROJ 128  // 16: 4bg x 4jg
#define NB_GIC  144  // 64: 4bg x 16jg
#define NB_GA   208  // 16: 4bg x 4jg
#define NBLK    224

// ---------------- ws float offsets (flags in words 0..8191) ----------------
// MEGA flag words: 0=ctx, 1=hatt, 2=x. helpers: word 0.
#define B_CTX(p)  (8192   + (p)*49152)   // [64][768]
#define B_HATT(p) (106496 + (p)*16384)   // [64][256]
#define B_H1(p)   (139264 + (p)*16384)
#define B_H2(p)   (172032 + (p)*16384)
#define B_X(p)    (204800 + (p)*16384)
#define B_X2(p)   (237568 + (p)*16384)
#define B_X3(p)   (270336 + (p)*16384)
#define B_FR(p)   (303104 + (p)*25600)   // [64][400]
#define B_GIC(p)  (354304 + (p)*49152)   // [64][768]
#define B_GH(p)   (452608 + (p)*49152)   // [64][768]
#define ZERO_END  550912

struct Prior { float v[11]; };

struct KArgs {
  const float *enc;
  const float *p1w,*p1b,*p2w,*p2b;
  const float *awi,*abi,*awh,*abh;
  const float *dWw,*dWb,*dVw,*dFw,*dUw,*dTw,*dTb,*dvw;
  const float *lw,*lb;
  const float *g1wi,*g1bi,*g1wh,*g1bh;
  const float *g2wi,*g2bi,*g2wh,*g2bh;
  const float *prw,*prb;
  float* ws; float* dout;
  Prior pr;
};

#define FMA4(a, av, wv) a = fmaf((av).x,(wv).x, fmaf((av).y,(wv).y, fmaf((av).z,(wv).z, fmaf((av).w,(wv).w,(a)))))

__device__ __forceinline__ float gld(const float* p) {
  return __uint_as_float(__hip_atomic_load((const unsigned*)p, __ATOMIC_RELAXED, __HIP_MEMORY_SCOPE_AGENT));
}
__device__ __forceinline__ void gst(float* p, float v) {
  __hip_atomic_store((unsigned*)p, __float_as_uint(v), __ATOMIC_RELAXED, __HIP_MEMORY_SCOPE_AGENT);
}
__device__ __forceinline__ float sigm(float x) { return 1.f / (1.f + expf(-x)); }

__global__ __launch_bounds__(256) void k_init(float* ws) {
  int idx = blockIdx.x * 256 + threadIdx.x;
  for (int i = idx; i < ZERO_END; i += gridDim.x * 256) ws[i] = 0.f;
}

__device__ __forceinline__ void postw(unsigned* fl, int word, unsigned v) {
  asm volatile("s_waitcnt vmcnt(0)" ::: "memory");
  __syncthreads();
  if (threadIdx.x == 0)
    __hip_atomic_store(&fl[blockIdx.x * 32 + word], v, __ATOMIC_RELAXED, __HIP_MEMORY_SCOPE_AGENT);
}
template <int SLP>
__device__ __forceinline__ void pollge(unsigned* fl, int line, int word, unsigned v) {
  while (__hip_atomic_load(&fl[line * 32 + word], __ATOMIC_RELAXED, __HIP_MEMORY_SCOPE_AGENT) < v)
    __builtin_amdgcn_s_sleep(SLP);
}

// ---------------- GRU block group (32 blocks: 4bg x 8jg, 16b x 32j) -------------
__device__ void gru_block(float* sm, unsigned* fl, float* ws,
                          int bg, int jg, int selfL0, int prodL0, int prodN, int prodWord,
                          const float* Wh, const float* Wi, const float* bi, const float* bh,
                          int offH0, int offXin0, int offXout0) {
  const int tid = threadIdx.x;
  const int B = bg * 16, J0 = jg * 32;
  float* hp   = sm;          // [16][260]
  float* gh1l = sm + 4160;   // [96][16]
  float* xs   = sm + 5696;   // [16][260]
  float* gil  = sm + 9856;   // [96][16]
  for (int t = 0; t < TDEC; ++t) {
    const int p = t & 1;
    // shadow: gh = Wh @ h(t-1)
    if (tid < 8) pollge<4>(fl, selfL0 + tid, 0, (unsigned)t);
    __syncthreads();
    for (int idx = tid; idx < 4096; idx += 1024) {
      int bb = idx >> 8, k = idx & 255;
      hp[bb * 260 + k] = gld(ws + offH0 + (p ^ 1) * 16384 + (B + bb) * 256 + k);
    }
    __syncthreads();
#pragma unroll
    for (int pass = 0; pass < 2; ++pass) {
      if (tid < 768) {
        int lr = pass * 48 + (tid >> 4), bb = tid & 15;
        int wrow = (lr >> 5) * 256 + J0 + (lr & 31);
        const float4* wr = (const float4*)(Wh + (size_t)wrow * 256);
        const float4* xr = (const float4*)(hp + bb * 260);
        float a = 0.f;
#pragma unroll 8
        for (int k4 = 0; k4 < 64; ++k4) { float4 av = xr[k4], wv = wr[k4]; FMA4(a, av, wv); }
        gh1l[lr * 16 + bb] = a + bh[wrow];
      }
    }
    // main: wait x
    if (tid < prodN) pollge<1>(fl, prodL0 + tid, prodWord, (unsigned)(t + 1));
    __syncthreads();
    for (int idx = tid; idx < 4096; idx += 1024) {
      int bb = idx >> 8, k = idx & 255;
      xs[bb * 260 + k] = gld(ws + offXin0 + p * 16384 + (B + bb) * 256 + k);
    }
    __syncthreads();
#pragma unroll
    for (int pass = 0; pass < 2; ++pass) {
      if (tid < 768) {
        int lr = pass * 48 + (tid >> 4), bb = tid & 15;
        int wrow = (lr >> 5) * 256 + J0 + (lr & 31);
        const float4* wr = (const float4*)(Wi + (size_t)wrow * 256);
        const float4* xr = (const float4*)(xs + bb * 260);
        float a = 0.f;
#pragma unroll 8
        for (int k4 = 0; k4 < 64; ++k4) { float4 av = xr[k4], wv = wr[k4]; FMA4(a, av, wv); }
        gil[lr * 16 + bb] = a + bi[wrow];
      }
    }
    __syncthreads();
    if (tid < 512) {
      int lj = tid >> 4, bb = tid & 15;
      float r = sigm(gil[lj * 16 + bb] + gh1l[lj * 16 + bb]);
      float z = sigm(gil[(32 + lj) * 16 + bb] + gh1l[(32 + lj) * 16 + bb]);
      float n = tanhf(gil[(64 + lj) * 16 + bb] + r * gh1l[(64 + lj) * 16 + bb]);
      float hprev = hp[bb * 260 + J0 + lj];
      float hnew = (1.f - z) * n + z * hprev;
      gst(ws + offH0 + p * 16384 + (B + bb) * 256 + J0 + lj, hnew);
      gst(ws + offXout0 + p * 16384 + (B + bb) * 256 + J0 + lj, xs[bb * 260 + J0 + lj] + hnew);
    }
    postw(fl, 0, (unsigned)(t + 1));
  }
}

// ---------------- the persistent decoder ----------------
__global__ __launch_bounds__(1024, 1) void k_decode(KArgs A) {
  __shared__ __align__(16) float sm[31960];
  float* ws = A.ws;
  unsigned* fl = (unsigned*)ws;
  const int blk = blockIdx.x;
  const int tid = threadIdx.x;

  if (blk < 64) {
    // ========== MEGA: per-b. prenet + att-GRU + dW/dV + convs + softmax + ctx + lw ==========
    const int b = blk, bg = b >> 4;
    float* alpha = sm;            // 512
    float* hattl = sm + 512;      // 256
    float* sal   = sm + 768;      // 544
    float* fr    = sm + 1312;     // 416
    float* h1s   = sm + 1728;     // 256
    float* pre   = sm + 1984;     // 128
    float* sgi   = sm + 2112;     // 768
    float* sgh   = sm + 2880;     // 768
    float* t1    = sm + 3648;     // 128
    float* Gl    = sm + 3776;     // 176
    float* sdF   = sm + 3952;     // 176
    float* sdU   = sm + 4128;     // 1024
    float* sdT   = sm + 5152;     // 1024
    float* sdtb  = sm + 6176;     // 128
    float* sdv   = sm + 6304;     // 128
    float* es    = sm + 6432;     // 1024
    float* e     = sm + 7456;     // 512
    float* red   = sm + 7968;     // 16
    int*   wc    = (int*)(sm + 7984); // 8
    float* lv    = sm + 7992;     // 512
    short* li    = (short*)(sm + 8504); // 512 shorts
    float* ctxl  = sm + 8760;     // 768
    float* sdV   = sm + 9528;     // 168x132 = 22176 -> ends 31704

    if (tid < 512) alpha[tid] = (tid == 0) ? 1.f : 0.f;
    if (tid < 256) hattl[tid] = 0.f;
    if (tid < 176) sdF[tid] = (tid < 168) ? A.dFw[tid] : 0.f;
    sdU[tid] = A.dUw[tid];
    sdT[tid] = A.dTw[tid];
    if (tid < 128) { sdtb[tid] = A.dTb[tid]; sdv[tid] = A.dvw[tid]; }
    for (int i = tid; i < 21504; i += 1024) sdV[(i >> 7) * 132 + (i & 127)] = A.dVw[i];
    __syncthreads();

    for (int t = 0; t < TDEC; ++t) {
      const int p = t & 1;
      // S0: wait frame(t) + alpha->sal
      if (tid < 544) { int sg = tid - 10; sal[tid] = (sg >= 0 && sg < 512) ? alpha[sg] : 0.f; }
      else if (tid >= 544 && tid < 548) pollge<1>(fl, NB_PROJ + bg * 4 + (tid - 544), 0, (unsigned)t);
      __syncthreads();
      if (tid < 400) fr[tid] = gld(ws + B_FR(p) + b * 400 + tid);
      __syncthreads();
      // S1: prenet L1 (256 j x 4 parts)
      {
        int j = tid >> 2, part = tid & 3;
        const float4* wr = (const float4*)(A.p1w + (size_t)j * 400 + part * 100);
        const float4* xr = (const float4*)(fr + part * 100);
        float a = 0.f;
#pragma unroll
        for (int k4 = 0; k4 < 25; ++k4) { float4 av = xr[k4], wv = wr[k4]; FMA4(a, av, wv); }
        a += __shfl_xor(a, 1); a += __shfl_xor(a, 2);
        if (part == 0) h1s[j] = fmaxf(a + A.p1b[j], 0.f);
      }
      __syncthreads();
      // S2: prenet L2 (128 j x 8 parts)
      {
        int j = tid >> 3, part = tid & 7;
        const float4* wr = (const float4*)(A.p2w + (size_t)j * 256 + part * 32);
        const float4* xr = (const float4*)(h1s + part * 32);
        float a = 0.f;
#pragma unroll
        for (int k4 = 0; k4 < 8; ++k4) { float4 av = xr[k4], wv = wr[k4]; FMA4(a, av, wv); }
        a += __shfl_xor(a, 1); a += __shfl_xor(a, 2); a += __shfl_xor(a, 4);
        if (part == 0) pre[j] = fmaxf(a + A.p2b[j], 0.f);
      }
      __syncthreads();
      // S3: gip (local awi pre-slice) || poll GIC + GA
      float gipre = 0.f;
      if (tid < 768) {
        const float4* wr = (const float4*)(A.awi + (size_t)tid * 896 + 768);
        const float4* xr = (const float4*)pre;
        float a = 0.f;
#pragma unroll 8
        for (int k4 = 0; k4 < 32; ++k4) { float4 av = xr[k4], wv = wr[k4]; FMA4(a, av, wv); }
        gipre = a;
      } else if (tid < 784) {
        pollge<1>(fl, NB_GIC + bg * 16 + (tid - 768), 0, (unsigned)(t + 1));
      } else if (tid < 788) {
        pollge<1>(fl, NB_GA + bg * 4 + (tid - 784), 0, (unsigned)(t + 1));
      }
      __syncthreads();
      // S4: gate pre-activations
      if (tid < 768) {
        sgi[tid] = gipre + gld(ws + B_GIC(p) + b * 768 + tid) + A.abi[tid];
        sgh[tid] = gld(ws + B_GH(p) + b * 768 + tid) + A.abh[tid];
      }
      __syncthreads();
      // S5: att-GRU combine -> hatt
      if (tid < 256) {
        float r = sigm(sgi[tid] + sgh[tid]);
        float z = sigm(sgi[256 + tid] + sgh[256 + tid]);
        float n = tanhf(sgi[512 + tid] + r * sgh[512 + tid]);
        float hnew = (1.f - z) * n + z * hattl[tid];
        hattl[tid] = hnew;
        gst(ws + B_HATT(p) + b * 256 + tid, hnew);
      }
      postw(fl, 1, (unsigned)(t + 1));
      // S6: t1 = tanh(dW @ hatt + dWb)
      {
        int j = tid >> 3, part = tid & 7;
        const float4* wr = (const float4*)(A.dWw + (size_t)j * 256);
        const float4* xr = (const float4*)hattl;
        float a = 0.f;
#pragma unroll
        for (int kk = 0; kk < 8; ++kk) {
          int i4 = part + kk * 8;
          float4 av = xr[i4], wv = wr[i4];
          FMA4(a, av, wv);
        }
        a += __shfl_xor(a, 1); a += __shfl_xor(a, 2); a += __shfl_xor(a, 4);
        if (part == 0) t1[j] = tanhf(a + A.dWb[j]);
      }
      __syncthreads();
      // S7: G = dV @ t1 (dV LDS-cached)
      if (tid < 168) {
        const float4* wr = (const float4*)(sdV + tid * 132);
        const float4* xr = (const float4*)t1;
        float a = 0.f;
#pragma unroll 8
        for (int k4 = 0; k4 < 32; ++k4) { float4 av = xr[k4], wv = wr[k4]; FMA4(a, av, wv); }
        Gl[tid] = a;
      }
      __syncthreads();
      // S8: static+dynamic conv fused with energy MLP
      {
        int sl = tid >> 1, half = tid & 1;
        float f0[8], g0[8];
#pragma unroll
        for (int q = 0; q < 8; ++q) {
          float fa = 0.f, ga = 0.f;
#pragma unroll
          for (int k = 0; k < 21; ++k) {
            float a = sal[sl + k];
            fa = fmaf(sdF[q * 21 + k], a, fa);
            ga = fmaf(Gl[q * 21 + k], a, ga);
          }
          f0[q] = fa; g0[q] = ga;
        }
        float acc = 0.f;
        for (int cc = half * 64; cc < half * 64 + 64; ++cc) {
          float a = sdtb[cc];
#pragma unroll
          for (int q = 0; q < 8; ++q)
            a = fmaf(sdU[cc * 8 + q], f0[q], fmaf(sdT[cc * 8 + q], g0[q], a));
          acc = fmaf(sdv[cc], tanhf(a), acc);
        }
        es[sl * 2 + half] = acc;
      }
      __syncthreads();
      // S9a: e = mlp + log(prior)
      if (tid < 512) {
        float pr = 0.f;
#pragma unroll
        for (int k = 0; k < 11; ++k) pr = fmaf(A.pr.v[k], sal[tid + k], pr);
        e[tid] = es[tid * 2] + es[tid * 2 + 1] + logf(fmaxf(pr, 1e-6f));
      }
      __syncthreads();
      // S9b: softmax + compaction + sparse ctx
      {
        int lane = tid & 63, wv = tid >> 6;
        float e0 = (tid < 512) ? e[tid] : -1e30f;
        float m = e0;
        for (int o = 32; o; o >>= 1) m = fmaxf(m, __shfl_xor(m, o));
        if (lane == 0) red[wv] = m;
        __syncthreads();
        m = red[0];
        for (int w = 1; w < 8; ++w) m = fmaxf(m, red[w]);
        float p0 = (tid < 512) ? expf(e0 - m) : 0.f;
        float s = p0;
        for (int o = 32; o; o >>= 1) s += __shfl_xor(s, o);
        __syncthreads();
        if (lane == 0) red[wv] = s;
        __syncthreads();
        float tot = red[0];
        for (int w = 1; w < 8; ++w) tot += red[w];
        float inv = 1.f / tot;
        float a0 = p0 * inv;
        if (tid < 512) alpha[tid] = a0;
        unsigned long long mk = __ballot(tid < 512 && a0 > EPS_A);
        if (lane == 0 && wv < 8) wc[wv] = (int)__popcll(mk);
        __syncthreads();
        int base = 0;
        for (int w = 0; w < wv && w < 8; ++w) base += wc[w];
        int n = 0;
        for (int w = 0; w < 8; ++w) n += wc[w];
        unsigned long long below = (1ull << lane) - 1ull;
        if (tid < 512 && a0 > EPS_A) {
          int pp = base + (int)__popcll(mk & below);
          li[pp] = (short)tid; lv[pp] = a0;
        }
        __syncthreads();
        const float* encb = A.enc + (size_t)b * 512 * 768;
        if (tid < 768) {
          float acc = 0.f;
          int i = 0;
          for (; i + 4 <= n; i += 4) {
            float v0 = encb[(size_t)li[i] * 768 + tid];
            float v1 = encb[(size_t)li[i+1] * 768 + tid];
            float v2 = encb[(size_t)li[i+2] * 768 + tid];
            float v3 = encb[(size_t)li[i+3] * 768 + tid];
            acc = fmaf(lv[i],v0, fmaf(lv[i+1],v1, fmaf(lv[i+2],v2, fmaf(lv[i+3],v3, acc))));
          }
          for (; i < n; ++i) acc = fmaf(lv[i], encb[(size_t)li[i] * 768 + tid], acc);
          ctxl[tid] = acc;
          gst(ws + B_CTX(p) + b * 768 + tid, acc);
        }
      }
      postw(fl, 0, (unsigned)(t + 1));
      // S10: x = lw @ [ctx; hatt] + lb
      {
        int j = tid >> 2, part = tid & 3;
        const float* xsrc = (part < 3) ? (ctxl + part * 256) : hattl;
        const float4* wr = (const float4*)(A.lw + (size_t)j * 1024 + part * 256);
        const float4* xr = (const float4*)xsrc;
        float a = 0.f;
#pragma unroll 8
        for (int k4 = 0; k4 < 64; ++k4) { float4 av = xr[k4], wv = wr[k4]; FMA4(a, av, wv); }
        a += __shfl_xor(a, 1); a += __shfl_xor(a, 2);
        if (part == 0) gst(ws + B_X(p) + b * 256 + j, a + A.lb[j]);
      }
      postw(fl, 2, (unsigned)(t + 1));
    }
  } else if (blk < NB_GRU2) {
    int rb = blk - NB_GRU1;
    int bg = rb >> 3, jg = rb & 7;
    gru_block(sm, fl, ws, bg, jg, NB_GRU1 + bg * 8, bg * 16, 16, 2,
              A.g1wh, A.g1wi, A.g1bi, A.g1bh, B_H1(0), B_X(0), B_X2(0));
  } else if (blk < NB_PROJ) {
    int rb = blk - NB_GRU2;
    int bg = rb >> 3, jg = rb & 7;
    gru_block(sm, fl, ws, bg, jg, NB_GRU2 + bg * 8, NB_GRU1 + bg * 8, 8, 0,
              A.g2wh, A.g2wi, A.g2bi, A.g2bh, B_H2(0), B_X2(0), B_X3(0));
  } else if (blk < NB_GIC) {
    // ---- PROJ: frame(t+1) = prw @ x3 + prb; dout row t ----
    int rb = blk - NB_PROJ, bg = rb >> 2, jg = rb & 3;
    int B = bg * 16, J0 = jg * 100;
    float* xs = sm;   // [16][260]
    for (int t = 0; t < TDEC; ++t) {
      const int p = t & 1;
      if (tid < 8) pollge<1>(fl, NB_GRU2 + bg * 8 + tid, 0, (unsigned)(t + 1));
      __syncthreads();
      for (int idx = tid; idx < 4096; idx += 1024) {
        int bb = idx >> 8, k = idx & 255;
        xs[bb * 260 + k] = gld(ws + B_X3(p) + (B + bb) * 256 + k);
      }
      __syncthreads();
#pragma unroll
      for (int pass = 0; pass < 2; ++pass) {
        int bb = pass * 8 + (tid & 7), lj = tid >> 3;
        if (lj < 100) {
          int row = J0 + lj;
          const float4* wr = (const float4*)(A.prw + (size_t)row * 256);
          const float4* xr = (const float4*)(xs + bb * 260);
          float a = 0.f;
#pragma unroll 8
          for (int k4 = 0; k4 < 64; ++k4) { float4 av = xr[k4], wv = wr[k4]; FMA4(a, av, wv); }
          float v = a + A.prb[row];
          gst(ws + B_FR((t + 1) & 1) + (B + bb) * 400 + row, v);
          A.dout[(size_t)(B + bb) * 100000 + (row / 5) * 1250 + t * 5 + (row % 5)] = v;
        }
      }
      postw(fl, 0, (unsigned)(t + 1));
    }
  } else if (blk < NB_GA) {
    // ---- GIC: gic(t) = awi[:, :768] @ ctx(t-1)  (shadow) ----
    int rb = blk - NB_GIC, bg = rb >> 4, jg = rb & 15;
    int B = bg * 16, R0 = jg * 48;
    float* cl = sm;  // [16][772]
    for (int t = 0; t < TDEC; ++t) {
      const int p = t & 1;
      if (tid < 16) pollge<4>(fl, bg * 16 + tid, 0, (unsigned)t);
      __syncthreads();
      for (int idx = tid; idx < 12288; idx += 1024) {
        int bb = idx / 768, k = idx - bb * 768;
        cl[bb * 772 + k] = gld(ws + B_CTX(p ^ 1) + (B + bb) * 768 + k);
      }
      __syncthreads();
      if (tid < 768) {
        int rr = tid >> 4, bb = tid & 15;
        int row = R0 + rr;
        const float4* wr = (const float4*)(A.awi + (size_t)row * 896);
        const float4* xr = (const float4*)(cl + bb * 772);
        float a = 0.f;
#pragma unroll 8
        for (int k4 = 0; k4 < 192; ++k4) { float4 av = xr[k4], wv = wr[k4]; FMA4(a, av, wv); }
        gst(ws + B_GIC(p) + (B + bb) * 768 + row, a);
      }
      postw(fl, 0, (unsigned)(t + 1));
    }
  } else {
    // ---- GA: gh(t) = awh @ hatt(t-1)  (shadow) ----
    int rb = blk - NB_GA, bg = rb >> 2, jg = rb & 3;
    int B = bg * 16, R0 = jg * 192;
    float* hl = sm;  // [16][260]
    for (int t = 0; t < TDEC; ++t) {
      const int p = t & 1;
      if (tid < 16) pollge<4>(fl, bg * 16 + tid, 1, (unsigned)t);
      __syncthreads();
      for (int idx = tid; idx < 4096; idx += 1024) {
        int bb = idx >> 8, k = idx & 255;
        hl[bb * 260 + k] = gld(ws + B_HATT(p ^ 1) + (B + bb) * 256 + k);
      }
      __syncthreads();
#pragma unroll
      for (int pass = 0; pass < 3; ++pass) {
        int rr = pass * 64 + (tid >> 4), bb = tid & 15;
        int row = R0 + rr;
        const float4* wr = (const float4*)(A.awh + (size_t)row * 256);
        const float4* xr = (const float4*)(hl + bb * 260);
        float a = 0.f;
#pragma unroll 8
        for (int k4 = 0; k4 < 64; ++k4) { float4 av = xr[k4], wv = wr[k4]; FMA4(a, av, wv); }
        gst(ws + B_GH(p) + (B + bb) * 768 + row, a);
      }
      postw(fl, 0, (unsigned)(t + 1));
    }
  }
}

// ---------------- host ----------------
extern "C" void kernel_launch(void* const* d_in, const int* in_sizes, int n_in,
                              void* d_out, int out_size, void* d_ws, size_t ws_size,
                              hipStream_t stream) {
  (void)in_sizes; (void)n_in; (void)out_size; (void)ws_size;
  KArgs A;
  A.enc  = (const float*)d_in[0];
  A.p1w  = (const float*)d_in[1];  A.p1b  = (const float*)d_in[2];
  A.p2w  = (const float*)d_in[3];  A.p2b  = (const float*)d_in[4];
  A.awi  = (const float*)d_in[5];  A.abi  = (const float*)d_in[6];
  A.awh  = (const float*)d_in[7];  A.abh  = (const float*)d_in[8];
  A.dWw  = (const float*)d_in[9];  A.dWb  = (const float*)d_in[10];
  A.dVw  = (const float*)d_in[11]; A.dFw  = (const float*)d_in[12];
  A.dUw  = (const float*)d_in[13]; A.dTw  = (const float*)d_in[14];
  A.dTb  = (const float*)d_in[15]; A.dvw  = (const float*)d_in[16];
  A.lw   = (const float*)d_in[17]; A.lb   = (const float*)d_in[18];
  A.g1wi = (const float*)d_in[19]; A.g1bi = (const float*)d_in[20];
  A.g1wh = (const float*)d_in[21]; A.g1bh = (const float*)d_in[22];
  A.g2wi = (const float*)d_in[23]; A.g2bi = (const float*)d_in[24];
  A.g2wh = (const float*)d_in[25]; A.g2bh = (const float*)d_in[26];
  A.prw  = (const float*)d_in[27]; A.prb  = (const float*)d_in[28];
  A.ws   = (float*)d_ws;
  A.dout = (float*)d_out;

  // beta-binomial prior pmf (n=10, a=0.1, b=0.9), flipped
  {
    double aP = 0.1, bP = 0.9;
    double logB0 = lgamma(aP) + lgamma(bP) - lgamma(aP + bP);
    double pm[11];
    for (int k = 0; k <= 10; ++k) {
      double logC = lgamma(11.0) - lgamma(k + 1.0) - lgamma(11.0 - k);
      double logBt = lgamma(k + aP) + lgamma(10.0 - k + bP) - lgamma(10.0 + aP + bP);
      pm[k] = exp(logC + logBt - logB0);
    }
    for (int k = 0; k < 11; ++k) A.pr.v[k] = (float)pm[10 - k];
  }

  k_init<<<256, 256, 0, stream>>>((float*)d_ws);
  k_decode<<<NBLK, 1024, 0, stream>>>(A);
}

// Round 12
// 32595.670 us; speedup vs baseline: 12.3270x; 1.3444x over previous
//
#include <hip/hip_runtime.h>
#include <cmath>

#define TDEC 250
#define EPS_A 1e-6f

// ---------------- block groups ----------------
#define NB_GRU1 64   // 32 blocks: 4bg x 8jg
#define NB_GRU2 96   // 32
#define NB_PROJ 128  // 16: 4bg x 4jg
#define NB_GIC  144  // 64: 4bg x 16jg
#define NB_GA   208  // 16: 4bg x 4jg
#define NBLK    224

// ---------------- ws float offsets (flags in words 0..8191) ----------------
// MEGA flag words: 0=ctx, 1=hatt, 2=x. helpers: word 0.
#define B_CTX(p)  (8192   + (p)*49152)   // [64][768]
#define B_HATT(p) (106496 + (p)*16384)   // [64][256]
#define B_H1(p)   (139264 + (p)*16384)
#define B_H2(p)   (172032 + (p)*16384)
#define B_X(p)    (204800 + (p)*16384)
#define B_X2(p)   (237568 + (p)*16384)
#define B_X3(p)   (270336 + (p)*16384)
#define B_FR(p)   (303104 + (p)*25600)   // [64][400]
#define B_GIC(p)  (354304 + (p)*49152)   // [64][768]
#define B_GH(p)   (452608 + (p)*49152)   // [64][768]
#define ZERO_END  550912
#define CVT_OFF   550912                 // bf16 weight region (u16), 2,203,648 u16

// bf16 weight offsets (u16 units)
#define OP1   0u        // p1w  [256][400]
#define OP2   102400u   // p2w  [128][256]
#define OAWI  135168u   // awi  [768][896]
#define OAWH  823296u   // awh  [768][256]
#define ODW   1019904u  // dWw  [128][256]
#define OLW   1052672u  // lw   [256][1024]
#define OG1I  1314816u  // g1wi [768][256]
#define OG1H  1511424u
#define OG2I  1708032u
#define OG2H  1904640u
#define OPR   2101248u  // prw  [400][256]
#define CVT_N 2203648u

struct Prior { float v[11]; };

struct KArgs {
  const float *enc;
  const float *p1w,*p1b,*p2w,*p2b;
  const float *awi,*abi,*awh,*abh;
  const float *dWw,*dWb,*dVw,*dFw,*dUw,*dTw,*dTb,*dvw;
  const float *lw,*lb;
  const float *g1wi,*g1bi,*g1wh,*g1bh;
  const float *g2wi,*g2bi,*g2wh,*g2bh;
  const float *prw,*prb;
  float* ws; float* dout;
  Prior pr;
};

__device__ __forceinline__ float gld(const float* p) {
  return __uint_as_float(__hip_atomic_load((const unsigned*)p, __ATOMIC_RELAXED, __HIP_MEMORY_SCOPE_AGENT));
}
__device__ __forceinline__ void gst(float* p, float v) {
  __hip_atomic_store((unsigned*)p, __float_as_uint(v), __ATOMIC_RELAXED, __HIP_MEMORY_SCOPE_AGENT);
}
__device__ __forceinline__ float sigm(float x) { return 1.f / (1.f + expf(-x)); }

// bf16-pair dot: one uint4 = 8 bf16 weights vs 8 fp32 activations (two float4)
__device__ __forceinline__ float dot8(uint4 w, float4 x0, float4 x1) {
  float a;
  a = __uint_as_float(w.x << 16) * x0.x;
  a = fmaf(__uint_as_float(w.x & 0xffff0000u), x0.y, a);
  a = fmaf(__uint_as_float(w.y << 16),         x0.z, a);
  a = fmaf(__uint_as_float(w.y & 0xffff0000u), x0.w, a);
  a = fmaf(__uint_as_float(w.z << 16),         x1.x, a);
  a = fmaf(__uint_as_float(w.z & 0xffff0000u), x1.y, a);
  a = fmaf(__uint_as_float(w.w << 16),         x1.z, a);
  a = fmaf(__uint_as_float(w.w & 0xffff0000u), x1.w, a);
  return a;
}

__global__ __launch_bounds__(256) void k_init(float* ws) {
  int idx = blockIdx.x * 256 + threadIdx.x;
  for (int i = idx; i < ZERO_END; i += gridDim.x * 256) ws[i] = 0.f;
}

// ---------------- fp32 -> bf16 (RTNE) weight conversion ----------------
struct CvtSeg { const float* src; unsigned dst; unsigned n; };
struct CvtArgs { CvtSeg s[11]; };
__global__ __launch_bounds__(256) void k_cvt(CvtArgs c, unsigned short* wb) {
  for (int seg = 0; seg < 11; ++seg) {
    const float* s = c.s[seg].src;
    unsigned short* d = wb + c.s[seg].dst;
    unsigned n = c.s[seg].n;
    for (unsigned i = blockIdx.x * 256 + threadIdx.x; i < n; i += gridDim.x * 256) {
      unsigned u = __float_as_uint(s[i]);
      d[i] = (unsigned short)((u + 0x7fffu + ((u >> 16) & 1u)) >> 16);
    }
  }
}

__device__ __forceinline__ void postw(unsigned* fl, int word, unsigned v) {
  asm volatile("s_waitcnt vmcnt(0)" ::: "memory");
  __syncthreads();
  if (threadIdx.x == 0)
    __hip_atomic_store(&fl[blockIdx.x * 32 + word], v, __ATOMIC_RELAXED, __HIP_MEMORY_SCOPE_AGENT);
}
template <int SLP>
__device__ __forceinline__ void pollge(unsigned* fl, int line, int word, unsigned v) {
  while (__hip_atomic_load(&fl[line * 32 + word], __ATOMIC_RELAXED, __HIP_MEMORY_SCOPE_AGENT) < v)
    __builtin_amdgcn_s_sleep(SLP);
}

// ---------------- GRU block group (32 blocks: 4bg x 8jg, 16b x 32j) -------------
__device__ void gru_block(float* sm, unsigned* fl, float* ws, const unsigned short* wb,
                          int bg, int jg, int selfL0, int prodL0, int prodN, int prodWord,
                          unsigned OWh, unsigned OWi, const float* bi, const float* bh,
                          int offH0, int offXin0, int offXout0) {
  const int tid = threadIdx.x;
  const int B = bg * 16, J0 = jg * 32;
  float* hp   = sm;          // [16][260]
  float* gh1l = sm + 4160;   // [96][16]
  float* xs   = sm + 5696;   // [16][260]
  float* gil  = sm + 9856;   // [96][16]
  for (int t = 0; t < TDEC; ++t) {
    const int p = t & 1;
    // shadow: gh = Wh @ h(t-1)
    if (tid < 8) pollge<4>(fl, selfL0 + tid, 0, (unsigned)t);
    __syncthreads();
    for (int idx = tid; idx < 4096; idx += 1024) {
      int bb = idx >> 8, k = idx & 255;
      hp[bb * 260 + k] = gld(ws + offH0 + (p ^ 1) * 16384 + (B + bb) * 256 + k);
    }
    __syncthreads();
#pragma unroll
    for (int pass = 0; pass < 2; ++pass) {
      if (tid < 768) {
        int lr = pass * 48 + (tid >> 4), bb = tid & 15;
        int wrow = (lr >> 5) * 256 + J0 + (lr & 31);
        const uint4* wr = (const uint4*)(wb + OWh + (size_t)wrow * 256);
        const float4* xr = (const float4*)(hp + bb * 260);
        float a = 0.f;
#pragma unroll 8
        for (int k4 = 0; k4 < 32; ++k4) a += dot8(wr[k4], xr[2*k4], xr[2*k4+1]);
        gh1l[lr * 16 + bb] = a + bh[wrow];
      }
    }
    // main: wait x
    if (tid < prodN) pollge<1>(fl, prodL0 + tid, prodWord, (unsigned)(t + 1));
    __syncthreads();
    for (int idx = tid; idx < 4096; idx += 1024) {
      int bb = idx >> 8, k = idx & 255;
      xs[bb * 260 + k] = gld(ws + offXin0 + p * 16384 + (B + bb) * 256 + k);
    }
    __syncthreads();
#pragma unroll
    for (int pass = 0; pass < 2; ++pass) {
      if (tid < 768) {
        int lr = pass * 48 + (tid >> 4), bb = tid & 15;
        int wrow = (lr >> 5) * 256 + J0 + (lr & 31);
        const uint4* wr = (const uint4*)(wb + OWi + (size_t)wrow * 256);
        const float4* xr = (const float4*)(xs + bb * 260);
        float a = 0.f;
#pragma unroll 8
        for (int k4 = 0; k4 < 32; ++k4) a += dot8(wr[k4], xr[2*k4], xr[2*k4+1]);
        gil[lr * 16 + bb] = a + bi[wrow];
      }
    }
    __syncthreads();
    if (tid < 512) {
      int lj = tid >> 4, bb = tid & 15;
      float r = sigm(gil[lj * 16 + bb] + gh1l[lj * 16 + bb]);
      float z = sigm(gil[(32 + lj) * 16 + bb] + gh1l[(32 + lj) * 16 + bb]);
      float n = tanhf(gil[(64 + lj) * 16 + bb] + r * gh1l[(64 + lj) * 16 + bb]);
      float hprev = hp[bb * 260 + J0 + lj];
      float hnew = (1.f - z) * n + z * hprev;
      gst(ws + offH0 + p * 16384 + (B + bb) * 256 + J0 + lj, hnew);
      gst(ws + offXout0 + p * 16384 + (B + bb) * 256 + J0 + lj, xs[bb * 260 + J0 + lj] + hnew);
    }
    postw(fl, 0, (unsigned)(t + 1));
  }
}

// ---------------- the persistent decoder ----------------
__global__ __launch_bounds__(1024, 1) void k_decode(KArgs A) {
  __shared__ __align__(16) float sm[31960];
  float* ws = A.ws;
  unsigned* fl = (unsigned*)ws;
  const unsigned short* wb = (const unsigned short*)(ws + CVT_OFF);
  const int blk = blockIdx.x;
  const int tid = threadIdx.x;

  if (blk < 64) {
    // ========== MEGA: per-b. prenet + att-GRU + dW/dV + convs + softmax + ctx + lw ==========
    const int b = blk, bg = b >> 4;
    float* alpha = sm;            // 512
    float* hattl = sm + 512;      // 256
    float* sal   = sm + 768;      // 544
    float* fr    = sm + 1312;     // 416
    float* h1s   = sm + 1728;     // 256
    float* pre   = sm + 1984;     // 128
    float* sgi   = sm + 2112;     // 768
    float* sgh   = sm + 2880;     // 768
    float* t1    = sm + 3648;     // 128
    float* Gl    = sm + 3776;     // 176
    float* sdF   = sm + 3952;     // 176
    float* sdU   = sm + 4128;     // 1024
    float* sdT   = sm + 5152;     // 1024
    float* sdtb  = sm + 6176;     // 128
    float* sdv   = sm + 6304;     // 128
    float* es    = sm + 6432;     // 1024
    float* e     = sm + 7456;     // 512
    float* red   = sm + 7968;     // 16
    int*   wc    = (int*)(sm + 7984); // 8
    float* lv    = sm + 7992;     // 512
    short* li    = (short*)(sm + 8504); // 512 shorts
    float* ctxl  = sm + 8760;     // 768
    float* sdV   = sm + 9528;     // 168x132 = 22176

    if (tid < 512) alpha[tid] = (tid == 0) ? 1.f : 0.f;
    if (tid < 256) hattl[tid] = 0.f;
    if (tid < 176) sdF[tid] = (tid < 168) ? A.dFw[tid] : 0.f;
    sdU[tid] = A.dUw[tid];
    sdT[tid] = A.dTw[tid];
    if (tid < 128) { sdtb[tid] = A.dTb[tid]; sdv[tid] = A.dvw[tid]; }
    for (int i = tid; i < 21504; i += 1024) sdV[(i >> 7) * 132 + (i & 127)] = A.dVw[i];
    __syncthreads();

    for (int t = 0; t < TDEC; ++t) {
      const int p = t & 1;
      // S0: wait frame(t) + alpha->sal
      if (tid < 544) { int sg = tid - 10; sal[tid] = (sg >= 0 && sg < 512) ? alpha[sg] : 0.f; }
      else if (tid >= 544 && tid < 548) pollge<1>(fl, NB_PROJ + bg * 4 + (tid - 544), 0, (unsigned)t);
      __syncthreads();
      if (tid < 400) fr[tid] = gld(ws + B_FR(p) + b * 400 + tid);
      __syncthreads();
      // S1: prenet L1 (256 j x 4 parts)
      {
        int j = tid >> 2, part = tid & 3;
        const uint4* wr = (const uint4*)(wb + OP1 + (size_t)j * 400);
        const float4* xr = (const float4*)fr;
        float a = 0.f;
        for (int k4 = part; k4 < 50; k4 += 4) a += dot8(wr[k4], xr[2*k4], xr[2*k4+1]);
        a += __shfl_xor(a, 1); a += __shfl_xor(a, 2);
        if (part == 0) h1s[j] = fmaxf(a + A.p1b[j], 0.f);
      }
      __syncthreads();
      // S2: prenet L2 (128 j x 8 parts)
      {
        int j = tid >> 3, part = tid & 7;
        const uint4* wr = (const uint4*)(wb + OP2 + (size_t)j * 256);
        const float4* xr = (const float4*)h1s;
        float a = 0.f;
        for (int k4 = part; k4 < 32; k4 += 8) a += dot8(wr[k4], xr[2*k4], xr[2*k4+1]);
        a += __shfl_xor(a, 1); a += __shfl_xor(a, 2); a += __shfl_xor(a, 4);
        if (part == 0) pre[j] = fmaxf(a + A.p2b[j], 0.f);
      }
      __syncthreads();
      // S3: gip (local awi pre-slice, bf16) || poll GIC + GA
      float gipre = 0.f;
      if (tid < 768) {
        const uint4* wr = (const uint4*)(wb + OAWI + (size_t)tid * 896 + 768);
        const float4* xr = (const float4*)pre;
        float a = 0.f;
#pragma unroll
        for (int k4 = 0; k4 < 16; ++k4) a += dot8(wr[k4], xr[2*k4], xr[2*k4+1]);
        gipre = a;
      } else if (tid < 784) {
        pollge<1>(fl, NB_GIC + bg * 16 + (tid - 768), 0, (unsigned)(t + 1));
      } else if (tid < 788) {
        pollge<1>(fl, NB_GA + bg * 4 + (tid - 784), 0, (unsigned)(t + 1));
      }
      __syncthreads();
      // S4: gate pre-activations
      if (tid < 768) {
        sgi[tid] = gipre + gld(ws + B_GIC(p) + b * 768 + tid) + A.abi[tid];
        sgh[tid] = gld(ws + B_GH(p) + b * 768 + tid) + A.abh[tid];
      }
      __syncthreads();
      // S5: att-GRU combine -> hatt
      if (tid < 256) {
        float r = sigm(sgi[tid] + sgh[tid]);
        float z = sigm(sgi[256 + tid] + sgh[256 + tid]);
        float n = tanhf(sgi[512 + tid] + r * sgh[512 + tid]);
        float hnew = (1.f - z) * n + z * hattl[tid];
        hattl[tid] = hnew;
        gst(ws + B_HATT(p) + b * 256 + tid, hnew);
      }
      postw(fl, 1, (unsigned)(t + 1));
      // S6: t1 = tanh(dW @ hatt + dWb)
      {
        int j = tid >> 3, part = tid & 7;
        const uint4* wr = (const uint4*)(wb + ODW + (size_t)j * 256);
        const float4* xr = (const float4*)hattl;
        float a = 0.f;
        for (int k4 = part; k4 < 32; k4 += 8) a += dot8(wr[k4], xr[2*k4], xr[2*k4+1]);
        a += __shfl_xor(a, 1); a += __shfl_xor(a, 2); a += __shfl_xor(a, 4);
        if (part == 0) t1[j] = tanhf(a + A.dWb[j]);
      }
      __syncthreads();
      // S7: G = dV @ t1 (dV LDS-cached fp32)
      if (tid < 168) {
        const float4* wr = (const float4*)(sdV + tid * 132);
        const float4* xr = (const float4*)t1;
        float a = 0.f;
#pragma unroll 8
        for (int k4 = 0; k4 < 32; ++k4) {
          float4 av = xr[k4], wv = wr[k4];
          a = fmaf(av.x,wv.x, fmaf(av.y,wv.y, fmaf(av.z,wv.z, fmaf(av.w,wv.w, a))));
        }
        Gl[tid] = a;
      }
      __syncthreads();
      // S8: static+dynamic conv fused with energy MLP
      {
        int sl = tid >> 1, half = tid & 1;
        float f0[8], g0[8];
#pragma unroll
        for (int q = 0; q < 8; ++q) {
          float fa = 0.f, ga = 0.f;
#pragma unroll
          for (int k = 0; k < 21; ++k) {
            float a = sal[sl + k];
            fa = fmaf(sdF[q * 21 + k], a, fa);
            ga = fmaf(Gl[q * 21 + k], a, ga);
          }
          f0[q] = fa; g0[q] = ga;
        }
        float acc = 0.f;
        for (int cc = half * 64; cc < half * 64 + 64; ++cc) {
          float a = sdtb[cc];
#pragma unroll
          for (int q = 0; q < 8; ++q)
            a = fmaf(sdU[cc * 8 + q], f0[q], fmaf(sdT[cc * 8 + q], g0[q], a));
          acc = fmaf(sdv[cc], tanhf(a), acc);
        }
        es[sl * 2 + half] = acc;
      }
      __syncthreads();
      // S9a: e = mlp + log(prior)
      if (tid < 512) {
        float pr = 0.f;
#pragma unroll
        for (int k = 0; k < 11; ++k) pr = fmaf(A.pr.v[k], sal[tid + k], pr);
        e[tid] = es[tid * 2] + es[tid * 2 + 1] + logf(fmaxf(pr, 1e-6f));
      }
      __syncthreads();
      // S9b: softmax + compaction + sparse ctx
      {
        int lane = tid & 63, wv = tid >> 6;
        float e0 = (tid < 512) ? e[tid] : -1e30f;
        float m = e0;
        for (int o = 32; o; o >>= 1) m = fmaxf(m, __shfl_xor(m, o));
        if (lane == 0) red[wv] = m;
        __syncthreads();
        m = red[0];
        for (int w = 1; w < 8; ++w) m = fmaxf(m, red[w]);
        float p0 = (tid < 512) ? expf(e0 - m) : 0.f;
        float s = p0;
        for (int o = 32; o; o >>= 1) s += __shfl_xor(s, o);
        __syncthreads();
        if (lane == 0) red[wv] = s;
        __syncthreads();
        float tot = red[0];
        for (int w = 1; w < 8; ++w) tot += red[w];
        float inv = 1.f / tot;
        float a0 = p0 * inv;
        if (tid < 512) alpha[tid] = a0;
        unsigned long long mk = __ballot(tid < 512 && a0 > EPS_A);
        if (lane == 0 && wv < 8) wc[wv] = (int)__popcll(mk);
        __syncthreads();
        int base = 0;
        for (int w = 0; w < wv && w < 8; ++w) base += wc[w];
        int n = 0;
        for (int w = 0; w < 8; ++w) n += wc[w];
        unsigned long long below = (1ull << lane) - 1ull;
        if (tid < 512 && a0 > EPS_A) {
          int pp = base + (int)__popcll(mk & below);
          li[pp] = (short)tid; lv[pp] = a0;
        }
        __syncthreads();
        const float* encb = A.enc + (size_t)b * 512 * 768;
        if (tid < 768) {
          float acc = 0.f;
          int i = 0;
          for (; i + 4 <= n; i += 4) {
            float v0 = encb[(size_t)li[i] * 768 + tid];
            float v1 = encb[(size_t)li[i+1] * 768 + tid];
            float v2 = encb[(size_t)li[i+2] * 768 + tid];
            float v3 = encb[(size_t)li[i+3] * 768 + tid];
            acc = fmaf(lv[i],v0, fmaf(lv[i+1],v1, fmaf(lv[i+2],v2, fmaf(lv[i+3],v3, acc))));
          }
          for (; i < n; ++i) acc = fmaf(lv[i], encb[(size_t)li[i] * 768 + tid], acc);
          ctxl[tid] = acc;
          gst(ws + B_CTX(p) + b * 768 + tid, acc);
        }
      }
      postw(fl, 0, (unsigned)(t + 1));
      // S10: x = lw @ [ctx; hatt] + lb (bf16 weights)
      {
        int j = tid >> 2, part = tid & 3;
        const uint4* wr = (const uint4*)(wb + OLW + (size_t)j * 1024);
        const float4* c4 = (const float4*)ctxl;
        const float4* h4 = (const float4*)hattl;
        float a = 0.f;
        for (int k4 = part; k4 < 128; k4 += 4) {
          float4 x0, x1;
          if (k4 < 96) { x0 = c4[2*k4]; x1 = c4[2*k4+1]; }
          else { int hk = k4 - 96; x0 = h4[2*hk]; x1 = h4[2*hk+1]; }
          a += dot8(wr[k4], x0, x1);
        }
        a += __shfl_xor(a, 1); a += __shfl_xor(a, 2);
        if (part == 0) gst(ws + B_X(p) + b * 256 + j, a + A.lb[j]);
      }
      postw(fl, 2, (unsigned)(t + 1));
    }
  } else if (blk < NB_GRU2) {
    int rb = blk - NB_GRU1;
    int bg = rb >> 3, jg = rb & 7;
    gru_block(sm, fl, ws, wb, bg, jg, NB_GRU1 + bg * 8, bg * 16, 16, 2,
              OG1H, OG1I, A.g1bi, A.g1bh, B_H1(0), B_X(0), B_X2(0));
  } else if (blk < NB_PROJ) {
    int rb = blk - NB_GRU2;
    int bg = rb >> 3, jg = rb & 7;
    gru_block(sm, fl, ws, wb, bg, jg, NB_GRU2 + bg * 8, NB_GRU1 + bg * 8, 8, 0,
              OG2H, OG2I, A.g2bi, A.g2bh, B_H2(0), B_X2(0), B_X3(0));
  } else if (blk < NB_GIC) {
    // ---- PROJ: frame(t+1) = prw @ x3 + prb; dout row t ----
    int rb = blk - NB_PROJ, bg = rb >> 2, jg = rb & 3;
    int B = bg * 16, J0 = jg * 100;
    float* xs = sm;   // [16][260]
    for (int t = 0; t < TDEC; ++t) {
      const int p = t & 1;
      if (tid < 8) pollge<1>(fl, NB_GRU2 + bg * 8 + tid, 0, (unsigned)(t + 1));
      __syncthreads();
      for (int idx = tid; idx < 4096; idx += 1024) {
        int bb = idx >> 8, k = idx & 255;
        xs[bb * 260 + k] = gld(ws + B_X3(p) + (B + bb) * 256 + k);
      }
      __syncthreads();
#pragma unroll
      for (int pass = 0; pass < 2; ++pass) {
        int bb = pass * 8 + (tid & 7), lj = tid >> 3;
        if (lj < 100) {
          int row = J0 + lj;
          const uint4* wr = (const uint4*)(wb + OPR + (size_t)row * 256);
          const float4* xr = (const float4*)(xs + bb * 260);
          float a = 0.f;
#pragma unroll 8
          for (int k4 = 0; k4 < 32; ++k4) a += dot8(wr[k4], xr[2*k4], xr[2*k4+1]);
          float v = a + A.prb[row];
          gst(ws + B_FR((t + 1) & 1) + (B + bb) * 400 + row, v);
          A.dout[(size_t)(B + bb) * 100000 + (row / 5) * 1250 + t * 5 + (row % 5)] = v;
        }
      }
      postw(fl, 0, (unsigned)(t + 1));
    }
  } else if (blk < NB_GA) {
    // ---- GIC: gic(t) = awi[:, :768] @ ctx(t-1)  (shadow) ----
    int rb = blk - NB_GIC, bg = rb >> 4, jg = rb & 15;
    int B = bg * 16, R0 = jg * 48;
    float* cl = sm;  // [16][772]
    for (int t = 0; t < TDEC; ++t) {
      const int p = t & 1;
      if (tid < 16) pollge<4>(fl, bg * 16 + tid, 0, (unsigned)t);
      __syncthreads();
      for (int idx = tid; idx < 12288; idx += 1024) {
        int bb = idx / 768, k = idx - bb * 768;
        cl[bb * 772 + k] = gld(ws + B_CTX(p ^ 1) + (B + bb) * 768 + k);
      }
      __syncthreads();
      if (tid < 768) {
        int rr = tid >> 4, bb = tid & 15;
        int row = R0 + rr;
        const uint4* wr = (const uint4*)(wb + OAWI + (size_t)row * 896);
        const float4* xr = (const float4*)(cl + bb * 772);
        float a = 0.f;
#pragma unroll 8
        for (int k4 = 0; k4 < 96; ++k4) a += dot8(wr[k4], xr[2*k4], xr[2*k4+1]);
        gst(ws + B_GIC(p) + (B + bb) * 768 + row, a);
      }
      postw(fl, 0, (unsigned)(t + 1));
    }
  } else {
    // ---- GA: gh(t) = awh @ hatt(t-1)  (shadow) ----
    int rb = blk - NB_GA, bg = rb >> 2, jg = rb & 3;
    int B = bg * 16, R0 = jg * 192;
    float* hl = sm;  // [16][260]
    for (int t = 0; t < TDEC; ++t) {
      const int p = t & 1;
      if (tid < 16) pollge<4>(fl, bg * 16 + tid, 1, (unsigned)t);
      __syncthreads();
      for (int idx = tid; idx < 4096; idx += 1024) {
        int bb = idx >> 8, k = idx & 255;
        hl[bb * 260 + k] = gld(ws + B_HATT(p ^ 1) + (B + bb) * 256 + k);
      }
      __syncthreads();
#pragma unroll
      for (int pass = 0; pass < 3; ++pass) {
        int rr = pass * 64 + (tid >> 4), bb = tid & 15;
        int row = R0 + rr;
        const uint4* wr = (const uint4*)(wb + OAWH + (size_t)row * 256);
        const float4* xr = (const float4*)(hl + bb * 260);
        float a = 0.f;
#pragma unroll 8
        for (int k4 = 0; k4 < 32; ++k4) a += dot8(wr[k4], xr[2*k4], xr[2*k4+1]);
        gst(ws + B_GH(p) + (B + bb) * 768 + row, a);
      }
      postw(fl, 0, (unsigned)(t + 1));
    }
  }
}

// ---------------- host ----------------
extern "C" void kernel_launch(void* const* d_in, const int* in_sizes, int n_in,
                              void* d_out, int out_size, void* d_ws, size_t ws_size,
                              hipStream_t stream) {
  (void)in_sizes; (void)n_in; (void)out_size; (void)ws_size;
  KArgs A;
  A.enc  = (const float*)d_in[0];
  A.p1w  = (const float*)d_in[1];  A.p1b  = (const float*)d_in[2];
  A.p2w  = (const float*)d_in[3];  A.p2b  = (const float*)d_in[4];
  A.awi  = (const float*)d_in[5];  A.abi  = (const float*)d_in[6];
  A.awh  = (const float*)d_in[7];  A.abh  = (const float*)d_in[8];
  A.dWw  = (const float*)d_in[9];  A.dWb  = (const float*)d_in[10];
  A.dVw  = (const float*)d_in[11]; A.dFw  = (const float*)d_in[12];
  A.dUw  = (const float*)d_in[13]; A.dTw  = (const float*)d_in[14];
  A.dTb  = (const float*)d_in[15]; A.dvw  = (const float*)d_in[16];
  A.lw   = (const float*)d_in[17]; A.lb   = (const float*)d_in[18];
  A.g1wi = (const float*)d_in[19]; A.g1bi = (const float*)d_in[20];
  A.g1wh = (const float*)d_in[21]; A.g1bh = (const float*)d_in[22];
  A.g2wi = (const float*)d_in[23]; A.g2bi = (const float*)d_in[24];
  A.g2wh = (const float*)d_in[25]; A.g2bh = (const float*)d_in[26];
  A.prw  = (const float*)d_in[27]; A.prb  = (const float*)d_in[28];
  A.ws   = (float*)d_ws;
  A.dout = (float*)d_out;

  // beta-binomial prior pmf (n=10, a=0.1, b=0.9), flipped
  {
    double aP = 0.1, bP = 0.9;
    double logB0 = lgamma(aP) + lgamma(bP) - lgamma(aP + bP);
    double pm[11];
    for (int k = 0; k <= 10; ++k) {
      double logC = lgamma(11.0) - lgamma(k + 1.0) - lgamma(11.0 - k);
      double logBt = lgamma(k + aP) + lgamma(10.0 - k + bP) - lgamma(10.0 + aP + bP);
      pm[k] = exp(logC + logBt - logB0);
    }
    for (int k = 0; k < 11; ++k) A.pr.v[k] = (float)pm[10 - k];
  }

  CvtArgs C;
  C.s[0]  = {A.p1w,  OP1,  102400u};
  C.s[1]  = {A.p2w,  OP2,  32768u};
  C.s[2]  = {A.awi,  OAWI, 688128u};
  C.s[3]  = {A.awh,  OAWH, 196608u};
  C.s[4]  = {A.dWw,  ODW,  32768u};
  C.s[5]  = {A.lw,   OLW,  262144u};
  C.s[6]  = {A.g1wi, OG1I, 196608u};
  C.s[7]  = {A.g1wh, OG1H, 196608u};
  C.s[8]  = {A.g2wi, OG2I, 196608u};
  C.s[9]  = {A.g2wh, OG2H, 196608u};
  C.s[10] = {A.prw,  OPR,  102400u};

  k_init<<<256, 256, 0, stream>>>((float*)d_ws);
  k_cvt<<<256, 256, 0, stream>>>(C, (unsigned short*)((float*)d_ws + CVT_OFF));
  k_decode<<<NBLK, 1024, 0, stream>>>(A);
}